// Round 19
// baseline (556.270 us; speedup 1.0000x reference)
//
#include <hip/hip_runtime.h>
#include <hip/hip_bf16.h>
#include <math.h>

#define NB 32
#define CC 256
#define TT 64
#define VV 48
#define NTOK (NB*TT*VV)   // 98304
#define LNE 1e-5f
#define PROWS 3264        // (4+64)*48
#define A0P_USH ((size_t)NB*PROWS*192)

typedef __attribute__((ext_vector_type(8))) __bf16 bf16x8;
typedef __attribute__((ext_vector_type(4))) float f32x4;

__device__ inline float bfbits2f(unsigned int bits){
    union{unsigned int u; float f;} c; c.u = bits<<16; return c.f;
}
__device__ inline unsigned short f2bf(float x){
    union{ __bf16 h; unsigned short u; } c; c.h = (__bf16)x; return c.u;
}
__device__ inline unsigned char f2fp8(float x){
    int p = __builtin_amdgcn_cvt_pk_fp8_f32(x, x, 0, false);
    return (unsigned char)(p & 0xff);
}
__device__ inline unsigned int pk4fp8(float a, float b, float c, float d){
    int w = 0;
    w = __builtin_amdgcn_cvt_pk_fp8_f32(a, b, w, false);
    w = __builtin_amdgcn_cvt_pk_fp8_f32(c, d, w, true);
    return (unsigned int)w;
}
__device__ __forceinline__ void unpk8(uint4 u, float* d){
    d[0]=bfbits2f(u.x&0xffffu); d[1]=bfbits2f(u.x>>16);
    d[2]=bfbits2f(u.y&0xffffu); d[3]=bfbits2f(u.y>>16);
    d[4]=bfbits2f(u.z&0xffffu); d[5]=bfbits2f(u.z>>16);
    d[6]=bfbits2f(u.w&0xffffu); d[7]=bfbits2f(u.w>>16);
}
__device__ __forceinline__ float gelu_fast(float x){
    float z = fminf(x*(1.5957691216f + 0.0713548162f*x*x), 30.f);
    float e = __expf(z);
    return x * e * __builtin_amdgcn_rcpf(e + 1.f);
}

__device__ __forceinline__ void gll16(const char* g, char* l){
    __builtin_amdgcn_global_load_lds(
        (const __attribute__((address_space(1))) unsigned int*)g,
        (__attribute__((address_space(3))) unsigned int*)l, 16, 0, 0);
}

// ---------------- weight prep ----------------
__global__ void prep_weights(const float* gconv, const float* tcl0, const float* tcl1,
                             const float* map_w, const float* proj_w,
                             const float* mlp_w1, const float* mlp_w2,
                             const float* qkv_w0, const float* qkv_w1,
                             const float* aproj_w0, const float* aproj_w1,
                             float* gct,
                             unsigned short* mapT, unsigned short* projT,
                             unsigned short* w1T, unsigned char* w2T8,
                             unsigned short* tclT0, unsigned short* tclT1,
                             unsigned short* qkvT, unsigned short* aprojT){
    int tid = blockIdx.x*blockDim.x + threadIdx.x;
    int stride = gridDim.x*blockDim.x;
    for (int i = tid; i < 8*48*48; i += stride){
        int g = i/(48*48); int r = i%(48*48); int u = r/48; int v = r%48;
        gct[i] = gconv[(g*48+v)*48+u];
    }
    for (int i = tid; i < 64*960; i += stride){
        int o = i/960, col = i%960, kh = col/192, c = col%192;
        tclT0[i] = f2bf(tcl0[(o*192+c)*5+kh]);
        tclT1[i] = f2bf(tcl1[(o*192+c)*5+kh]);
    }
    for (int i = tid; i < 65536; i += stride){
        int n = i>>8, k = i&255;
        mapT[i] = f2bf(map_w[k*256+n]);
        projT[i] = f2bf(proj_w[k*256+n]);
    }
    for (int i = tid; i < 262144; i += stride){
        int n = i>>8, k = i&255;
        w1T[i] = f2bf(mlp_w1[k*1024+n]);
    }
    // w2T8[n][k] = fp8(mlp_w2[k][n] * 32)
    for (int i = tid; i < 262144; i += stride){
        int n = i>>10, k = i&1023;
        w2T8[i] = f2fp8(mlp_w2[k*256+n] * 32.f);
    }
    for (int i = tid; i < 12288; i += stride){
        int n = i/64, k = i%64;
        qkvT[i]          = f2bf(qkv_w0[k*192+n]);
        qkvT[12288+i]    = f2bf(qkv_w1[k*192+n]);
        aprojT[i]        = f2bf(aproj_w0[k*192+n]);
        aprojT[12288+i]  = f2bf(aproj_w1[k*192+n]);
    }
}

// ---------------- LN1 + transpose -> A1 bf16 [N][256] + raw skip copy ----------------
__global__ __launch_bounds__(256) void xpose_ln1(const float* __restrict__ x,
        const float* __restrict__ g, const float* __restrict__ bb,
        unsigned short* __restrict__ A1, unsigned short* __restrict__ xskip){
    int bt = blockIdx.x; int b = bt/TT, t = bt%TT;
    __shared__ float X[48*257];
    __shared__ float S[4][48], SS[4][48], sm[48], sv[48];
    int tid = threadIdx.x;
    const float* xb = x + (size_t)b*256*3072 + (size_t)t*48;
    for (int it = 0; it < 12; it++){
        int idx = it*256 + tid;
        int c = idx/12, q = idx%12;
        float4 v = *(const float4*)(xb + (size_t)c*3072 + q*4);
        X[(q*4+0)*257 + c] = v.x;
        X[(q*4+1)*257 + c] = v.y;
        X[(q*4+2)*257 + c] = v.z;
        X[(q*4+3)*257 + c] = v.w;
    }
    __syncthreads();
    if (tid < 192){
        int v = tid % 48, w = tid / 48;
        float s = 0.f, ss = 0.f;
        for (int c = w*64; c < w*64+64; c++){
            float val = X[v*257 + c];
            s += val; ss += val*val;
        }
        S[w][v] = s; SS[w][v] = ss;
    }
    __syncthreads();
    if (tid < 48){
        float s = S[0][tid]+S[1][tid]+S[2][tid]+S[3][tid];
        float q = SS[0][tid]+SS[1][tid]+SS[2][tid]+SS[3][tid];
        float m = s*(1.f/256);
        sm[tid] = m; sv[tid] = rsqrtf(q*(1.f/256) - m*m + LNE);
    }
    __syncthreads();
    int nb = bt*48;
    for (int it = 0; it < 12; it++){
        int idx = it*256 + tid;
        int v = idx>>6, cq = idx&63;
        float m = sm[v], rs = sv[v];
        float4 g4 = *(const float4*)(g + cq*4);
        float4 b4 = *(const float4*)(bb + cq*4);
        float x0 = X[v*257 + cq*4+0], x1 = X[v*257 + cq*4+1];
        float x2 = X[v*257 + cq*4+2], x3 = X[v*257 + cq*4+3];
        ushort4 u;
        u.x = f2bf((x0-m)*rs*g4.x + b4.x);
        u.y = f2bf((x1-m)*rs*g4.y + b4.y);
        u.z = f2bf((x2-m)*rs*g4.z + b4.z);
        u.w = f2bf((x3-m)*rs*g4.w + b4.w);
        *(ushort4*)(A1 + (size_t)(nb+v)*256 + cq*4) = u;
        ushort4 s;
        s.x = f2bf(x0); s.y = f2bf(x1); s.z = f2bf(x2); s.w = f2bf(x3);
        *(ushort4*)(xskip + (size_t)(nb+v)*256 + cq*4) = s;
    }
}

// ---------------- swizzled staging (single-shot, for k64 GEMM) ----------------
__device__ __forceinline__ void stage_swz(const char* src, size_t rowbytes, char* lds,
                                          int nchunks, int tid){
    for (int c = tid; c < nchunks; c += 256){
        int p = c << 4;
        int r = p >> 7;
        int kl = (p & 127) ^ ((r & 7) << 4);
        gll16(src + (size_t)r*rowbytes + kl, lds + p);
    }
}

__device__ __forceinline__ bf16x8 frag_ld(const char* lds, int R, int kb){
    return *(const bf16x8*)(lds + R*128 + (kb ^ ((R & 7) << 4)));
}
__device__ __forceinline__ long frag_ld8(const char* lds, int R, int kb){
    return *(const long*)(lds + R*128 + (kb ^ ((R & 7) << 4)));
}

// ---------------- MFMA GEMM: BM=192, BN=128, 8 waves, dbuf + counted vmcnt ----------------
// EPI 2: outH8 = fp8(gelu(bf16(acc+bias)) * 4)  [bf16 LDS repack, packed cvt, 8B stores]
// EPI 4: outH  = bf16(acc + bias)               [LDS repack, 16B stores]
template<int KTOT, int EPI>
__global__ __launch_bounds__(512, 4) void mfma_gemm(
    const unsigned short* __restrict__ A, const unsigned short* __restrict__ BT,
    const float* __restrict__ bias,
    unsigned short* __restrict__ outH, unsigned char* __restrict__ outH8,
    int ncols, int nx){

    constexpr int BM = 192, BN = 128;
    constexpr int HALF = (BM+BN)*128;           // 40960
    __shared__ __align__(16) char smem[2*HALF]; // 81920 -> 2 blocks/CU
    int tid = threadIdx.x, lane = tid & 63;
    int wid = tid >> 6;
    int wm = wid >> 1, wn = wid & 1;
    int l15 = lane & 15, lq = lane >> 4;
    int bid = blockIdx.x;
    int per = gridDim.x >> 3;
    int wkid = (bid & 7)*per + (bid >> 3);
    int m0 = (wkid / nx) * BM, n0 = (wkid % nx) * BN;
    const size_t arb = KTOT*2, brb = KTOT*2;
    constexpr int KT = KTOT/64;

    const char* gA[3]; int loA[3];
    const char* gB[2]; int loB[2];
    {
        const char* Ab = (const char*)A + (size_t)m0*arb;
        const char* Bb = (const char*)BT + (size_t)n0*brb;
        #pragma unroll
        for (int i = 0; i < 3; i++){
            int c = tid + i*512;
            int p = c << 4, r = p >> 7;
            int kl = (p & 127) ^ ((r & 7) << 4);
            gA[i] = Ab + (size_t)r*arb + kl; loA[i] = p;
        }
        #pragma unroll
        for (int i = 0; i < 2; i++){
            int c = tid + i*512;
            int p = c << 4, r = p >> 7;
            int kl = (p & 127) ^ ((r & 7) << 4);
            gB[i] = Bb + (size_t)r*brb + kl; loB[i] = BM*128 + p;
        }
    }

    f32x4 acc[3][4];
    #pragma unroll
    for (int i = 0; i < 3; i++)
        #pragma unroll
        for (int j = 0; j < 4; j++){ f32x4 z = {0.f,0.f,0.f,0.f}; acc[i][j] = z; }

    #pragma unroll
    for (int i = 0; i < 3; i++) gll16(gA[i], smem + loA[i]);
    #pragma unroll
    for (int i = 0; i < 2; i++) gll16(gB[i], smem + loB[i]);

    int koff = 128;
    for (int kt = 0; kt < KT; kt++){
        char* cur = smem + (kt & 1)*HALF;
        if (kt + 1 < KT){
            char* nxt = smem + ((kt + 1) & 1)*HALF;
            #pragma unroll
            for (int i = 0; i < 3; i++) gll16(gA[i] + koff, nxt + loA[i]);
            #pragma unroll
            for (int i = 0; i < 2; i++) gll16(gB[i] + koff, nxt + loB[i]);
            koff += 128;
            asm volatile("s_waitcnt vmcnt(5)" ::: "memory");
        } else {
            asm volatile("s_waitcnt vmcnt(0)" ::: "memory");
        }
        __builtin_amdgcn_s_barrier();
        __builtin_amdgcn_sched_barrier(0);
        char* ldsA = cur;
        char* ldsB = cur + BM*128;
        #pragma unroll
        for (int ks = 0; ks < 2; ks++){
            bf16x8 a[3], b[4];
            int kb = ks*64 + lq*16;
            #pragma unroll
            for (int mf = 0; mf < 3; mf++) a[mf] = frag_ld(ldsA, wm*48 + mf*16 + l15, kb);
            #pragma unroll
            for (int nf = 0; nf < 4; nf++) b[nf] = frag_ld(ldsB, wn*64 + nf*16 + l15, kb);
            #pragma unroll
            for (int mf = 0; mf < 3; mf++)
                #pragma unroll
                for (int nf = 0; nf < 4; nf++)
                    acc[mf][nf] = __builtin_amdgcn_mfma_f32_16x16x32_bf16(a[mf], b[nf], acc[mf][nf], 0, 0, 0);
        }
        __builtin_amdgcn_sched_barrier(0);
        __builtin_amdgcn_s_barrier();
    }

    // shared epilogue part: pre-activation to bf16 LDS [192][136] (conflict-free)
    unsigned short* Hs = (unsigned short*)smem;
    #pragma unroll
    for (int nf = 0; nf < 4; nf++){
        int col = wn*64 + nf*16 + l15;
        float bb = bias[n0 + col];
        #pragma unroll
        for (int mf = 0; mf < 3; mf++){
            int row = wm*48 + mf*16 + lq*4;
            f32x4 v = acc[mf][nf];
            #pragma unroll
            for (int r = 0; r < 4; r++)
                Hs[(row+r)*136 + col] = f2bf(v[r] + bb);
        }
    }
    __syncthreads();
    if constexpr (EPI == 4){
        for (int idx = tid; idx < 192*16; idx += 512){
            int row = idx >> 4, c8 = idx & 15;
            *(uint4*)(outH + (size_t)(m0+row)*ncols + n0 + c8*8) =
                *(const uint4*)(Hs + row*136 + c8*8);
        }
    }
    if constexpr (EPI == 2){
        for (int idx = tid; idx < 192*16; idx += 512){
            int row = idx >> 4, c8 = idx & 15;
            uint4 hv = *(const uint4*)(Hs + row*136 + c8*8);
            float v[8]; unpk8(hv, v);
            #pragma unroll
            for (int j = 0; j < 8; j++) v[j] = gelu_fast(v[j]) * 4.f;
            uint2 o;
            o.x = pk4fp8(v[0], v[1], v[2], v[3]);
            o.y = pk4fp8(v[4], v[5], v[6], v[7]);
            *(uint2*)(outH8 + (size_t)(m0+row)*ncols + n0 + c8*8) = o;
        }
    }
}

// ---------------- final GEMM in fp8: K=1024 as 8 tiles of K=128 (128B rows) ----------------
// dout(NCHW) = acc/128 + bias + bf16 extraH(outtH), two-pass transposed store
__global__ __launch_bounds__(512, 4) void mfma_final_fp8(
    const unsigned char* __restrict__ A, const unsigned char* __restrict__ BT,
    const float* __restrict__ bias, const unsigned short* __restrict__ extraH,
    float* __restrict__ outF){

    constexpr int BM = 192, BN = 128, NX = 2;
    constexpr int HALF = (BM+BN)*128;           // 40960
    __shared__ __align__(16) char smem[2*HALF]; // 81920 -> 2 blocks/CU
    int tid = threadIdx.x, lane = tid & 63;
    int wid = tid >> 6;
    int wm = wid >> 1, wn = wid & 1;
    int l15 = lane & 15, lq = lane >> 4;
    int bid = blockIdx.x;
    int per = gridDim.x >> 3;
    int wkid = (bid & 7)*per + (bid >> 3);
    int m0 = (wkid / NX) * BM, n0 = (wkid % NX) * BN;
    const size_t arb = 1024, brb = 1024;
    constexpr int KT = 8;

    const char* gA[3]; int loA[3];
    const char* gB[2]; int loB[2];
    {
        const char* Ab = (const char*)A + (size_t)m0*arb;
        const char* Bb = (const char*)BT + (size_t)n0*brb;
        #pragma unroll
        for (int i = 0; i < 3; i++){
            int c = tid + i*512;
            int p = c << 4, r = p >> 7;
            int kl = (p & 127) ^ ((r & 7) << 4);
            gA[i] = Ab + (size_t)r*arb + kl; loA[i] = p;
        }
        #pragma unroll
        for (int i = 0; i < 2; i++){
            int c = tid + i*512;
            int p = c << 4, r = p >> 7;
            int kl = (p & 127) ^ ((r & 7) << 4);
            gB[i] = Bb + (size_t)r*brb + kl; loB[i] = BM*128 + p;
        }
    }

    f32x4 acc[3][4];
    #pragma unroll
    for (int i = 0; i < 3; i++)
        #pragma unroll
        for (int j = 0; j < 4; j++){ f32x4 z = {0.f,0.f,0.f,0.f}; acc[i][j] = z; }

    #pragma unroll
    for (int i = 0; i < 3; i++) gll16(gA[i], smem + loA[i]);
    #pragma unroll
    for (int i = 0; i < 2; i++) gll16(gB[i], smem + loB[i]);

    int koff = 128;
    for (int kt = 0; kt < KT; kt++){
        char* cur = smem + (kt & 1)*HALF;
        if (kt + 1 < KT){
            char* nxt = smem + ((kt + 1) & 1)*HALF;
            #pragma unroll
            for (int i = 0; i < 3; i++) gll16(gA[i] + koff, nxt + loA[i]);
            #pragma unroll
            for (int i = 0; i < 2; i++) gll16(gB[i] + koff, nxt + loB[i]);
            koff += 128;
            asm volatile("s_waitcnt vmcnt(5)" ::: "memory");
        } else {
            asm volatile("s_waitcnt vmcnt(0)" ::: "memory");
        }
        __builtin_amdgcn_s_barrier();
        __builtin_amdgcn_sched_barrier(0);
        char* ldsA = cur;
        char* ldsB = cur + BM*128;
        #pragma unroll
        for (int ks = 0; ks < 4; ks++){
            long a[3], b[4];
            int kb = ks*32 + lq*8;
            #pragma unroll
            for (int mf = 0; mf < 3; mf++) a[mf] = frag_ld8(ldsA, wm*48 + mf*16 + l15, kb);
            #pragma unroll
            for (int nf = 0; nf < 4; nf++) b[nf] = frag_ld8(ldsB, wn*64 + nf*16 + l15, kb);
            #pragma unroll
            for (int mf = 0; mf < 3; mf++)
                #pragma unroll
                for (int nf = 0; nf < 4; nf++)
                    acc[mf][nf] = __builtin_amdgcn_mfma_f32_16x16x32_fp8_fp8(a[mf], b[nf], acc[mf][nf], 0, 0, 0);
        }
        __builtin_amdgcn_sched_barrier(0);
        __builtin_amdgcn_s_barrier();
    }

    // epilogue: dout NCHW = acc/128 + bias + resid (bf16 outtH), two-pass transpose
    float* Tt = (float*)smem;  // [64 cols][196]
    #pragma unroll
    for (int ph = 0; ph < 2; ph++){
        __syncthreads();
        if (wn == ph){
            #pragma unroll
            for (int nf = 0; nf < 4; nf++){
                int lc = nf*16 + l15;
                float bb = bias[n0 + ph*64 + lc];
                #pragma unroll
                for (int mf = 0; mf < 3; mf++){
                    int tl = wm*48 + mf*16 + lq*4;
                    f32x4 v = acc[mf][nf];
                    #pragma unroll
                    for (int r = 0; r < 4; r++){
                        float resid = bfbits2f(extraH[(size_t)(m0+tl+r)*256 + n0 + ph*64 + lc]);
                        Tt[lc*196 + tl + r] = v[r]*0.0078125f + bb + resid;
                    }
                }
            }
        }
        __syncthreads();
        {
            int lc = tid & 63, btl = (tid>>6)&3, dup = tid>>8;
            int gtok = m0 + btl*48;
            int bg = gtok/3072, t = (gtok%3072)/48;
            float* dst = outF + ((size_t)(bg*256 + n0 + ph*64 + lc)*64 + t)*48 + dup*24;
            const float* tr = Tt + lc*196 + btl*48 + dup*24;
            #pragma unroll
            for (int j = 0; j < 6; j++)
                *(float4*)(dst + j*4) = *(const float4*)(tr + j*4);
        }
    }
}

// ---------------- proj GEMM fused with skip-add + LN2: BM=192, BN=256, K=256 ----------------
__global__ __launch_bounds__(512, 2) void proj_ln2(
    const unsigned short* __restrict__ A, const unsigned short* __restrict__ BT,
    const float* __restrict__ bias, const unsigned short* __restrict__ xskip,
    const float* __restrict__ n2g, const float* __restrict__ n2b,
    unsigned short* __restrict__ outtH, unsigned short* __restrict__ xn){

    constexpr int BM = 192, BN = 256, KTOT = 256;
    constexpr int HALF = (BM+BN)*128;
    __shared__ __align__(16) char smem[2*HALF];
    int tid = threadIdx.x, lane = tid & 63;
    int wid = tid >> 6;
    int wm = wid >> 1, wn = wid & 1;
    int l15 = lane & 15, lq = lane >> 4;
    int bid = blockIdx.x;
    int per = gridDim.x >> 3;
    int wkid = (bid & 7)*per + (bid >> 3);
    int m0 = wkid * BM;
    const size_t arb = KTOT*2, brb = KTOT*2;
    constexpr int KT = KTOT/64;

    const char* gA[3]; int loA[3];
    const char* gB[4]; int loB[4];
    {
        const char* Ab = (const char*)A + (size_t)m0*arb;
        const char* Bb = (const char*)BT;
        #pragma unroll
        for (int i = 0; i < 3; i++){
            int c = tid + i*512;
            int p = c << 4, r = p >> 7;
            int kl = (p & 127) ^ ((r & 7) << 4);
            gA[i] = Ab + (size_t)r*arb + kl; loA[i] = p;
        }
        #pragma unroll
        for (int i = 0; i < 4; i++){
            int c = tid + i*512;
            int p = c << 4, r = p >> 7;
            int kl = (p & 127) ^ ((r & 7) << 4);
            gB[i] = Bb + (size_t)r*brb + kl; loB[i] = BM*128 + p;
        }
    }

    f32x4 acc[3][8];
    #pragma unroll
    for (int i = 0; i < 3; i++)
        #pragma unroll
        for (int j = 0; j < 8; j++){ f32x4 z = {0.f,0.f,0.f,0.f}; acc[i][j] = z; }

    #pragma unroll
    for (int i = 0; i < 3; i++) gll16(gA[i], smem + loA[i]);
    #pragma unroll
    for (int i = 0; i < 4; i++) gll16(gB[i], smem + loB[i]);

    int koff = 128;
    for (int kt = 0; kt < KT; kt++){
        char* cur = smem + (kt & 1)*HALF;
        if (kt + 1 < KT){
            char* nxt = smem + ((kt + 1) & 1)*HALF;
            #pragma unroll
            for (int i = 0; i < 3; i++) gll16(gA[i] + koff, nxt + loA[i]);
            #pragma unroll
            for (int i = 0; i < 4; i++) gll16(gB[i] + koff, nxt + loB[i]);
            koff += 128;
            asm volatile("s_waitcnt vmcnt(7)" ::: "memory");
        } else {
            asm volatile("s_waitcnt vmcnt(0)" ::: "memory");
        }
        __builtin_amdgcn_s_barrier();
        __builtin_amdgcn_sched_barrier(0);
        char* ldsA = cur;
        char* ldsB = cur + BM*128;
        #pragma unroll
        for (int ks = 0; ks < 2; ks++){
            bf16x8 a[3], b[8];
            int kb = ks*64 + lq*16;
            #pragma unroll
            for (int mf = 0; mf < 3; mf++) a[mf] = frag_ld(ldsA, wm*48 + mf*16 + l15, kb);
            #pragma unroll
            for (int nf = 0; nf < 8; nf++) b[nf] = frag_ld(ldsB, wn*128 + nf*16 + l15, kb);
            #pragma unroll
            for (int mf = 0; mf < 3; mf++)
                #pragma unroll
                for (int nf = 0; nf < 8; nf++)
                    acc[mf][nf] = __builtin_amdgcn_mfma_f32_16x16x32_bf16(a[mf], b[nf], acc[mf][nf], 0, 0, 0);
        }
        __builtin_amdgcn_sched_barrier(0);
        __builtin_amdgcn_s_barrier();
    }

    unsigned short* Hs = (unsigned short*)smem;
    float* Sred = (float*)(smem + 101376);
    float s_acc[3][4], ss_acc[3][4];
    #pragma unroll
    for (int i = 0; i < 3; i++)
        #pragma unroll
        for (int r = 0; r < 4; r++){ s_acc[i][r] = 0.f; ss_acc[i][r] = 0.f; }

    #pragma unroll
    for (int nf = 0; nf < 8; nf++){
        int col = wn*128 + nf*16 + l15;
        float bb = bias[col];
        #pragma unroll
        for (int mf = 0; mf < 3; mf++){
            int row = wm*48 + mf*16 + lq*4;
            f32x4 v = acc[mf][nf];
            #pragma unroll
            for (int r = 0; r < 4; r++){
                float sk = bfbits2f(xskip[(size_t)(m0+row+r)*256 + col]);
                unsigned short us = f2bf(v[r] + bb + sk);
                Hs[(row+r)*264 + col] = us;
                float tf = bfbits2f(us);
                s_acc[mf][r] += tf; ss_acc[mf][r] += tf*tf;
            }
        }
    }
    #pragma unroll
    for (int mf = 0; mf < 3; mf++)
        #pragma unroll
        for (int r = 0; r < 4; r++){
            float s = s_acc[mf][r], ss = ss_acc[mf][r];
            #pragma unroll
            for (int d = 1; d < 16; d <<= 1){
                s  += __shfl_xor(s, d);
                ss += __shfl_xor(ss, d);
            }
            if (l15 == 0){
                int row = wm*48 + mf*16 + lq*4 + r;
                Sred[wn*192 + row] = s;
                Sred[384 + wn*192 + row] = ss;
            }
        }
    __syncthreads();
    if (tid < 192){
        float s  = Sred[tid] + Sred[192+tid];
        float ss = Sred[384+tid] + Sred[576+tid];
        float m = s*(1.f/256);
        Sred[tid] = m;
        Sred[192+tid] = rsqrtf(ss*(1.f/256) - m*m + LNE);
    }
    __syncthreads();
    for (int idx = tid; idx < 192*32; idx += 512){
        int row = idx >> 5, c8 = idx & 31;
        uint4 hv = *(const uint4*)(Hs + row*264 + c8*8);
        *(uint4*)(outtH + (size_t)(m0+row)*256 + c8*8) = hv;
        float v[8]; unpk8(hv, v);
        float m = Sred[row], rs = Sred[192+row];
        unsigned int w[4];
        #pragma unroll
        for (int j = 0; j < 4; j++){
            float g0 = n2g[c8*8 + j*2],   b0 = n2b[c8*8 + j*2];
            float g1 = n2g[c8*8 + j*2+1], b1 = n2b[c8*8 + j*2+1];
            unsigned int lo = f2bf((v[j*2]  -m)*rs*g0 + b0);
            unsigned int hi = f2bf((v[j*2+1]-m)*rs*g1 + b1);
            w[j] = lo | (hi << 16);
        }
        uint4 o; o.x=w[0]; o.y=w[1]; o.z=w[2]; o.w=w[3];
        *(uint4*)(xn + (size_t)(m0+row)*256 + c8*8) = o;
    }
}

// ---------------- K=64 MFMA GEMM: BM=96, BN=192, 4 waves ----------------
template<int EPI>
__global__ __launch_bounds__(256) void gemm_k64(
    const unsigned short* __restrict__ A, int arb,
    const unsigned short* __restrict__ BT,
    const float* __restrict__ bias,
    unsigned short* __restrict__ out){
    __shared__ __align__(16) char smem[96*128 + 192*128];
    char* ldsA = smem;
    char* ldsB = smem + 96*128;
    int tid = threadIdx.x, lane = tid & 63;
    int wid = tid >> 6, wm = wid >> 1, wn = wid & 1;
    int l15 = lane & 15, lq = lane >> 4;
    int m0 = blockIdx.x * 96;

    stage_swz((const char*)A + (size_t)m0*arb, arb, ldsA, 96*8, tid);
    stage_swz((const char*)BT, 128, ldsB, 192*8, tid);
    __syncthreads();

    f32x4 acc[3][6];
    #pragma unroll
    for (int i = 0; i < 3; i++)
        #pragma unroll
        for (int j = 0; j < 6; j++){ f32x4 z = {0.f,0.f,0.f,0.f}; acc[i][j] = z; }

    #pragma unroll
    for (int ks = 0; ks < 2; ks++){
        bf16x8 a[3], b[6];
        int kb = ks*64 + lq*16;
        #pragma unroll
        for (int mf = 0; mf < 3; mf++) a[mf] = frag_ld(ldsA, wm*48 + mf*16 + l15, kb);
        #pragma unroll
        for (int nf = 0; nf < 6; nf++) b[nf] = frag_ld(ldsB, wn*96 + nf*16 + l15, kb);
        #pragma unroll
        for (int mf = 0; mf < 3; mf++)
            #pragma unroll
            for (int nf = 0; nf < 6; nf++)
                acc[mf][nf] = __builtin_amdgcn_mfma_f32_16x16x32_bf16(a[mf], b[nf], acc[mf][nf], 0, 0, 0);
    }

    size_t row0;
    if constexpr (EPI == 0) row0 = (size_t)m0;
    else {
        int b = m0/3072;
        row0 = (size_t)b*PROWS + 192 + (m0 - b*3072);
    }
    #pragma unroll
    for (int nf = 0; nf < 6; nf++){
        int col = wn*96 + nf*16 + l15;
        float bb = bias[col];
        #pragma unroll
        for (int mf = 0; mf < 3; mf++){
            size_t rr = row0 + wm*48 + mf*16 + lq*4;
            f32x4 v = acc[mf][nf];
            #pragma unroll
            for (int r = 0; r < 4; r++)
                out[(rr+r)*192 + col] = f2bf(v[r] + bb);
        }
    }
}

// ---------------- windowed attention ----------------
__global__ __launch_bounds__(192) void attn_win(
        const unsigned short* __restrict__ qkvbuf,
        unsigned short* __restrict__ attnout){
    int win = blockIdx.x, br = blockIdx.y;
    size_t base = (size_t)br*NTOK + (size_t)win*48;
    __shared__ float Q[48*196];
    int tid = threadIdx.x;
    const unsigned short* src = qkvbuf + base*192;
    for (int i = 0; i < 6; i++){
        int ch = i*192 + tid;
        int v = ch/24, c8 = ch%24;
        uint4 u = *(const uint4*)(src + (size_t)v*192 + c8*8);
        unpk8(u, &Q[v*196 + c8*8]);
    }
    __syncthreads();
    int u = tid & 15, gh = tid >> 4, g = gh >> 2, h = gh & 3;
    int ru = g*16 + u;
    float qreg[16];
    #pragma unroll
    for (int d = 0; d < 16; d++) qreg[d] = Q[ru*196 + h*16 + d];
    float sc[16]; float mx = -1e30f;
    #pragma unroll
    for (int w = 0; w < 16; w++){
        float s = 0.f;
        #pragma unroll
        for (int d = 0; d < 16; d++) s += qreg[d]*Q[(g*16+w)*196 + 64 + h*16 + d];
        s *= 0.5f; sc[w] = s; mx = fmaxf(mx, s);
    }
    float sum = 0.f;
    #pragma unroll
    for (int w = 0; w < 16; w++){ sc[w] = __expf(sc[w]-mx); sum += sc[w]; }
    float inv = __builtin_amdgcn_rcpf(sum);
    unsigned int w32[8];
    #pragma unroll
    for (int dp = 0; dp < 8; dp++){
        float o0 = 0.f, o1 = 0.f;
        #pragma unroll
        for (int w = 0; w < 16; w++){
            float p = sc[w];
            o0 += p*Q[(g*16+w)*196 + 128 + h*16 + dp*2];
            o1 += p*Q[(g*16+w)*196 + 128 + h*16 + dp*2+1];
        }
        w32[dp] = (unsigned int)f2bf(o0*inv) | ((unsigned int)f2bf(o1*inv) << 16);
    }
    unsigned short* dst = attnout + (base + ru)*64 + h*16;
    uint4 q0; q0.x=w32[0]; q0.y=w32[1]; q0.z=w32[2]; q0.w=w32[3];
    uint4 q1; q1.x=w32[4]; q1.y=w32[5]; q1.z=w32[6]; q1.w=w32[7];
    *(uint4*)(dst)   = q0;
    *(uint4*)(dst+8) = q1;
}

// ---------------- tcl as MFMA GEMM: K=960 (15 tiles), dbuf + counted vmcnt ----------------
__global__ __launch_bounds__(256) void tcl_mfma(const unsigned short* __restrict__ A0p,
        const unsigned short* __restrict__ BT, const float* __restrict__ tb,
        unsigned short* __restrict__ ybf, int outoff){
    constexpr int HALF = (192+64)*128;
    __shared__ __align__(16) char smem[2*HALF];
    int tid = threadIdx.x, lane = tid & 63;
    int wid = tid >> 6;
    int l15 = lane & 15, lq = lane >> 4;
    int bid = blockIdx.x;
    int per = gridDim.x >> 3;
    int wkid = (bid & 7)*per + (bid >> 3);
    int m0 = wkid * 192;
    int b = m0 / 3072;
    long brow0 = (long)b*PROWS + 192 + (m0 - b*3072);

    const char* gA[6]; int loA[6];
    const char* gB[2]; int loB[2];
    {
        const char* Ab = (const char*)A0p + (brow0 - 192)*384;
        #pragma unroll
        for (int i = 0; i < 6; i++){
            int c = tid + i*256;
            int p = c << 4, r = p >> 7;
            int kl = (p & 127) ^ ((r & 7) << 4);
            gA[i] = Ab + (size_t)r*384 + kl; loA[i] = p;
        }
        #pragma unroll
        for (int i = 0; i < 2; i++){
            int c = tid + i*256;
            int p = c << 4, r = p >> 7;
            int kl = (p & 127) ^ ((r & 7) << 4);
            gB[i] = (const char*)BT + (size_t)r*1920 + kl; loB[i] = 192*128 + p;
        }
    }

    f32x4 acc[3][4];
    #pragma unroll
    for (int i = 0; i < 3; i++)
        #pragma unroll
        for (int j = 0; j < 4; j++){ f32x4 z = {0.f,0.f,0.f,0.f}; acc[i][j] = z; }

    #pragma unroll
    for (int i = 0; i < 6; i++) gll16(gA[i], smem + loA[i]);
    #pragma unroll
    for (int i = 0; i < 2; i++) gll16(gB[i], smem + loB[i]);

    long offA = 0; int kc3 = 0; int offB = 0;
    for (int kt = 0; kt < 15; kt++){
        char* cur = smem + (kt & 1)*HALF;
        if (kt + 1 < 15){
            char* nxt = smem + ((kt + 1) & 1)*HALF;
            if (kc3 == 2){ offA += 18432 - 256; kc3 = 0; }
            else         { offA += 128; kc3++; }
            offB += 128;
            #pragma unroll
            for (int i = 0; i < 6; i++) gll16(gA[i] + offA, nxt + loA[i]);
            #pragma unroll
            for (int i = 0; i < 2; i++) gll16(gB[i] + offB, nxt + loB[i]);
            asm volatile("s_waitcnt vmcnt(8)" ::: "memory");
        } else {
            asm volatile("s_waitcnt vmcnt(0)" ::: "memory");
        }
        __builtin_amdgcn_s_barrier();
        __builtin_amdgcn_sched_barrier(0);
        char* ldsA = cur;
        char* ldsB = cur + 192*128;
        #pragma unroll
        for (int ks = 0; ks < 2; ks++){
            bf16x8 a[3], bb[4];
            int kb = ks*64 + lq*16;
            #pragma unroll
            for (int mf = 0; mf < 3; mf++) a[mf] = frag_ld(ldsA, wid*48 + mf*16 + l15, kb);
            #pragma unroll
            for (int nf = 0; nf < 4; nf++) bb[nf] = frag_ld(ldsB, nf*16 + l15, kb);
            #pragma unroll
            for (int mf = 0; mf < 3; mf++)
                #pragma unroll
                for (int nf = 0; nf < 4; nf++)
                    acc[mf][nf] = __builtin_amdgcn_mfma_f32_16x16x32_bf16(a[mf], bb[nf], acc[mf][nf], 0, 0, 0);
        }
        __builtin_amdgcn_sched_barrier(0);
        __builtin_amdgcn_s_barrier();
    }
    #pragma unroll
    for (int nf = 0; nf < 4; nf++){
        int col = nf*16 + l15;
        float bb = tb[col];
        #pragma unroll
        for (int mf = 0; mf < 3; mf++){
            int tok = m0 + wid*48 + mf*16 + lq*4;
            f32x4 v = acc[mf][nf];
            #pragma unroll
            for (int r = 0; r < 4; r++)
                ybf[(size_t)(tok+r)*256 + outoff + col] = f2bf(v[r] + bb);
        }
    }
}

// ---------------- y0: grouped V-mix -> ybf cols 0..63 ----------------
__global__ __launch_bounds__(256) void y0_kernel(const unsigned short* __restrict__ fbf,
        const float* __restrict__ gct, unsigned short* __restrict__ ybf){
    int bt = blockIdx.x; int nb = bt*VV;
    __shared__ float X[48*68];
    for (int it = 0; it < 2; it++){
        int idx = it*256 + threadIdx.x;
        if (idx < 384){
            int v = idx >> 3, c8 = idx & 7;
            uint4 u = *(const uint4*)(fbf + (size_t)(nb+v)*256 + c8*8);
            unpk8(u, &X[v*68 + c8*8]);
        }
    }
    __syncthreads();
    int c = threadIdx.x % 64, vv = threadIdx.x / 64;
    int g = c >> 3;
    float acc[12] = {};
    for (int u = 0; u < 48; u++){
        float xv = X[u*68 + c];
        const float* gr = gct + (size_t)(g*48+u)*48 + vv*12;
        float4 g0 = *(const float4*)(gr);
        float4 g1 = *(const float4*)(gr+4);
        float4 g2 = *(const float4*)(gr+8);
        acc[0]+=xv*g0.x; acc[1]+=xv*g0.y; acc[2]+=xv*g0.z;  acc[3]+=xv*g0.w;
        acc[4]+=xv*g1.x; acc[5]+=xv*g1.y; acc[6]+=xv*g1.z;  acc[7]+=xv*g1.w;
        acc[8]+=xv*g2.x; acc[9]+=xv*g2.y; acc[10]+=xv*g2.z; acc[11]+=xv*g2.w;
    }
    #pragma unroll
    for (int j = 0; j < 12; j++)
        ybf[(size_t)(nb + vv*12 + j)*256 + c] = f2bf(acc[j]);
}

// ---------------- y1: grouped temporal conv (k=7) -> ybf cols 64..127 ----------------
__global__ __launch_bounds__(256) void y1_kernel(const unsigned short* __restrict__ fbf,
        const float* __restrict__ tw, const float* __restrict__ tb, unsigned short* __restrict__ ybf){
    int bt = blockIdx.x; int b = bt/TT, t = bt%TT;
    int o = threadIdx.x % 64, vv = threadIdx.x / 64;
    int g = o >> 3;
    float bv = tb[o];
    float acc[12];
    #pragma unroll
    for (int j = 0; j < 12; j++) acc[j] = bv;
    for (int kh = 0; kh < 7; kh++){
        int tt = t + kh - 3;
        if (tt < 0 || tt >= TT) continue;
        float wk[8];
        #pragma unroll
        for (int ci = 0; ci < 8; ci++) wk[ci] = tw[(o*8+ci)*7 + kh];
        int nb2 = (b*TT+tt)*VV;
        #pragma unroll
        for (int j = 0; j < 12; j++){
            uint4 u = *(const uint4*)(fbf + (size_t)(nb2 + vv*12 + j)*256 + 64 + g*8);
            float fv[8]; unpk8(u, fv);
            acc[j] += fv[0]*wk[0]+fv[1]*wk[1]+fv[2]*wk[2]+fv[3]*wk[3]
                    + fv[4]*wk[4]+fv[5]*wk[5]+fv[6]*wk[6]+fv[7]*wk[7];
        }
    }
    int nb = bt*VV;
    #pragma unroll
    for (int j = 0; j < 12; j++)
        ybf[(size_t)(nb + vv*12 + j)*256 + 64 + o] = f2bf(acc[j]);
}

extern "C" void kernel_launch(void* const* d_in, const int* in_sizes, int n_in,
                              void* d_out, int out_size, void* d_ws, size_t ws_size,
                              hipStream_t stream){
    const float* input   = (const float*)d_in[0];
    const float* n1g     = (const float*)d_in[1];
    const float* n1b     = (const float*)d_in[2];
    const float* map_w   = (const float*)d_in[3];
    const float* map_b   = (const float*)d_in[4];
    const float* gconv   = (const float*)d_in[5];
    const float* tconv_w = (const float*)d_in[6];
    const float* tconv_b = (const float*)d_in[7];
    const float* qkv_w0  = (const float*)d_in[8];
    const float* qkv_b0  = (const float*)d_in[9];
    const float* aproj_w0= (const float*)d_in[10];
    const float* aproj_b0= (const float*)d_in[11];
    const float* tcl_w0  = (const float*)d_in[12];
    const float* tcl_b0  = (const float*)d_in[13];
    const float* qkv_w1  = (const float*)d_in[14];
    const float* qkv_b1  = (const float*)d_in[15];
    const float* aproj_w1= (const float*)d_in[16];
    const float* aproj_b1= (const float*)d_in[17];
    const float* tcl_w1  = (const float*)d_in[18];
    const float* tcl_b1  = (const float*)d_in[19];
    const float* proj_w  = (const float*)d_in[20];
    const float* proj_b  = (const float*)d_in[21];
    const float* n2g     = (const float*)d_in[22];
    const float* n2b     = (const float*)d_in[23];
    const float* mlp_w1  = (const float*)d_in[24];
    const float* mlp_b1  = (const float*)d_in[25];
    const float* mlp_w2  = (const float*)d_in[26];
    const float* mlp_b2  = (const float*)d_in[27];

    const size_t Nt = NTOK;
    if (ws_size < 354050048ull) return;

    char* base = (char*)d_ws;
    unsigned short* outtH  = (unsigned short*)base;                  //  50 MB (bf16 outt)
    unsigned short* fbf    = (unsigned short*)(base + 100663296);    //  50 MB
    unsigned short* a0p    = (unsigned short*)(base + 150994944);    //  40 MB
    unsigned short* qkvbuf = (unsigned short*)(base + 191102976);    //  75 MB
    unsigned short* attnout= (unsigned short*)(base + 266600448);    //  25 MB
    unsigned short* A1     = (unsigned short*)(base + 301989888);    //  50 MB
    char* wp = base + 352321536;
    float* gct            = (float*)wp;
    unsigned short* mapT  = (unsigned short*)(wp + 73728);
    unsigned short* projT = mapT + 65536;
    unsigned short* w1T   = projT + 65536;
    unsigned char* w2T8   = (unsigned char*)(w1T + 262144);
    unsigned short* tclT0 = w1T + 262144 + 262144;   // w2T region reused as fp8
    unsigned short* tclT1 = tclT0 + 61440;
    unsigned short* qkvT  = tclT1 + 61440;
    unsigned short* aprojT= qkvT + 24576;

    unsigned char* h8   = (unsigned char*)fbf;   // fp8 Nt x 1024 = 100 MB, spans fbf+a0p+part of qkvbuf (dead)
    unsigned short* xn  = A1;
    unsigned short* ybf = (unsigned short*)d_out;
    unsigned short* xskip = ybf + (size_t)256*Nt;
    float* dout = (float*)d_out;

    prep_weights<<<256, 256, 0, stream>>>(gconv, tcl_w0, tcl_w1, map_w, proj_w, mlp_w1, mlp_w2,
                                          qkv_w0, qkv_w1, aproj_w0, aproj_w1,
                                          gct, mapT, projT, w1T, w2T8, tclT0, tclT1, qkvT, aprojT);
    xpose_ln1<<<NB*TT, 256, 0, stream>>>(input, n1g, n1b, A1, xskip);
    mfma_gemm<256,4><<<1024, 512, 0, stream>>>(A1, mapT, map_b, fbf, nullptr, 256, 2);
    hipMemsetAsync(a0p, 0, A0P_USH*sizeof(unsigned short), stream);
    gemm_k64<0><<<1024, 256, 0, stream>>>(fbf + 128, 512, qkvT,         qkv_b0, qkvbuf);
    gemm_k64<0><<<1024, 256, 0, stream>>>(fbf + 192, 512, qkvT + 12288, qkv_b1, qkvbuf + (size_t)Nt*192);
    attn_win<<<dim3(2048,2), 192, 0, stream>>>(qkvbuf, attnout);
    y0_kernel<<<NB*TT, 256, 0, stream>>>(fbf, gct, ybf);
    y1_kernel<<<NB*TT, 256, 0, stream>>>(fbf, tconv_w, tconv_b, ybf);
    gemm_k64<1><<<1024, 256, 0, stream>>>(attnout,                 128, aprojT,         aproj_b0, a0p);
    tcl_mfma<<<NTOK/192, 256, 0, stream>>>(a0p, tclT0, tcl_b0, ybf, 128);
    gemm_k64<1><<<1024, 256, 0, stream>>>(attnout + (size_t)Nt*64, 128, aprojT + 12288, aproj_b1, a0p);
    tcl_mfma<<<NTOK/192, 256, 0, stream>>>(a0p, tclT1, tcl_b1, ybf, 192);
    proj_ln2<<<512, 512, 0, stream>>>(ybf, projT, proj_b, xskip, n2g, n2b, outtH, xn);
    mfma_gemm<256,2><<<4096, 512, 0, stream>>>(xn, w1T, mlp_b1, nullptr, h8, 1024, 8);
    mfma_final_fp8<<<1024, 512, 0, stream>>>(h8, w2T8, mlp_b2, outtH, dout);
}

// Round 20
// 553.014 us; speedup vs baseline: 1.0059x; 1.0059x over previous
//
#include <hip/hip_runtime.h>
#include <hip/hip_bf16.h>
#include <math.h>

#define NB 32
#define CC 256
#define TT 64
#define VV 48
#define NTOK (NB*TT*VV)   // 98304
#define LNE 1e-5f
#define PROWS 3264        // (4+64)*48
#define A0P_USH ((size_t)NB*PROWS*192)

typedef __attribute__((ext_vector_type(8))) __bf16 bf16x8;
typedef __attribute__((ext_vector_type(4))) float f32x4;

__device__ inline float bfbits2f(unsigned int bits){
    union{unsigned int u; float f;} c; c.u = bits<<16; return c.f;
}
__device__ inline unsigned short f2bf(float x){
    union{ __bf16 h; unsigned short u; } c; c.h = (__bf16)x; return c.u;
}
__device__ inline unsigned char f2fp8(float x){
    int p = __builtin_amdgcn_cvt_pk_fp8_f32(x, x, 0, false);
    return (unsigned char)(p & 0xff);
}
__device__ __forceinline__ void unpk8(uint4 u, float* d){
    d[0]=bfbits2f(u.x&0xffffu); d[1]=bfbits2f(u.x>>16);
    d[2]=bfbits2f(u.y&0xffffu); d[3]=bfbits2f(u.y>>16);
    d[4]=bfbits2f(u.z&0xffffu); d[5]=bfbits2f(u.z>>16);
    d[6]=bfbits2f(u.w&0xffffu); d[7]=bfbits2f(u.w>>16);
}
__device__ __forceinline__ float gelu_fast(float x){
    float z = fminf(x*(1.5957691216f + 0.0713548162f*x*x), 30.f);
    float e = __expf(z);
    return x * e * __builtin_amdgcn_rcpf(e + 1.f);
}

__device__ __forceinline__ void gll16(const char* g, char* l){
    __builtin_amdgcn_global_load_lds(
        (const __attribute__((address_space(1))) unsigned int*)g,
        (__attribute__((address_space(3))) unsigned int*)l, 16, 0, 0);
}

// ---------------- weight prep ----------------
__global__ void prep_weights(const float* gconv, const float* tcl0, const float* tcl1,
                             const float* map_w, const float* proj_w,
                             const float* mlp_w1, const float* mlp_w2,
                             const float* qkv_w0, const float* qkv_w1,
                             const float* aproj_w0, const float* aproj_w1,
                             float* gct,
                             unsigned short* mapT, unsigned short* projT,
                             unsigned short* w1T, unsigned char* w2T8,
                             unsigned short* tclT0, unsigned short* tclT1,
                             unsigned short* qkvT, unsigned short* aprojT){
    int tid = blockIdx.x*blockDim.x + threadIdx.x;
    int stride = gridDim.x*blockDim.x;
    for (int i = tid; i < 8*48*48; i += stride){
        int g = i/(48*48); int r = i%(48*48); int u = r/48; int v = r%48;
        gct[i] = gconv[(g*48+v)*48+u];
    }
    for (int i = tid; i < 64*960; i += stride){
        int o = i/960, col = i%960, kh = col/192, c = col%192;
        tclT0[i] = f2bf(tcl0[(o*192+c)*5+kh]);
        tclT1[i] = f2bf(tcl1[(o*192+c)*5+kh]);
    }
    for (int i = tid; i < 65536; i += stride){
        int n = i>>8, k = i&255;
        mapT[i] = f2bf(map_w[k*256+n]);
        projT[i] = f2bf(proj_w[k*256+n]);
    }
    for (int i = tid; i < 262144; i += stride){
        int n = i>>8, k = i&255;
        w1T[i] = f2bf(mlp_w1[k*1024+n]);
    }
    // w2T8[n][k] = fp8(mlp_w2[k][n] * 32)
    for (int i = tid; i < 262144; i += stride){
        int n = i>>10, k = i&1023;
        w2T8[i] = f2fp8(mlp_w2[k*256+n] * 32.f);
    }
    for (int i = tid; i < 12288; i += stride){
        int n = i/64, k = i%64;
        qkvT[i]          = f2bf(qkv_w0[k*192+n]);
        qkvT[12288+i]    = f2bf(qkv_w1[k*192+n]);
        aprojT[i]        = f2bf(aproj_w0[k*192+n]);
        aprojT[12288+i]  = f2bf(aproj_w1[k*192+n]);
    }
}

// ---------------- LN1 + transpose -> A1 bf16 [N][256] + raw skip copy ----------------
__global__ __launch_bounds__(256) void xpose_ln1(const float* __restrict__ x,
        const float* __restrict__ g, const float* __restrict__ bb,
        unsigned short* __restrict__ A1, unsigned short* __restrict__ xskip){
    int bt = blockIdx.x; int b = bt/TT, t = bt%TT;
    __shared__ float X[48*257];
    __shared__ float S[4][48], SS[4][48], sm[48], sv[48];
    int tid = threadIdx.x;
    const float* xb = x + (size_t)b*256*3072 + (size_t)t*48;
    for (int it = 0; it < 12; it++){
        int idx = it*256 + tid;
        int c = idx/12, q = idx%12;
        float4 v = *(const float4*)(xb + (size_t)c*3072 + q*4);
        X[(q*4+0)*257 + c] = v.x;
        X[(q*4+1)*257 + c] = v.y;
        X[(q*4+2)*257 + c] = v.z;
        X[(q*4+3)*257 + c] = v.w;
    }
    __syncthreads();
    if (tid < 192){
        int v = tid % 48, w = tid / 48;
        float s = 0.f, ss = 0.f;
        for (int c = w*64; c < w*64+64; c++){
            float val = X[v*257 + c];
            s += val; ss += val*val;
        }
        S[w][v] = s; SS[w][v] = ss;
    }
    __syncthreads();
    if (tid < 48){
        float s = S[0][tid]+S[1][tid]+S[2][tid]+S[3][tid];
        float q = SS[0][tid]+SS[1][tid]+SS[2][tid]+SS[3][tid];
        float m = s*(1.f/256);
        sm[tid] = m; sv[tid] = rsqrtf(q*(1.f/256) - m*m + LNE);
    }
    __syncthreads();
    int nb = bt*48;
    for (int it = 0; it < 12; it++){
        int idx = it*256 + tid;
        int v = idx>>6, cq = idx&63;
        float m = sm[v], rs = sv[v];
        float4 g4 = *(const float4*)(g + cq*4);
        float4 b4 = *(const float4*)(bb + cq*4);
        float x0 = X[v*257 + cq*4+0], x1 = X[v*257 + cq*4+1];
        float x2 = X[v*257 + cq*4+2], x3 = X[v*257 + cq*4+3];
        ushort4 u;
        u.x = f2bf((x0-m)*rs*g4.x + b4.x);
        u.y = f2bf((x1-m)*rs*g4.y + b4.y);
        u.z = f2bf((x2-m)*rs*g4.z + b4.z);
        u.w = f2bf((x3-m)*rs*g4.w + b4.w);
        *(ushort4*)(A1 + (size_t)(nb+v)*256 + cq*4) = u;
        ushort4 s;
        s.x = f2bf(x0); s.y = f2bf(x1); s.z = f2bf(x2); s.w = f2bf(x3);
        *(ushort4*)(xskip + (size_t)(nb+v)*256 + cq*4) = s;
    }
}

// ---------------- swizzled staging (single-shot, for k64 GEMM) ----------------
__device__ __forceinline__ void stage_swz(const char* src, size_t rowbytes, char* lds,
                                          int nchunks, int tid){
    for (int c = tid; c < nchunks; c += 256){
        int p = c << 4;
        int r = p >> 7;
        int kl = (p & 127) ^ ((r & 7) << 4);
        gll16(src + (size_t)r*rowbytes + kl, lds + p);
    }
}

__device__ __forceinline__ bf16x8 frag_ld(const char* lds, int R, int kb){
    return *(const bf16x8*)(lds + R*128 + (kb ^ ((R & 7) << 4)));
}
__device__ __forceinline__ long frag_ld8(const char* lds, int R, int kb){
    return *(const long*)(lds + R*128 + (kb ^ ((R & 7) << 4)));
}

// ---------------- MFMA GEMM: BM=192, BN=128, 8 waves, dbuf + counted vmcnt ----------------
// EPI 2: outH8 = fp8(gelu(acc + bias) * 4)   [LDS repack, 16B stores]
// EPI 4: outH  = bf16(acc + bias)            [LDS repack, 16B stores]
template<int KTOT, int EPI>
__global__ __launch_bounds__(512, 4) void mfma_gemm(
    const unsigned short* __restrict__ A, const unsigned short* __restrict__ BT,
    const float* __restrict__ bias,
    unsigned short* __restrict__ outH, unsigned char* __restrict__ outH8,
    int ncols, int nx){

    constexpr int BM = 192, BN = 128;
    constexpr int HALF = (BM+BN)*128;           // 40960
    __shared__ __align__(16) char smem[2*HALF]; // 81920 -> 2 blocks/CU
    int tid = threadIdx.x, lane = tid & 63;
    int wid = tid >> 6;
    int wm = wid >> 1, wn = wid & 1;
    int l15 = lane & 15, lq = lane >> 4;
    int bid = blockIdx.x;
    int per = gridDim.x >> 3;
    int wkid = (bid & 7)*per + (bid >> 3);
    int m0 = (wkid / nx) * BM, n0 = (wkid % nx) * BN;
    const size_t arb = KTOT*2, brb = KTOT*2;
    constexpr int KT = KTOT/64;

    const char* gA[3]; int loA[3];
    const char* gB[2]; int loB[2];
    {
        const char* Ab = (const char*)A + (size_t)m0*arb;
        const char* Bb = (const char*)BT + (size_t)n0*brb;
        #pragma unroll
        for (int i = 0; i < 3; i++){
            int c = tid + i*512;
            int p = c << 4, r = p >> 7;
            int kl = (p & 127) ^ ((r & 7) << 4);
            gA[i] = Ab + (size_t)r*arb + kl; loA[i] = p;
        }
        #pragma unroll
        for (int i = 0; i < 2; i++){
            int c = tid + i*512;
            int p = c << 4, r = p >> 7;
            int kl = (p & 127) ^ ((r & 7) << 4);
            gB[i] = Bb + (size_t)r*brb + kl; loB[i] = BM*128 + p;
        }
    }

    f32x4 acc[3][4];
    #pragma unroll
    for (int i = 0; i < 3; i++)
        #pragma unroll
        for (int j = 0; j < 4; j++){ f32x4 z = {0.f,0.f,0.f,0.f}; acc[i][j] = z; }

    #pragma unroll
    for (int i = 0; i < 3; i++) gll16(gA[i], smem + loA[i]);
    #pragma unroll
    for (int i = 0; i < 2; i++) gll16(gB[i], smem + loB[i]);

    int koff = 128;
    for (int kt = 0; kt < KT; kt++){
        char* cur = smem + (kt & 1)*HALF;
        if (kt + 1 < KT){
            char* nxt = smem + ((kt + 1) & 1)*HALF;
            #pragma unroll
            for (int i = 0; i < 3; i++) gll16(gA[i] + koff, nxt + loA[i]);
            #pragma unroll
            for (int i = 0; i < 2; i++) gll16(gB[i] + koff, nxt + loB[i]);
            koff += 128;
            asm volatile("s_waitcnt vmcnt(5)" ::: "memory");
        } else {
            asm volatile("s_waitcnt vmcnt(0)" ::: "memory");
        }
        __builtin_amdgcn_s_barrier();
        __builtin_amdgcn_sched_barrier(0);
        char* ldsA = cur;
        char* ldsB = cur + BM*128;
        #pragma unroll
        for (int ks = 0; ks < 2; ks++){
            bf16x8 a[3], b[4];
            int kb = ks*64 + lq*16;
            #pragma unroll
            for (int mf = 0; mf < 3; mf++) a[mf] = frag_ld(ldsA, wm*48 + mf*16 + l15, kb);
            #pragma unroll
            for (int nf = 0; nf < 4; nf++) b[nf] = frag_ld(ldsB, wn*64 + nf*16 + l15, kb);
            #pragma unroll
            for (int mf = 0; mf < 3; mf++)
                #pragma unroll
                for (int nf = 0; nf < 4; nf++)
                    acc[mf][nf] = __builtin_amdgcn_mfma_f32_16x16x32_bf16(a[mf], b[nf], acc[mf][nf], 0, 0, 0);
        }
        __builtin_amdgcn_sched_barrier(0);
        __builtin_amdgcn_s_barrier();
    }

    if constexpr (EPI == 4){
        unsigned short* Hs = (unsigned short*)smem;   // [192][136]
        #pragma unroll
        for (int nf = 0; nf < 4; nf++){
            int col = wn*64 + nf*16 + l15;
            float bb = bias[n0 + col];
            #pragma unroll
            for (int mf = 0; mf < 3; mf++){
                int row = wm*48 + mf*16 + lq*4;
                f32x4 v = acc[mf][nf];
                #pragma unroll
                for (int r = 0; r < 4; r++)
                    Hs[(row+r)*136 + col] = f2bf(v[r] + bb);
            }
        }
        __syncthreads();
        for (int idx = tid; idx < 192*16; idx += 512){
            int row = idx >> 4, c8 = idx & 15;
            *(uint4*)(outH + (size_t)(m0+row)*ncols + n0 + c8*8) =
                *(const uint4*)(Hs + row*136 + c8*8);
        }
    }
    if constexpr (EPI == 2){
        unsigned char* Hc = (unsigned char*)smem;     // [192][144] fp8
        #pragma unroll
        for (int nf = 0; nf < 4; nf++){
            int col = wn*64 + nf*16 + l15;
            float bb = bias[n0 + col];
            #pragma unroll
            for (int mf = 0; mf < 3; mf++){
                int row = wm*48 + mf*16 + lq*4;
                f32x4 v = acc[mf][nf];
                #pragma unroll
                for (int r = 0; r < 4; r++){
                    float t0 = gelu_fast(v[r] + bb) * 4.f;
                    Hc[(row+r)*144 + col] = f2fp8(t0);
                }
            }
        }
        __syncthreads();
        for (int idx = tid; idx < 192*8; idx += 512){
            int row = idx >> 3, c16 = idx & 7;
            *(uint4*)(outH8 + (size_t)(m0+row)*ncols + n0 + c16*16) =
                *(const uint4*)(Hc + row*144 + c16*16);
        }
    }
}

// ---------------- final GEMM in fp8: K=1024 as 8 tiles of K=128 (128B rows) ----------------
// dout(NCHW) = acc/128 + bias + bf16 extraH(outtH), two-pass transposed store
__global__ __launch_bounds__(512, 4) void mfma_final_fp8(
    const unsigned char* __restrict__ A, const unsigned char* __restrict__ BT,
    const float* __restrict__ bias, const unsigned short* __restrict__ extraH,
    float* __restrict__ outF){

    constexpr int BM = 192, BN = 128, NX = 2;
    constexpr int HALF = (BM+BN)*128;           // 40960
    __shared__ __align__(16) char smem[2*HALF]; // 81920 -> 2 blocks/CU
    int tid = threadIdx.x, lane = tid & 63;
    int wid = tid >> 6;
    int wm = wid >> 1, wn = wid & 1;
    int l15 = lane & 15, lq = lane >> 4;
    int bid = blockIdx.x;
    int per = gridDim.x >> 3;
    int wkid = (bid & 7)*per + (bid >> 3);
    int m0 = (wkid / NX) * BM, n0 = (wkid % NX) * BN;
    const size_t arb = 1024, brb = 1024;
    constexpr int KT = 8;

    const char* gA[3]; int loA[3];
    const char* gB[2]; int loB[2];
    {
        const char* Ab = (const char*)A + (size_t)m0*arb;
        const char* Bb = (const char*)BT + (size_t)n0*brb;
        #pragma unroll
        for (int i = 0; i < 3; i++){
            int c = tid + i*512;
            int p = c << 4, r = p >> 7;
            int kl = (p & 127) ^ ((r & 7) << 4);
            gA[i] = Ab + (size_t)r*arb + kl; loA[i] = p;
        }
        #pragma unroll
        for (int i = 0; i < 2; i++){
            int c = tid + i*512;
            int p = c << 4, r = p >> 7;
            int kl = (p & 127) ^ ((r & 7) << 4);
            gB[i] = Bb + (size_t)r*brb + kl; loB[i] = BM*128 + p;
        }
    }

    f32x4 acc[3][4];
    #pragma unroll
    for (int i = 0; i < 3; i++)
        #pragma unroll
        for (int j = 0; j < 4; j++){ f32x4 z = {0.f,0.f,0.f,0.f}; acc[i][j] = z; }

    #pragma unroll
    for (int i = 0; i < 3; i++) gll16(gA[i], smem + loA[i]);
    #pragma unroll
    for (int i = 0; i < 2; i++) gll16(gB[i], smem + loB[i]);

    int koff = 128;
    for (int kt = 0; kt < KT; kt++){
        char* cur = smem + (kt & 1)*HALF;
        if (kt + 1 < KT){
            char* nxt = smem + ((kt + 1) & 1)*HALF;
            #pragma unroll
            for (int i = 0; i < 3; i++) gll16(gA[i] + koff, nxt + loA[i]);
            #pragma unroll
            for (int i = 0; i < 2; i++) gll16(gB[i] + koff, nxt + loB[i]);
            koff += 128;
            asm volatile("s_waitcnt vmcnt(5)" ::: "memory");
        } else {
            asm volatile("s_waitcnt vmcnt(0)" ::: "memory");
        }
        __builtin_amdgcn_s_barrier();
        __builtin_amdgcn_sched_barrier(0);
        char* ldsA = cur;
        char* ldsB = cur + BM*128;
        #pragma unroll
        for (int ks = 0; ks < 4; ks++){
            long a[3], b[4];
            int kb = ks*32 + lq*8;
            #pragma unroll
            for (int mf = 0; mf < 3; mf++) a[mf] = frag_ld8(ldsA, wm*48 + mf*16 + l15, kb);
            #pragma unroll
            for (int nf = 0; nf < 4; nf++) b[nf] = frag_ld8(ldsB, wn*64 + nf*16 + l15, kb);
            #pragma unroll
            for (int mf = 0; mf < 3; mf++)
                #pragma unroll
                for (int nf = 0; nf < 4; nf++)
                    acc[mf][nf] = __builtin_amdgcn_mfma_f32_16x16x32_fp8_fp8(a[mf], b[nf], acc[mf][nf], 0, 0, 0);
        }
        __builtin_amdgcn_sched_barrier(0);
        __builtin_amdgcn_s_barrier();
    }

    // epilogue: dout NCHW = acc/128 + bias + resid (bf16 outtH), two-pass transpose
    float* Tt = (float*)smem;  // [64 cols][196]
    #pragma unroll
    for (int ph = 0; ph < 2; ph++){
        __syncthreads();
        if (wn == ph){
            #pragma unroll
            for (int nf = 0; nf < 4; nf++){
                int lc = nf*16 + l15;
                float bb = bias[n0 + ph*64 + lc];
                #pragma unroll
                for (int mf = 0; mf < 3; mf++){
                    int tl = wm*48 + mf*16 + lq*4;
                    f32x4 v = acc[mf][nf];
                    #pragma unroll
                    for (int r = 0; r < 4; r++){
                        float resid = bfbits2f(extraH[(size_t)(m0+tl+r)*256 + n0 + ph*64 + lc]);
                        Tt[lc*196 + tl + r] = v[r]*0.0078125f + bb + resid;
                    }
                }
            }
        }
        __syncthreads();
        {
            int lc = tid & 63, btl = (tid>>6)&3, dup = tid>>8;
            int gtok = m0 + btl*48;
            int bg = gtok/3072, t = (gtok%3072)/48;
            float* dst = outF + ((size_t)(bg*256 + n0 + ph*64 + lc)*64 + t)*48 + dup*24;
            const float* tr = Tt + lc*196 + btl*48 + dup*24;
            #pragma unroll
            for (int j = 0; j < 6; j++)
                *(float4*)(dst + j*4) = *(const float4*)(tr + j*4);
        }
    }
}

// ---------------- proj GEMM fused with skip-add + LN2: BM=192, BN=256, K=256 ----------------
__global__ __launch_bounds__(512, 2) void proj_ln2(
    const unsigned short* __restrict__ A, const unsigned short* __restrict__ BT,
    const float* __restrict__ bias, const unsigned short* __restrict__ xskip,
    const float* __restrict__ n2g, const float* __restrict__ n2b,
    unsigned short* __restrict__ outtH, unsigned short* __restrict__ xn){

    constexpr int BM = 192, BN = 256, KTOT = 256;
    constexpr int HALF = (BM+BN)*128;
    __shared__ __align__(16) char smem[2*HALF];
    int tid = threadIdx.x, lane = tid & 63;
    int wid = tid >> 6;
    int wm = wid >> 1, wn = wid & 1;
    int l15 = lane & 15, lq = lane >> 4;
    int bid = blockIdx.x;
    int per = gridDim.x >> 3;
    int wkid = (bid & 7)*per + (bid >> 3);
    int m0 = wkid * BM;
    const size_t arb = KTOT*2, brb = KTOT*2;
    constexpr int KT = KTOT/64;

    const char* gA[3]; int loA[3];
    const char* gB[4]; int loB[4];
    {
        const char* Ab = (const char*)A + (size_t)m0*arb;
        const char* Bb = (const char*)BT;
        #pragma unroll
        for (int i = 0; i < 3; i++){
            int c = tid + i*512;
            int p = c << 4, r = p >> 7;
            int kl = (p & 127) ^ ((r & 7) << 4);
            gA[i] = Ab + (size_t)r*arb + kl; loA[i] = p;
        }
        #pragma unroll
        for (int i = 0; i < 4; i++){
            int c = tid + i*512;
            int p = c << 4, r = p >> 7;
            int kl = (p & 127) ^ ((r & 7) << 4);
            gB[i] = Bb + (size_t)r*brb + kl; loB[i] = BM*128 + p;
        }
    }

    f32x4 acc[3][8];
    #pragma unroll
    for (int i = 0; i < 3; i++)
        #pragma unroll
        for (int j = 0; j < 8; j++){ f32x4 z = {0.f,0.f,0.f,0.f}; acc[i][j] = z; }

    #pragma unroll
    for (int i = 0; i < 3; i++) gll16(gA[i], smem + loA[i]);
    #pragma unroll
    for (int i = 0; i < 4; i++) gll16(gB[i], smem + loB[i]);

    int koff = 128;
    for (int kt = 0; kt < KT; kt++){
        char* cur = smem + (kt & 1)*HALF;
        if (kt + 1 < KT){
            char* nxt = smem + ((kt + 1) & 1)*HALF;
            #pragma unroll
            for (int i = 0; i < 3; i++) gll16(gA[i] + koff, nxt + loA[i]);
            #pragma unroll
            for (int i = 0; i < 4; i++) gll16(gB[i] + koff, nxt + loB[i]);
            koff += 128;
            asm volatile("s_waitcnt vmcnt(7)" ::: "memory");
        } else {
            asm volatile("s_waitcnt vmcnt(0)" ::: "memory");
        }
        __builtin_amdgcn_s_barrier();
        __builtin_amdgcn_sched_barrier(0);
        char* ldsA = cur;
        char* ldsB = cur + BM*128;
        #pragma unroll
        for (int ks = 0; ks < 2; ks++){
            bf16x8 a[3], b[8];
            int kb = ks*64 + lq*16;
            #pragma unroll
            for (int mf = 0; mf < 3; mf++) a[mf] = frag_ld(ldsA, wm*48 + mf*16 + l15, kb);
            #pragma unroll
            for (int nf = 0; nf < 8; nf++) b[nf] = frag_ld(ldsB, wn*128 + nf*16 + l15, kb);
            #pragma unroll
            for (int mf = 0; mf < 3; mf++)
                #pragma unroll
                for (int nf = 0; nf < 8; nf++)
                    acc[mf][nf] = __builtin_amdgcn_mfma_f32_16x16x32_bf16(a[mf], b[nf], acc[mf][nf], 0, 0, 0);
        }
        __builtin_amdgcn_sched_barrier(0);
        __builtin_amdgcn_s_barrier();
    }

    unsigned short* Hs = (unsigned short*)smem;
    float* Sred = (float*)(smem + 101376);
    float s_acc[3][4], ss_acc[3][4];
    #pragma unroll
    for (int i = 0; i < 3; i++)
        #pragma unroll
        for (int r = 0; r < 4; r++){ s_acc[i][r] = 0.f; ss_acc[i][r] = 0.f; }

    #pragma unroll
    for (int nf = 0; nf < 8; nf++){
        int col = wn*128 + nf*16 + l15;
        float bb = bias[col];
        #pragma unroll
        for (int mf = 0; mf < 3; mf++){
            int row = wm*48 + mf*16 + lq*4;
            f32x4 v = acc[mf][nf];
            #pragma unroll
            for (int r = 0; r < 4; r++){
                float sk = bfbits2f(xskip[(size_t)(m0+row+r)*256 + col]);
                unsigned short us = f2bf(v[r] + bb + sk);
                Hs[(row+r)*264 + col] = us;
                float tf = bfbits2f(us);
                s_acc[mf][r] += tf; ss_acc[mf][r] += tf*tf;
            }
        }
    }
    #pragma unroll
    for (int mf = 0; mf < 3; mf++)
        #pragma unroll
        for (int r = 0; r < 4; r++){
            float s = s_acc[mf][r], ss = ss_acc[mf][r];
            #pragma unroll
            for (int d = 1; d < 16; d <<= 1){
                s  += __shfl_xor(s, d);
                ss += __shfl_xor(ss, d);
            }
            if (l15 == 0){
                int row = wm*48 + mf*16 + lq*4 + r;
                Sred[wn*192 + row] = s;
                Sred[384 + wn*192 + row] = ss;
            }
        }
    __syncthreads();
    if (tid < 192){
        float s  = Sred[tid] + Sred[192+tid];
        float ss = Sred[384+tid] + Sred[576+tid];
        float m = s*(1.f/256);
        Sred[tid] = m;
        Sred[192+tid] = rsqrtf(ss*(1.f/256) - m*m + LNE);
    }
    __syncthreads();
    for (int idx = tid; idx < 192*32; idx += 512){
        int row = idx >> 5, c8 = idx & 31;
        uint4 hv = *(const uint4*)(Hs + row*264 + c8*8);
        *(uint4*)(outtH + (size_t)(m0+row)*256 + c8*8) = hv;
        float v[8]; unpk8(hv, v);
        float m = Sred[row], rs = Sred[192+row];
        unsigned int w[4];
        #pragma unroll
        for (int j = 0; j < 4; j++){
            float g0 = n2g[c8*8 + j*2],   b0 = n2b[c8*8 + j*2];
            float g1 = n2g[c8*8 + j*2+1], b1 = n2b[c8*8 + j*2+1];
            unsigned int lo = f2bf((v[j*2]  -m)*rs*g0 + b0);
            unsigned int hi = f2bf((v[j*2+1]-m)*rs*g1 + b1);
            w[j] = lo | (hi << 16);
        }
        uint4 o; o.x=w[0]; o.y=w[1]; o.z=w[2]; o.w=w[3];
        *(uint4*)(xn + (size_t)(m0+row)*256 + c8*8) = o;
    }
}

// ---------------- K=64 MFMA GEMM: BM=96, BN=192, 4 waves ----------------
template<int EPI>
__global__ __launch_bounds__(256) void gemm_k64(
    const unsigned short* __restrict__ A, int arb,
    const unsigned short* __restrict__ BT,
    const float* __restrict__ bias,
    unsigned short* __restrict__ out){
    __shared__ __align__(16) char smem[96*128 + 192*128];
    char* ldsA = smem;
    char* ldsB = smem + 96*128;
    int tid = threadIdx.x, lane = tid & 63;
    int wid = tid >> 6, wm = wid >> 1, wn = wid & 1;
    int l15 = lane & 15, lq = lane >> 4;
    int m0 = blockIdx.x * 96;

    stage_swz((const char*)A + (size_t)m0*arb, arb, ldsA, 96*8, tid);
    stage_swz((const char*)BT, 128, ldsB, 192*8, tid);
    __syncthreads();

    f32x4 acc[3][6];
    #pragma unroll
    for (int i = 0; i < 3; i++)
        #pragma unroll
        for (int j = 0; j < 6; j++){ f32x4 z = {0.f,0.f,0.f,0.f}; acc[i][j] = z; }

    #pragma unroll
    for (int ks = 0; ks < 2; ks++){
        bf16x8 a[3], b[6];
        int kb = ks*64 + lq*16;
        #pragma unroll
        for (int mf = 0; mf < 3; mf++) a[mf] = frag_ld(ldsA, wm*48 + mf*16 + l15, kb);
        #pragma unroll
        for (int nf = 0; nf < 6; nf++) b[nf] = frag_ld(ldsB, wn*96 + nf*16 + l15, kb);
        #pragma unroll
        for (int mf = 0; mf < 3; mf++)
            #pragma unroll
            for (int nf = 0; nf < 6; nf++)
                acc[mf][nf] = __builtin_amdgcn_mfma_f32_16x16x32_bf16(a[mf], b[nf], acc[mf][nf], 0, 0, 0);
    }

    size_t row0;
    if constexpr (EPI == 0) row0 = (size_t)m0;
    else {
        int b = m0/3072;
        row0 = (size_t)b*PROWS + 192 + (m0 - b*3072);
    }
    #pragma unroll
    for (int nf = 0; nf < 6; nf++){
        int col = wn*96 + nf*16 + l15;
        float bb = bias[col];
        #pragma unroll
        for (int mf = 0; mf < 3; mf++){
            size_t rr = row0 + wm*48 + mf*16 + lq*4;
            f32x4 v = acc[mf][nf];
            #pragma unroll
            for (int r = 0; r < 4; r++)
                out[(rr+r)*192 + col] = f2bf(v[r] + bb);
        }
    }
}

// ---------------- windowed attention ----------------
__global__ __launch_bounds__(192) void attn_win(
        const unsigned short* __restrict__ qkvbuf,
        unsigned short* __restrict__ attnout){
    int win = blockIdx.x, br = blockIdx.y;
    size_t base = (size_t)br*NTOK + (size_t)win*48;
    __shared__ float Q[48*196];
    int tid = threadIdx.x;
    const unsigned short* src = qkvbuf + base*192;
    for (int i = 0; i < 6; i++){
        int ch = i*192 + tid;
        int v = ch/24, c8 = ch%24;
        uint4 u = *(const uint4*)(src + (size_t)v*192 + c8*8);
        unpk8(u, &Q[v*196 + c8*8]);
    }
    __syncthreads();
    int u = tid & 15, gh = tid >> 4, g = gh >> 2, h = gh & 3;
    int ru = g*16 + u;
    float qreg[16];
    #pragma unroll
    for (int d = 0; d < 16; d++) qreg[d] = Q[ru*196 + h*16 + d];
    float sc[16]; float mx = -1e30f;
    #pragma unroll
    for (int w = 0; w < 16; w++){
        float s = 0.f;
        #pragma unroll
        for (int d = 0; d < 16; d++) s += qreg[d]*Q[(g*16+w)*196 + 64 + h*16 + d];
        s *= 0.5f; sc[w] = s; mx = fmaxf(mx, s);
    }
    float sum = 0.f;
    #pragma unroll
    for (int w = 0; w < 16; w++){ sc[w] = __expf(sc[w]-mx); sum += sc[w]; }
    float inv = __builtin_amdgcn_rcpf(sum);
    unsigned int w32[8];
    #pragma unroll
    for (int dp = 0; dp < 8; dp++){
        float o0 = 0.f, o1 = 0.f;
        #pragma unroll
        for (int w = 0; w < 16; w++){
            float p = sc[w];
            o0 += p*Q[(g*16+w)*196 + 128 + h*16 + dp*2];
            o1 += p*Q[(g*16+w)*196 + 128 + h*16 + dp*2+1];
        }
        w32[dp] = (unsigned int)f2bf(o0*inv) | ((unsigned int)f2bf(o1*inv) << 16);
    }
    unsigned short* dst = attnout + (base + ru)*64 + h*16;
    uint4 q0; q0.x=w32[0]; q0.y=w32[1]; q0.z=w32[2]; q0.w=w32[3];
    uint4 q1; q1.x=w32[4]; q1.y=w32[5]; q1.z=w32[6]; q1.w=w32[7];
    *(uint4*)(dst)   = q0;
    *(uint4*)(dst+8) = q1;
}

// ---------------- tcl as MFMA GEMM: K=960 (15 tiles), dbuf + counted vmcnt ----------------
__global__ __launch_bounds__(256) void tcl_mfma(const unsigned short* __restrict__ A0p,
        const unsigned short* __restrict__ BT, const float* __restrict__ tb,
        unsigned short* __restrict__ ybf, int outoff){
    constexpr int HALF = (192+64)*128;
    __shared__ __align__(16) char smem[2*HALF];
    int tid = threadIdx.x, lane = tid & 63;
    int wid = tid >> 6;
    int l15 = lane & 15, lq = lane >> 4;
    int bid = blockIdx.x;
    int per = gridDim.x >> 3;
    int wkid = (bid & 7)*per + (bid >> 3);
    int m0 = wkid * 192;
    int b = m0 / 3072;
    long brow0 = (long)b*PROWS + 192 + (m0 - b*3072);

    const char* gA[6]; int loA[6];
    const char* gB[2]; int loB[2];
    {
        const char* Ab = (const char*)A0p + (brow0 - 192)*384;
        #pragma unroll
        for (int i = 0; i < 6; i++){
            int c = tid + i*256;
            int p = c << 4, r = p >> 7;
            int kl = (p & 127) ^ ((r & 7) << 4);
            gA[i] = Ab + (size_t)r*384 + kl; loA[i] = p;
        }
        #pragma unroll
        for (int i = 0; i < 2; i++){
            int c = tid + i*256;
            int p = c << 4, r = p >> 7;
            int kl = (p & 127) ^ ((r & 7) << 4);
            gB[i] = (const char*)BT + (size_t)r*1920 + kl; loB[i] = 192*128 + p;
        }
    }

    f32x4 acc[3][4];
    #pragma unroll
    for (int i = 0; i < 3; i++)
        #pragma unroll
        for (int j = 0; j < 4; j++){ f32x4 z = {0.f,0.f,0.f,0.f}; acc[i][j] = z; }

    #pragma unroll
    for (int i = 0; i < 6; i++) gll16(gA[i], smem + loA[i]);
    #pragma unroll
    for (int i = 0; i < 2; i++) gll16(gB[i], smem + loB[i]);

    long offA = 0; int kc3 = 0; int offB = 0;
    for (int kt = 0; kt < 15; kt++){
        char* cur = smem + (kt & 1)*HALF;
        if (kt + 1 < 15){
            char* nxt = smem + ((kt + 1) & 1)*HALF;
            if (kc3 == 2){ offA += 18432 - 256; kc3 = 0; }
            else         { offA += 128; kc3++; }
            offB += 128;
            #pragma unroll
            for (int i = 0; i < 6; i++) gll16(gA[i] + offA, nxt + loA[i]);
            #pragma unroll
            for (int i = 0; i < 2; i++) gll16(gB[i] + offB, nxt + loB[i]);
            asm volatile("s_waitcnt vmcnt(8)" ::: "memory");
        } else {
            asm volatile("s_waitcnt vmcnt(0)" ::: "memory");
        }
        __builtin_amdgcn_s_barrier();
        __builtin_amdgcn_sched_barrier(0);
        char* ldsA = cur;
        char* ldsB = cur + 192*128;
        #pragma unroll
        for (int ks = 0; ks < 2; ks++){
            bf16x8 a[3], bb[4];
            int kb = ks*64 + lq*16;
            #pragma unroll
            for (int mf = 0; mf < 3; mf++) a[mf] = frag_ld(ldsA, wid*48 + mf*16 + l15, kb);
            #pragma unroll
            for (int nf = 0; nf < 4; nf++) bb[nf] = frag_ld(ldsB, nf*16 + l15, kb);
            #pragma unroll
            for (int mf = 0; mf < 3; mf++)
                #pragma unroll
                for (int nf = 0; nf < 4; nf++)
                    acc[mf][nf] = __builtin_amdgcn_mfma_f32_16x16x32_bf16(a[mf], bb[nf], acc[mf][nf], 0, 0, 0);
        }
        __builtin_amdgcn_sched_barrier(0);
        __builtin_amdgcn_s_barrier();
    }
    #pragma unroll
    for (int nf = 0; nf < 4; nf++){
        int col = nf*16 + l15;
        float bb = tb[col];
        #pragma unroll
        for (int mf = 0; mf < 3; mf++){
            int tok = m0 + wid*48 + mf*16 + lq*4;
            f32x4 v = acc[mf][nf];
            #pragma unroll
            for (int r = 0; r < 4; r++)
                ybf[(size_t)(tok+r)*256 + outoff + col] = f2bf(v[r] + bb);
        }
    }
}

// ---------------- y0: grouped V-mix -> ybf cols 0..63 ----------------
__global__ __launch_bounds__(256) void y0_kernel(const unsigned short* __restrict__ fbf,
        const float* __restrict__ gct, unsigned short* __restrict__ ybf){
    int bt = blockIdx.x; int nb = bt*VV;
    __shared__ float X[48*68];
    for (int it = 0; it < 2; it++){
        int idx = it*256 + threadIdx.x;
        if (idx < 384){
            int v = idx >> 3, c8 = idx & 7;
            uint4 u = *(const uint4*)(fbf + (size_t)(nb+v)*256 + c8*8);
            unpk8(u, &X[v*68 + c8*8]);
        }
    }
    __syncthreads();
    int c = threadIdx.x % 64, vv = threadIdx.x / 64;
    int g = c >> 3;
    float acc[12] = {};
    for (int u = 0; u < 48; u++){
        float xv = X[u*68 + c];
        const float* gr = gct + (size_t)(g*48+u)*48 + vv*12;
        float4 g0 = *(const float4*)(gr);
        float4 g1 = *(const float4*)(gr+4);
        float4 g2 = *(const float4*)(gr+8);
        acc[0]+=xv*g0.x; acc[1]+=xv*g0.y; acc[2]+=xv*g0.z;  acc[3]+=xv*g0.w;
        acc[4]+=xv*g1.x; acc[5]+=xv*g1.y; acc[6]+=xv*g1.z;  acc[7]+=xv*g1.w;
        acc[8]+=xv*g2.x; acc[9]+=xv*g2.y; acc[10]+=xv*g2.z; acc[11]+=xv*g2.w;
    }
    #pragma unroll
    for (int j = 0; j < 12; j++)
        ybf[(size_t)(nb + vv*12 + j)*256 + c] = f2bf(acc[j]);
}

// ---------------- y1: grouped temporal conv (k=7) -> ybf cols 64..127 ----------------
__global__ __launch_bounds__(256) void y1_kernel(const unsigned short* __restrict__ fbf,
        const float* __restrict__ tw, const float* __restrict__ tb, unsigned short* __restrict__ ybf){
    int bt = blockIdx.x; int b = bt/TT, t = bt%TT;
    int o = threadIdx.x % 64, vv = threadIdx.x / 64;
    int g = o >> 3;
    float bv = tb[o];
    float acc[12];
    #pragma unroll
    for (int j = 0; j < 12; j++) acc[j] = bv;
    for (int kh = 0; kh < 7; kh++){
        int tt = t + kh - 3;
        if (tt < 0 || tt >= TT) continue;
        float wk[8];
        #pragma unroll
        for (int ci = 0; ci < 8; ci++) wk[ci] = tw[(o*8+ci)*7 + kh];
        int nb2 = (b*TT+tt)*VV;
        #pragma unroll
        for (int j = 0; j < 12; j++){
            uint4 u = *(const uint4*)(fbf + (size_t)(nb2 + vv*12 + j)*256 + 64 + g*8);
            float fv[8]; unpk8(u, fv);
            acc[j] += fv[0]*wk[0]+fv[1]*wk[1]+fv[2]*wk[2]+fv[3]*wk[3]
                    + fv[4]*wk[4]+fv[5]*wk[5]+fv[6]*wk[6]+fv[7]*wk[7];
        }
    }
    int nb = bt*VV;
    #pragma unroll
    for (int j = 0; j < 12; j++)
        ybf[(size_t)(nb + vv*12 + j)*256 + 64 + o] = f2bf(acc[j]);
}

extern "C" void kernel_launch(void* const* d_in, const int* in_sizes, int n_in,
                              void* d_out, int out_size, void* d_ws, size_t ws_size,
                              hipStream_t stream){
    const float* input   = (const float*)d_in[0];
    const float* n1g     = (const float*)d_in[1];
    const float* n1b     = (const float*)d_in[2];
    const float* map_w   = (const float*)d_in[3];
    const float* map_b   = (const float*)d_in[4];
    const float* gconv   = (const float*)d_in[5];
    const float* tconv_w = (const float*)d_in[6];
    const float* tconv_b = (const float*)d_in[7];
    const float* qkv_w0  = (const float*)d_in[8];
    const float* qkv_b0  = (const float*)d_in[9];
    const float* aproj_w0= (const float*)d_in[10];
    const float* aproj_b0= (const float*)d_in[11];
    const float* tcl_w0  = (const float*)d_in[12];
    const float* tcl_b0  = (const float*)d_in[13];
    const float* qkv_w1  = (const float*)d_in[14];
    const float* qkv_b1  = (const float*)d_in[15];
    const float* aproj_w1= (const float*)d_in[16];
    const float* aproj_b1= (const float*)d_in[17];
    const float* tcl_w1  = (const float*)d_in[18];
    const float* tcl_b1  = (const float*)d_in[19];
    const float* proj_w  = (const float*)d_in[20];
    const float* proj_b  = (const float*)d_in[21];
    const float* n2g     = (const float*)d_in[22];
    const float* n2b     = (const float*)d_in[23];
    const float* mlp_w1  = (const float*)d_in[24];
    const float* mlp_b1  = (const float*)d_in[25];
    const float* mlp_w2  = (const float*)d_in[26];
    const float* mlp_b2  = (const float*)d_in[27];

    const size_t Nt = NTOK;
    if (ws_size < 354050048ull) return;

    char* base = (char*)d_ws;
    unsigned short* outtH  = (unsigned short*)base;                  //  50 MB (bf16 outt)
    unsigned short* fbf    = (unsigned short*)(base + 100663296);    //  50 MB
    unsigned short* a0p    = (unsigned short*)(base + 150994944);    //  40 MB
    unsigned short* qkvbuf = (unsigned short*)(base + 191102976);    //  75 MB
    unsigned short* attnout= (unsigned short*)(base + 266600448);    //  25 MB
    unsigned short* A1     = (unsigned short*)(base + 301989888);    //  50 MB
    char* wp = base + 352321536;
    float* gct            = (float*)wp;
    unsigned short* mapT  = (unsigned short*)(wp + 73728);
    unsigned short* projT = mapT + 65536;
    unsigned short* w1T   = projT + 65536;
    unsigned char* w2T8   = (unsigned char*)(w1T + 262144);
    unsigned short* tclT0 = w1T + 262144 + 262144;   // w2T region reused as fp8
    unsigned short* tclT1 = tclT0 + 61440;
    unsigned short* qkvT  = tclT1 + 61440;
    unsigned short* aprojT= qkvT + 24576;

    unsigned char* h8   = (unsigned char*)fbf;   // fp8 Nt x 1024 = 100 MB, spans fbf+a0p+part of qkvbuf (dead)
    unsigned short* xn  = A1;
    unsigned short* ybf = (unsigned short*)d_out;
    unsigned short* xskip = ybf + (size_t)256*Nt;
    float* dout = (float*)d_out;

    prep_weights<<<256, 256, 0, stream>>>(gconv, tcl_w0, tcl_w1, map_w, proj_w, mlp_w1, mlp_w2,
                                          qkv_w0, qkv_w1, aproj_w0, aproj_w1,
                                          gct, mapT, projT, w1T, w2T8, tclT0, tclT1, qkvT, aprojT);
    xpose_ln1<<<NB*TT, 256, 0, stream>>>(input, n1g, n1b, A1, xskip);
    mfma_gemm<256,4><<<1024, 512, 0, stream>>>(A1, mapT, map_b, fbf, nullptr, 256, 2);
    hipMemsetAsync(a0p, 0, A0P_USH*sizeof(unsigned short), stream);
    gemm_k64<0><<<1024, 256, 0, stream>>>(fbf + 128, 512, qkvT,         qkv_b0, qkvbuf);
    gemm_k64<0><<<1024, 256, 0, stream>>>(fbf + 192, 512, qkvT + 12288, qkv_b1, qkvbuf + (size_t)Nt*192);
    attn_win<<<dim3(2048,2), 192, 0, stream>>>(qkvbuf, attnout);
    y0_kernel<<<NB*TT, 256, 0, stream>>>(fbf, gct, ybf);
    y1_kernel<<<NB*TT, 256, 0, stream>>>(fbf, tconv_w, tconv_b, ybf);
    gemm_k64<1><<<1024, 256, 0, stream>>>(attnout,                 128, aprojT,         aproj_b0, a0p);
    tcl_mfma<<<NTOK/192, 256, 0, stream>>>(a0p, tclT0, tcl_b0, ybf, 128);
    gemm_k64<1><<<1024, 256, 0, stream>>>(attnout + (size_t)Nt*64, 128, aprojT + 12288, aproj_b1, a0p);
    tcl_mfma<<<NTOK/192, 256, 0, stream>>>(a0p, tclT1, tcl_b1, ybf, 192);
    proj_ln2<<<512, 512, 0, stream>>>(ybf, projT, proj_b, xskip, n2g, n2b, outtH, xn);
    mfma_gemm<256,2><<<4096, 512, 0, stream>>>(xn, w1T, mlp_b1, nullptr, h8, 1024, 8);
    mfma_final_fp8<<<1024, 512, 0, stream>>>(h8, w2T8, mlp_b2, outtH, dout);
}

// Round 21
// 543.362 us; speedup vs baseline: 1.0238x; 1.0178x over previous
//
#include <hip/hip_runtime.h>
#include <hip/hip_bf16.h>
#include <math.h>

#define NB 32
#define CC 256
#define TT 64
#define VV 48
#define NTOK (NB*TT*VV)   // 98304
#define LNE 1e-5f
#define PROWS 3264        // (4+64)*48
#define A0P_USH ((size_t)NB*PROWS*192)

typedef __attribute__((ext_vector_type(8))) __bf16 bf16x8;
typedef __attribute__((ext_vector_type(4))) float f32x4;

__device__ inline float bfbits2f(unsigned int bits){
    union{unsigned int u; float f;} c; c.u = bits<<16; return c.f;
}
__device__ inline unsigned short f2bf(float x){
    union{ __bf16 h; unsigned short u; } c; c.h = (__bf16)x; return c.u;
}
__device__ inline unsigned char f2fp8(float x){
    int p = __builtin_amdgcn_cvt_pk_fp8_f32(x, x, 0, false);
    return (unsigned char)(p & 0xff);
}
__device__ __forceinline__ void unpk8(uint4 u, float* d){
    d[0]=bfbits2f(u.x&0xffffu); d[1]=bfbits2f(u.x>>16);
    d[2]=bfbits2f(u.y&0xffffu); d[3]=bfbits2f(u.y>>16);
    d[4]=bfbits2f(u.z&0xffffu); d[5]=bfbits2f(u.z>>16);
    d[6]=bfbits2f(u.w&0xffffu); d[7]=bfbits2f(u.w>>16);
}
// 4*gelu(x) via sigmoid form: 4x * rcp(1 + exp(-1.702x)).
// No clamp needed: x->-inf => exp->inf => rcp->0 => result 0 (correct limit).
__device__ __forceinline__ float gelu4_fast(float x){
    float e = __expf(-1.702f * x);
    return (4.f * x) * __builtin_amdgcn_rcpf(1.f + e);
}

__device__ __forceinline__ void gll16(const char* g, char* l){
    __builtin_amdgcn_global_load_lds(
        (const __attribute__((address_space(1))) unsigned int*)g,
        (__attribute__((address_space(3))) unsigned int*)l, 16, 0, 0);
}

// ---------------- weight prep ----------------
__global__ void prep_weights(const float* gconv, const float* tcl0, const float* tcl1,
                             const float* map_w, const float* proj_w,
                             const float* mlp_w1, const float* mlp_w2,
                             const float* qkv_w0, const float* qkv_w1,
                             const float* aproj_w0, const float* aproj_w1,
                             float* gct,
                             unsigned short* mapT, unsigned short* projT,
                             unsigned short* w1T, unsigned char* w2T8,
                             unsigned short* tclT0, unsigned short* tclT1,
                             unsigned short* qkvT, unsigned short* aprojT){
    int tid = blockIdx.x*blockDim.x + threadIdx.x;
    int stride = gridDim.x*blockDim.x;
    for (int i = tid; i < 8*48*48; i += stride){
        int g = i/(48*48); int r = i%(48*48); int u = r/48; int v = r%48;
        gct[i] = gconv[(g*48+v)*48+u];
    }
    for (int i = tid; i < 64*960; i += stride){
        int o = i/960, col = i%960, kh = col/192, c = col%192;
        tclT0[i] = f2bf(tcl0[(o*192+c)*5+kh]);
        tclT1[i] = f2bf(tcl1[(o*192+c)*5+kh]);
    }
    for (int i = tid; i < 65536; i += stride){
        int n = i>>8, k = i&255;
        mapT[i] = f2bf(map_w[k*256+n]);
        projT[i] = f2bf(proj_w[k*256+n]);
    }
    for (int i = tid; i < 262144; i += stride){
        int n = i>>8, k = i&255;
        w1T[i] = f2bf(mlp_w1[k*1024+n]);
    }
    // w2T8[n][k] = fp8(mlp_w2[k][n] * 32)
    for (int i = tid; i < 262144; i += stride){
        int n = i>>10, k = i&1023;
        w2T8[i] = f2fp8(mlp_w2[k*256+n] * 32.f);
    }
    for (int i = tid; i < 12288; i += stride){
        int n = i/64, k = i%64;
        qkvT[i]          = f2bf(qkv_w0[k*192+n]);
        qkvT[12288+i]    = f2bf(qkv_w1[k*192+n]);
        aprojT[i]        = f2bf(aproj_w0[k*192+n]);
        aprojT[12288+i]  = f2bf(aproj_w1[k*192+n]);
    }
}

// ---------------- LN1 + transpose -> A1 bf16 [N][256] + raw skip copy ----------------
__global__ __launch_bounds__(256) void xpose_ln1(const float* __restrict__ x,
        const float* __restrict__ g, const float* __restrict__ bb,
        unsigned short* __restrict__ A1, unsigned short* __restrict__ xskip){
    int bt = blockIdx.x; int b = bt/TT, t = bt%TT;
    __shared__ float X[48*257];
    __shared__ float S[4][48], SS[4][48], sm[48], sv[48];
    int tid = threadIdx.x;
    const float* xb = x + (size_t)b*256*3072 + (size_t)t*48;
    for (int it = 0; it < 12; it++){
        int idx = it*256 + tid;
        int c = idx/12, q = idx%12;
        float4 v = *(const float4*)(xb + (size_t)c*3072 + q*4);
        X[(q*4+0)*257 + c] = v.x;
        X[(q*4+1)*257 + c] = v.y;
        X[(q*4+2)*257 + c] = v.z;
        X[(q*4+3)*257 + c] = v.w;
    }
    __syncthreads();
    if (tid < 192){
        int v = tid % 48, w = tid / 48;
        float s = 0.f, ss = 0.f;
        for (int c = w*64; c < w*64+64; c++){
            float val = X[v*257 + c];
            s += val; ss += val*val;
        }
        S[w][v] = s; SS[w][v] = ss;
    }
    __syncthreads();
    if (tid < 48){
        float s = S[0][tid]+S[1][tid]+S[2][tid]+S[3][tid];
        float q = SS[0][tid]+SS[1][tid]+SS[2][tid]+SS[3][tid];
        float m = s*(1.f/256);
        sm[tid] = m; sv[tid] = rsqrtf(q*(1.f/256) - m*m + LNE);
    }
    __syncthreads();
    int nb = bt*48;
    for (int it = 0; it < 12; it++){
        int idx = it*256 + tid;
        int v = idx>>6, cq = idx&63;
        float m = sm[v], rs = sv[v];
        float4 g4 = *(const float4*)(g + cq*4);
        float4 b4 = *(const float4*)(bb + cq*4);
        float x0 = X[v*257 + cq*4+0], x1 = X[v*257 + cq*4+1];
        float x2 = X[v*257 + cq*4+2], x3 = X[v*257 + cq*4+3];
        ushort4 u;
        u.x = f2bf((x0-m)*rs*g4.x + b4.x);
        u.y = f2bf((x1-m)*rs*g4.y + b4.y);
        u.z = f2bf((x2-m)*rs*g4.z + b4.z);
        u.w = f2bf((x3-m)*rs*g4.w + b4.w);
        *(ushort4*)(A1 + (size_t)(nb+v)*256 + cq*4) = u;
        ushort4 s;
        s.x = f2bf(x0); s.y = f2bf(x1); s.z = f2bf(x2); s.w = f2bf(x3);
        *(ushort4*)(xskip + (size_t)(nb+v)*256 + cq*4) = s;
    }
}

// ---------------- swizzled staging (single-shot, for k64 GEMM) ----------------
__device__ __forceinline__ void stage_swz(const char* src, size_t rowbytes, char* lds,
                                          int nchunks, int tid){
    for (int c = tid; c < nchunks; c += 256){
        int p = c << 4;
        int r = p >> 7;
        int kl = (p & 127) ^ ((r & 7) << 4);
        gll16(src + (size_t)r*rowbytes + kl, lds + p);
    }
}

__device__ __forceinline__ bf16x8 frag_ld(const char* lds, int R, int kb){
    return *(const bf16x8*)(lds + R*128 + (kb ^ ((R & 7) << 4)));
}
__device__ __forceinline__ long frag_ld8(const char* lds, int R, int kb){
    return *(const long*)(lds + R*128 + (kb ^ ((R & 7) << 4)));
}

// ---------------- MFMA GEMM: BM=192, BN=128, 8 waves, dbuf + counted vmcnt ----------------
// EPI 2: outH8 = fp8(gelu(acc + bias) * 4)   [LDS repack, 16B stores]
// EPI 4: outH  = bf16(acc + bias)            [LDS repack, 16B stores]
template<int KTOT, int EPI>
__global__ __launch_bounds__(512, 4) void mfma_gemm(
    const unsigned short* __restrict__ A, const unsigned short* __restrict__ BT,
    const float* __restrict__ bias,
    unsigned short* __restrict__ outH, unsigned char* __restrict__ outH8,
    int ncols, int nx){

    constexpr int BM = 192, BN = 128;
    constexpr int HALF = (BM+BN)*128;           // 40960
    __shared__ __align__(16) char smem[2*HALF]; // 81920 -> 2 blocks/CU
    int tid = threadIdx.x, lane = tid & 63;
    int wid = tid >> 6;
    int wm = wid >> 1, wn = wid & 1;
    int l15 = lane & 15, lq = lane >> 4;
    int bid = blockIdx.x;
    int per = gridDim.x >> 3;
    int wkid = (bid & 7)*per + (bid >> 3);
    int m0 = (wkid / nx) * BM, n0 = (wkid % nx) * BN;
    const size_t arb = KTOT*2, brb = KTOT*2;
    constexpr int KT = KTOT/64;

    const char* gA[3]; int loA[3];
    const char* gB[2]; int loB[2];
    {
        const char* Ab = (const char*)A + (size_t)m0*arb;
        const char* Bb = (const char*)BT + (size_t)n0*brb;
        #pragma unroll
        for (int i = 0; i < 3; i++){
            int c = tid + i*512;
            int p = c << 4, r = p >> 7;
            int kl = (p & 127) ^ ((r & 7) << 4);
            gA[i] = Ab + (size_t)r*arb + kl; loA[i] = p;
        }
        #pragma unroll
        for (int i = 0; i < 2; i++){
            int c = tid + i*512;
            int p = c << 4, r = p >> 7;
            int kl = (p & 127) ^ ((r & 7) << 4);
            gB[i] = Bb + (size_t)r*brb + kl; loB[i] = BM*128 + p;
        }
    }

    f32x4 acc[3][4];
    #pragma unroll
    for (int i = 0; i < 3; i++)
        #pragma unroll
        for (int j = 0; j < 4; j++){ f32x4 z = {0.f,0.f,0.f,0.f}; acc[i][j] = z; }

    #pragma unroll
    for (int i = 0; i < 3; i++) gll16(gA[i], smem + loA[i]);
    #pragma unroll
    for (int i = 0; i < 2; i++) gll16(gB[i], smem + loB[i]);

    int koff = 128;
    for (int kt = 0; kt < KT; kt++){
        char* cur = smem + (kt & 1)*HALF;
        if (kt + 1 < KT){
            char* nxt = smem + ((kt + 1) & 1)*HALF;
            #pragma unroll
            for (int i = 0; i < 3; i++) gll16(gA[i] + koff, nxt + loA[i]);
            #pragma unroll
            for (int i = 0; i < 2; i++) gll16(gB[i] + koff, nxt + loB[i]);
            koff += 128;
            asm volatile("s_waitcnt vmcnt(5)" ::: "memory");
        } else {
            asm volatile("s_waitcnt vmcnt(0)" ::: "memory");
        }
        __builtin_amdgcn_s_barrier();
        __builtin_amdgcn_sched_barrier(0);
        char* ldsA = cur;
        char* ldsB = cur + BM*128;
        #pragma unroll
        for (int ks = 0; ks < 2; ks++){
            bf16x8 a[3], b[4];
            int kb = ks*64 + lq*16;
            #pragma unroll
            for (int mf = 0; mf < 3; mf++) a[mf] = frag_ld(ldsA, wm*48 + mf*16 + l15, kb);
            #pragma unroll
            for (int nf = 0; nf < 4; nf++) b[nf] = frag_ld(ldsB, wn*64 + nf*16 + l15, kb);
            #pragma unroll
            for (int mf = 0; mf < 3; mf++)
                #pragma unroll
                for (int nf = 0; nf < 4; nf++)
                    acc[mf][nf] = __builtin_amdgcn_mfma_f32_16x16x32_bf16(a[mf], b[nf], acc[mf][nf], 0, 0, 0);
        }
        __builtin_amdgcn_sched_barrier(0);
        __builtin_amdgcn_s_barrier();
    }

    if constexpr (EPI == 4){
        unsigned short* Hs = (unsigned short*)smem;   // [192][136]
        #pragma unroll
        for (int nf = 0; nf < 4; nf++){
            int col = wn*64 + nf*16 + l15;
            float bb = bias[n0 + col];
            #pragma unroll
            for (int mf = 0; mf < 3; mf++){
                int row = wm*48 + mf*16 + lq*4;
                f32x4 v = acc[mf][nf];
                #pragma unroll
                for (int r = 0; r < 4; r++)
                    Hs[(row+r)*136 + col] = f2bf(v[r] + bb);
            }
        }
        __syncthreads();
        for (int idx = tid; idx < 192*16; idx += 512){
            int row = idx >> 4, c8 = idx & 15;
            *(uint4*)(outH + (size_t)(m0+row)*ncols + n0 + c8*8) =
                *(const uint4*)(Hs + row*136 + c8*8);
        }
    }
    if constexpr (EPI == 2){
        unsigned char* Hc = (unsigned char*)smem;     // [192][144] fp8
        #pragma unroll
        for (int nf = 0; nf < 4; nf++){
            int col = wn*64 + nf*16 + l15;
            float bb = bias[n0 + col];
            #pragma unroll
            for (int mf = 0; mf < 3; mf++){
                int row = wm*48 + mf*16 + lq*4;
                f32x4 v = acc[mf][nf];
                #pragma unroll
                for (int r = 0; r < 4; r++){
                    float t0 = gelu4_fast(v[r] + bb);
                    Hc[(row+r)*144 + col] = f2fp8(t0);
                }
            }
        }
        __syncthreads();
        for (int idx = tid; idx < 192*8; idx += 512){
            int row = idx >> 3, c16 = idx & 7;
            *(uint4*)(outH8 + (size_t)(m0+row)*ncols + n0 + c16*16) =
                *(const uint4*)(Hc + row*144 + c16*16);
        }
    }
}

// ---------------- final GEMM in fp8: K=1024 as 8 tiles of K=128 (128B rows) ----------------
// dout(NCHW) = acc/128 + bias + bf16 extraH(outtH), two-pass transposed store
__global__ __launch_bounds__(512, 4) void mfma_final_fp8(
    const unsigned char* __restrict__ A, const unsigned char* __restrict__ BT,
    const float* __restrict__ bias, const unsigned short* __restrict__ extraH,
    float* __restrict__ outF){

    constexpr int BM = 192, BN = 128, NX = 2;
    constexpr int HALF = (BM+BN)*128;           // 40960
    __shared__ __align__(16) char smem[2*HALF]; // 81920 -> 2 blocks/CU
    int tid = threadIdx.x, lane = tid & 63;
    int wid = tid >> 6;
    int wm = wid >> 1, wn = wid & 1;
    int l15 = lane & 15, lq = lane >> 4;
    int bid = blockIdx.x;
    int per = gridDim.x >> 3;
    int wkid = (bid & 7)*per + (bid >> 3);
    int m0 = (wkid / NX) * BM, n0 = (wkid % NX) * BN;
    const size_t arb = 1024, brb = 1024;
    constexpr int KT = 8;

    const char* gA[3]; int loA[3];
    const char* gB[2]; int loB[2];
    {
        const char* Ab = (const char*)A + (size_t)m0*arb;
        const char* Bb = (const char*)BT + (size_t)n0*brb;
        #pragma unroll
        for (int i = 0; i < 3; i++){
            int c = tid + i*512;
            int p = c << 4, r = p >> 7;
            int kl = (p & 127) ^ ((r & 7) << 4);
            gA[i] = Ab + (size_t)r*arb + kl; loA[i] = p;
        }
        #pragma unroll
        for (int i = 0; i < 2; i++){
            int c = tid + i*512;
            int p = c << 4, r = p >> 7;
            int kl = (p & 127) ^ ((r & 7) << 4);
            gB[i] = Bb + (size_t)r*brb + kl; loB[i] = BM*128 + p;
        }
    }

    f32x4 acc[3][4];
    #pragma unroll
    for (int i = 0; i < 3; i++)
        #pragma unroll
        for (int j = 0; j < 4; j++){ f32x4 z = {0.f,0.f,0.f,0.f}; acc[i][j] = z; }

    #pragma unroll
    for (int i = 0; i < 3; i++) gll16(gA[i], smem + loA[i]);
    #pragma unroll
    for (int i = 0; i < 2; i++) gll16(gB[i], smem + loB[i]);

    int koff = 128;
    for (int kt = 0; kt < KT; kt++){
        char* cur = smem + (kt & 1)*HALF;
        if (kt + 1 < KT){
            char* nxt = smem + ((kt + 1) & 1)*HALF;
            #pragma unroll
            for (int i = 0; i < 3; i++) gll16(gA[i] + koff, nxt + loA[i]);
            #pragma unroll
            for (int i = 0; i < 2; i++) gll16(gB[i] + koff, nxt + loB[i]);
            koff += 128;
            asm volatile("s_waitcnt vmcnt(5)" ::: "memory");
        } else {
            asm volatile("s_waitcnt vmcnt(0)" ::: "memory");
        }
        __builtin_amdgcn_s_barrier();
        __builtin_amdgcn_sched_barrier(0);
        char* ldsA = cur;
        char* ldsB = cur + BM*128;
        #pragma unroll
        for (int ks = 0; ks < 4; ks++){
            long a[3], b[4];
            int kb = ks*32 + lq*8;
            #pragma unroll
            for (int mf = 0; mf < 3; mf++) a[mf] = frag_ld8(ldsA, wm*48 + mf*16 + l15, kb);
            #pragma unroll
            for (int nf = 0; nf < 4; nf++) b[nf] = frag_ld8(ldsB, wn*64 + nf*16 + l15, kb);
            #pragma unroll
            for (int mf = 0; mf < 3; mf++)
                #pragma unroll
                for (int nf = 0; nf < 4; nf++)
                    acc[mf][nf] = __builtin_amdgcn_mfma_f32_16x16x32_fp8_fp8(a[mf], b[nf], acc[mf][nf], 0, 0, 0);
        }
        __builtin_amdgcn_sched_barrier(0);
        __builtin_amdgcn_s_barrier();
    }

    // epilogue: dout NCHW = acc/128 + bias + resid (bf16 outtH), two-pass transpose
    float* Tt = (float*)smem;  // [64 cols][196]
    #pragma unroll
    for (int ph = 0; ph < 2; ph++){
        __syncthreads();
        if (wn == ph){
            #pragma unroll
            for (int nf = 0; nf < 4; nf++){
                int lc = nf*16 + l15;
                float bb = bias[n0 + ph*64 + lc];
                #pragma unroll
                for (int mf = 0; mf < 3; mf++){
                    int tl = wm*48 + mf*16 + lq*4;
                    f32x4 v = acc[mf][nf];
                    #pragma unroll
                    for (int r = 0; r < 4; r++){
                        float resid = bfbits2f(extraH[(size_t)(m0+tl+r)*256 + n0 + ph*64 + lc]);
                        Tt[lc*196 + tl + r] = v[r]*0.0078125f + bb + resid;
                    }
                }
            }
        }
        __syncthreads();
        {
            int lc = tid & 63, btl = (tid>>6)&3, dup = tid>>8;
            int gtok = m0 + btl*48;
            int bg = gtok/3072, t = (gtok%3072)/48;
            float* dst = outF + ((size_t)(bg*256 + n0 + ph*64 + lc)*64 + t)*48 + dup*24;
            const float* tr = Tt + lc*196 + btl*48 + dup*24;
            #pragma unroll
            for (int j = 0; j < 6; j++)
                *(float4*)(dst + j*4) = *(const float4*)(tr + j*4);
        }
    }
}

// ---------------- proj GEMM fused with skip-add + LN2: BM=192, BN=256, K=256 ----------------
__global__ __launch_bounds__(512, 2) void proj_ln2(
    const unsigned short* __restrict__ A, const unsigned short* __restrict__ BT,
    const float* __restrict__ bias, const unsigned short* __restrict__ xskip,
    const float* __restrict__ n2g, const float* __restrict__ n2b,
    unsigned short* __restrict__ outtH, unsigned short* __restrict__ xn){

    constexpr int BM = 192, BN = 256, KTOT = 256;
    constexpr int HALF = (BM+BN)*128;
    __shared__ __align__(16) char smem[2*HALF];
    int tid = threadIdx.x, lane = tid & 63;
    int wid = tid >> 6;
    int wm = wid >> 1, wn = wid & 1;
    int l15 = lane & 15, lq = lane >> 4;
    int bid = blockIdx.x;
    int per = gridDim.x >> 3;
    int wkid = (bid & 7)*per + (bid >> 3);
    int m0 = wkid * BM;
    const size_t arb = KTOT*2, brb = KTOT*2;
    constexpr int KT = KTOT/64;

    const char* gA[3]; int loA[3];
    const char* gB[4]; int loB[4];
    {
        const char* Ab = (const char*)A + (size_t)m0*arb;
        const char* Bb = (const char*)BT;
        #pragma unroll
        for (int i = 0; i < 3; i++){
            int c = tid + i*512;
            int p = c << 4, r = p >> 7;
            int kl = (p & 127) ^ ((r & 7) << 4);
            gA[i] = Ab + (size_t)r*arb + kl; loA[i] = p;
        }
        #pragma unroll
        for (int i = 0; i < 4; i++){
            int c = tid + i*512;
            int p = c << 4, r = p >> 7;
            int kl = (p & 127) ^ ((r & 7) << 4);
            gB[i] = Bb + (size_t)r*brb + kl; loB[i] = BM*128 + p;
        }
    }

    f32x4 acc[3][8];
    #pragma unroll
    for (int i = 0; i < 3; i++)
        #pragma unroll
        for (int j = 0; j < 8; j++){ f32x4 z = {0.f,0.f,0.f,0.f}; acc[i][j] = z; }

    #pragma unroll
    for (int i = 0; i < 3; i++) gll16(gA[i], smem + loA[i]);
    #pragma unroll
    for (int i = 0; i < 4; i++) gll16(gB[i], smem + loB[i]);

    int koff = 128;
    for (int kt = 0; kt < KT; kt++){
        char* cur = smem + (kt & 1)*HALF;
        if (kt + 1 < KT){
            char* nxt = smem + ((kt + 1) & 1)*HALF;
            #pragma unroll
            for (int i = 0; i < 3; i++) gll16(gA[i] + koff, nxt + loA[i]);
            #pragma unroll
            for (int i = 0; i < 4; i++) gll16(gB[i] + koff, nxt + loB[i]);
            koff += 128;
            asm volatile("s_waitcnt vmcnt(7)" ::: "memory");
        } else {
            asm volatile("s_waitcnt vmcnt(0)" ::: "memory");
        }
        __builtin_amdgcn_s_barrier();
        __builtin_amdgcn_sched_barrier(0);
        char* ldsA = cur;
        char* ldsB = cur + BM*128;
        #pragma unroll
        for (int ks = 0; ks < 2; ks++){
            bf16x8 a[3], b[8];
            int kb = ks*64 + lq*16;
            #pragma unroll
            for (int mf = 0; mf < 3; mf++) a[mf] = frag_ld(ldsA, wm*48 + mf*16 + l15, kb);
            #pragma unroll
            for (int nf = 0; nf < 8; nf++) b[nf] = frag_ld(ldsB, wn*128 + nf*16 + l15, kb);
            #pragma unroll
            for (int mf = 0; mf < 3; mf++)
                #pragma unroll
                for (int nf = 0; nf < 8; nf++)
                    acc[mf][nf] = __builtin_amdgcn_mfma_f32_16x16x32_bf16(a[mf], b[nf], acc[mf][nf], 0, 0, 0);
        }
        __builtin_amdgcn_sched_barrier(0);
        __builtin_amdgcn_s_barrier();
    }

    unsigned short* Hs = (unsigned short*)smem;
    float* Sred = (float*)(smem + 101376);
    float s_acc[3][4], ss_acc[3][4];
    #pragma unroll
    for (int i = 0; i < 3; i++)
        #pragma unroll
        for (int r = 0; r < 4; r++){ s_acc[i][r] = 0.f; ss_acc[i][r] = 0.f; }

    #pragma unroll
    for (int nf = 0; nf < 8; nf++){
        int col = wn*128 + nf*16 + l15;
        float bb = bias[col];
        #pragma unroll
        for (int mf = 0; mf < 3; mf++){
            int row = wm*48 + mf*16 + lq*4;
            f32x4 v = acc[mf][nf];
            #pragma unroll
            for (int r = 0; r < 4; r++){
                float sk = bfbits2f(xskip[(size_t)(m0+row+r)*256 + col]);
                unsigned short us = f2bf(v[r] + bb + sk);
                Hs[(row+r)*264 + col] = us;
                float tf = bfbits2f(us);
                s_acc[mf][r] += tf; ss_acc[mf][r] += tf*tf;
            }
        }
    }
    #pragma unroll
    for (int mf = 0; mf < 3; mf++)
        #pragma unroll
        for (int r = 0; r < 4; r++){
            float s = s_acc[mf][r], ss = ss_acc[mf][r];
            #pragma unroll
            for (int d = 1; d < 16; d <<= 1){
                s  += __shfl_xor(s, d);
                ss += __shfl_xor(ss, d);
            }
            if (l15 == 0){
                int row = wm*48 + mf*16 + lq*4 + r;
                Sred[wn*192 + row] = s;
                Sred[384 + wn*192 + row] = ss;
            }
        }
    __syncthreads();
    if (tid < 192){
        float s  = Sred[tid] + Sred[192+tid];
        float ss = Sred[384+tid] + Sred[576+tid];
        float m = s*(1.f/256);
        Sred[tid] = m;
        Sred[192+tid] = rsqrtf(ss*(1.f/256) - m*m + LNE);
    }
    __syncthreads();
    for (int idx = tid; idx < 192*32; idx += 512){
        int row = idx >> 5, c8 = idx & 31;
        uint4 hv = *(const uint4*)(Hs + row*264 + c8*8);
        *(uint4*)(outtH + (size_t)(m0+row)*256 + c8*8) = hv;
        float v[8]; unpk8(hv, v);
        float m = Sred[row], rs = Sred[192+row];
        unsigned int w[4];
        #pragma unroll
        for (int j = 0; j < 4; j++){
            float g0 = n2g[c8*8 + j*2],   b0 = n2b[c8*8 + j*2];
            float g1 = n2g[c8*8 + j*2+1], b1 = n2b[c8*8 + j*2+1];
            unsigned int lo = f2bf((v[j*2]  -m)*rs*g0 + b0);
            unsigned int hi = f2bf((v[j*2+1]-m)*rs*g1 + b1);
            w[j] = lo | (hi << 16);
        }
        uint4 o; o.x=w[0]; o.y=w[1]; o.z=w[2]; o.w=w[3];
        *(uint4*)(xn + (size_t)(m0+row)*256 + c8*8) = o;
    }
}

// ---------------- K=64 MFMA GEMM: BM=96, BN=192, 4 waves ----------------
template<int EPI>
__global__ __launch_bounds__(256) void gemm_k64(
    const unsigned short* __restrict__ A, int arb,
    const unsigned short* __restrict__ BT,
    const float* __restrict__ bias,
    unsigned short* __restrict__ out){
    __shared__ __align__(16) char smem[96*128 + 192*128];
    char* ldsA = smem;
    char* ldsB = smem + 96*128;
    int tid = threadIdx.x, lane = tid & 63;
    int wid = tid >> 6, wm = wid >> 1, wn = wid & 1;
    int l15 = lane & 15, lq = lane >> 4;
    int m0 = blockIdx.x * 96;

    stage_swz((const char*)A + (size_t)m0*arb, arb, ldsA, 96*8, tid);
    stage_swz((const char*)BT, 128, ldsB, 192*8, tid);
    __syncthreads();

    f32x4 acc[3][6];
    #pragma unroll
    for (int i = 0; i < 3; i++)
        #pragma unroll
        for (int j = 0; j < 6; j++){ f32x4 z = {0.f,0.f,0.f,0.f}; acc[i][j] = z; }

    #pragma unroll
    for (int ks = 0; ks < 2; ks++){
        bf16x8 a[3], b[6];
        int kb = ks*64 + lq*16;
        #pragma unroll
        for (int mf = 0; mf < 3; mf++) a[mf] = frag_ld(ldsA, wm*48 + mf*16 + l15, kb);
        #pragma unroll
        for (int nf = 0; nf < 6; nf++) b[nf] = frag_ld(ldsB, wn*96 + nf*16 + l15, kb);
        #pragma unroll
        for (int mf = 0; mf < 3; mf++)
            #pragma unroll
            for (int nf = 0; nf < 6; nf++)
                acc[mf][nf] = __builtin_amdgcn_mfma_f32_16x16x32_bf16(a[mf], b[nf], acc[mf][nf], 0, 0, 0);
    }

    size_t row0;
    if constexpr (EPI == 0) row0 = (size_t)m0;
    else {
        int b = m0/3072;
        row0 = (size_t)b*PROWS + 192 + (m0 - b*3072);
    }
    #pragma unroll
    for (int nf = 0; nf < 6; nf++){
        int col = wn*96 + nf*16 + l15;
        float bb = bias[col];
        #pragma unroll
        for (int mf = 0; mf < 3; mf++){
            size_t rr = row0 + wm*48 + mf*16 + lq*4;
            f32x4 v = acc[mf][nf];
            #pragma unroll
            for (int r = 0; r < 4; r++)
                out[(rr+r)*192 + col] = f2bf(v[r] + bb);
        }
    }
}

// ---------------- windowed attention ----------------
__global__ __launch_bounds__(192) void attn_win(
        const unsigned short* __restrict__ qkvbuf,
        unsigned short* __restrict__ attnout){
    int win = blockIdx.x, br = blockIdx.y;
    size_t base = (size_t)br*NTOK + (size_t)win*48;
    __shared__ float Q[48*196];
    int tid = threadIdx.x;
    const unsigned short* src = qkvbuf + base*192;
    for (int i = 0; i < 6; i++){
        int ch = i*192 + tid;
        int v = ch/24, c8 = ch%24;
        uint4 u = *(const uint4*)(src + (size_t)v*192 + c8*8);
        unpk8(u, &Q[v*196 + c8*8]);
    }
    __syncthreads();
    int u = tid & 15, gh = tid >> 4, g = gh >> 2, h = gh & 3;
    int ru = g*16 + u;
    float qreg[16];
    #pragma unroll
    for (int d = 0; d < 16; d++) qreg[d] = Q[ru*196 + h*16 + d];
    float sc[16]; float mx = -1e30f;
    #pragma unroll
    for (int w = 0; w < 16; w++){
        float s = 0.f;
        #pragma unroll
        for (int d = 0; d < 16; d++) s += qreg[d]*Q[(g*16+w)*196 + 64 + h*16 + d];
        s *= 0.5f; sc[w] = s; mx = fmaxf(mx, s);
    }
    float sum = 0.f;
    #pragma unroll
    for (int w = 0; w < 16; w++){ sc[w] = __expf(sc[w]-mx); sum += sc[w]; }
    float inv = __builtin_amdgcn_rcpf(sum);
    unsigned int w32[8];
    #pragma unroll
    for (int dp = 0; dp < 8; dp++){
        float o0 = 0.f, o1 = 0.f;
        #pragma unroll
        for (int w = 0; w < 16; w++){
            float p = sc[w];
            o0 += p*Q[(g*16+w)*196 + 128 + h*16 + dp*2];
            o1 += p*Q[(g*16+w)*196 + 128 + h*16 + dp*2+1];
        }
        w32[dp] = (unsigned int)f2bf(o0*inv) | ((unsigned int)f2bf(o1*inv) << 16);
    }
    unsigned short* dst = attnout + (base + ru)*64 + h*16;
    uint4 q0; q0.x=w32[0]; q0.y=w32[1]; q0.z=w32[2]; q0.w=w32[3];
    uint4 q1; q1.x=w32[4]; q1.y=w32[5]; q1.z=w32[6]; q1.w=w32[7];
    *(uint4*)(dst)   = q0;
    *(uint4*)(dst+8) = q1;
}

// ---------------- tcl as MFMA GEMM: K=960 (15 tiles), dbuf + counted vmcnt ----------------
__global__ __launch_bounds__(256) void tcl_mfma(const unsigned short* __restrict__ A0p,
        const unsigned short* __restrict__ BT, const float* __restrict__ tb,
        unsigned short* __restrict__ ybf, int outoff){
    constexpr int HALF = (192+64)*128;
    __shared__ __align__(16) char smem[2*HALF];
    int tid = threadIdx.x, lane = tid & 63;
    int wid = tid >> 6;
    int l15 = lane & 15, lq = lane >> 4;
    int bid = blockIdx.x;
    int per = gridDim.x >> 3;
    int wkid = (bid & 7)*per + (bid >> 3);
    int m0 = wkid * 192;
    int b = m0 / 3072;
    long brow0 = (long)b*PROWS + 192 + (m0 - b*3072);

    const char* gA[6]; int loA[6];
    const char* gB[2]; int loB[2];
    {
        const char* Ab = (const char*)A0p + (brow0 - 192)*384;
        #pragma unroll
        for (int i = 0; i < 6; i++){
            int c = tid + i*256;
            int p = c << 4, r = p >> 7;
            int kl = (p & 127) ^ ((r & 7) << 4);
            gA[i] = Ab + (size_t)r*384 + kl; loA[i] = p;
        }
        #pragma unroll
        for (int i = 0; i < 2; i++){
            int c = tid + i*256;
            int p = c << 4, r = p >> 7;
            int kl = (p & 127) ^ ((r & 7) << 4);
            gB[i] = (const char*)BT + (size_t)r*1920 + kl; loB[i] = 192*128 + p;
        }
    }

    f32x4 acc[3][4];
    #pragma unroll
    for (int i = 0; i < 3; i++)
        #pragma unroll
        for (int j = 0; j < 4; j++){ f32x4 z = {0.f,0.f,0.f,0.f}; acc[i][j] = z; }

    #pragma unroll
    for (int i = 0; i < 6; i++) gll16(gA[i], smem + loA[i]);
    #pragma unroll
    for (int i = 0; i < 2; i++) gll16(gB[i], smem + loB[i]);

    long offA = 0; int kc3 = 0; int offB = 0;
    for (int kt = 0; kt < 15; kt++){
        char* cur = smem + (kt & 1)*HALF;
        if (kt + 1 < 15){
            char* nxt = smem + ((kt + 1) & 1)*HALF;
            if (kc3 == 2){ offA += 18432 - 256; kc3 = 0; }
            else         { offA += 128; kc3++; }
            offB += 128;
            #pragma unroll
            for (int i = 0; i < 6; i++) gll16(gA[i] + offA, nxt + loA[i]);
            #pragma unroll
            for (int i = 0; i < 2; i++) gll16(gB[i] + offB, nxt + loB[i]);
            asm volatile("s_waitcnt vmcnt(8)" ::: "memory");
        } else {
            asm volatile("s_waitcnt vmcnt(0)" ::: "memory");
        }
        __builtin_amdgcn_s_barrier();
        __builtin_amdgcn_sched_barrier(0);
        char* ldsA = cur;
        char* ldsB = cur + 192*128;
        #pragma unroll
        for (int ks = 0; ks < 2; ks++){
            bf16x8 a[3], bb[4];
            int kb = ks*64 + lq*16;
            #pragma unroll
            for (int mf = 0; mf < 3; mf++) a[mf] = frag_ld(ldsA, wid*48 + mf*16 + l15, kb);
            #pragma unroll
            for (int nf = 0; nf < 4; nf++) bb[nf] = frag_ld(ldsB, nf*16 + l15, kb);
            #pragma unroll
            for (int mf = 0; mf < 3; mf++)
                #pragma unroll
                for (int nf = 0; nf < 4; nf++)
                    acc[mf][nf] = __builtin_amdgcn_mfma_f32_16x16x32_bf16(a[mf], bb[nf], acc[mf][nf], 0, 0, 0);
        }
        __builtin_amdgcn_sched_barrier(0);
        __builtin_amdgcn_s_barrier();
    }
    #pragma unroll
    for (int nf = 0; nf < 4; nf++){
        int col = nf*16 + l15;
        float bb = tb[col];
        #pragma unroll
        for (int mf = 0; mf < 3; mf++){
            int tok = m0 + wid*48 + mf*16 + lq*4;
            f32x4 v = acc[mf][nf];
            #pragma unroll
            for (int r = 0; r < 4; r++)
                ybf[(size_t)(tok+r)*256 + outoff + col] = f2bf(v[r] + bb);
        }
    }
}

// ---------------- y0: grouped V-mix -> ybf cols 0..63 ----------------
__global__ __launch_bounds__(256) void y0_kernel(const unsigned short* __restrict__ fbf,
        const float* __restrict__ gct, unsigned short* __restrict__ ybf){
    int bt = blockIdx.x; int nb = bt*VV;
    __shared__ float X[48*68];
    for (int it = 0; it < 2; it++){
        int idx = it*256 + threadIdx.x;
        if (idx < 384){
            int v = idx >> 3, c8 = idx & 7;
            uint4 u = *(const uint4*)(fbf + (size_t)(nb+v)*256 + c8*8);
            unpk8(u, &X[v*68 + c8*8]);
        }
    }
    __syncthreads();
    int c = threadIdx.x % 64, vv = threadIdx.x / 64;
    int g = c >> 3;
    float acc[12] = {};
    for (int u = 0; u < 48; u++){
        float xv = X[u*68 + c];
        const float* gr = gct + (size_t)(g*48+u)*48 + vv*12;
        float4 g0 = *(const float4*)(gr);
        float4 g1 = *(const float4*)(gr+4);
        float4 g2 = *(const float4*)(gr+8);
        acc[0]+=xv*g0.x; acc[1]+=xv*g0.y; acc[2]+=xv*g0.z;  acc[3]+=xv*g0.w;
        acc[4]+=xv*g1.x; acc[5]+=xv*g1.y; acc[6]+=xv*g1.z;  acc[7]+=xv*g1.w;
        acc[8]+=xv*g2.x; acc[9]+=xv*g2.y; acc[10]+=xv*g2.z; acc[11]+=xv*g2.w;
    }
    #pragma unroll
    for (int j = 0; j < 12; j++)
        ybf[(size_t)(nb + vv*12 + j)*256 + c] = f2bf(acc[j]);
}

// ---------------- y1: grouped temporal conv (k=7) -> ybf cols 64..127 ----------------
__global__ __launch_bounds__(256) void y1_kernel(const unsigned short* __restrict__ fbf,
        const float* __restrict__ tw, const float* __restrict__ tb, unsigned short* __restrict__ ybf){
    int bt = blockIdx.x; int b = bt/TT, t = bt%TT;
    int o = threadIdx.x % 64, vv = threadIdx.x / 64;
    int g = o >> 3;
    float bv = tb[o];
    float acc[12];
    #pragma unroll
    for (int j = 0; j < 12; j++) acc[j] = bv;
    for (int kh = 0; kh < 7; kh++){
        int tt = t + kh - 3;
        if (tt < 0 || tt >= TT) continue;
        float wk[8];
        #pragma unroll
        for (int ci = 0; ci < 8; ci++) wk[ci] = tw[(o*8+ci)*7 + kh];
        int nb2 = (b*TT+tt)*VV;
        #pragma unroll
        for (int j = 0; j < 12; j++){
            uint4 u = *(const uint4*)(fbf + (size_t)(nb2 + vv*12 + j)*256 + 64 + g*8);
            float fv[8]; unpk8(u, fv);
            acc[j] += fv[0]*wk[0]+fv[1]*wk[1]+fv[2]*wk[2]+fv[3]*wk[3]
                    + fv[4]*wk[4]+fv[5]*wk[5]+fv[6]*wk[6]+fv[7]*wk[7];
        }
    }
    int nb = bt*VV;
    #pragma unroll
    for (int j = 0; j < 12; j++)
        ybf[(size_t)(nb + vv*12 + j)*256 + 64 + o] = f2bf(acc[j]);
}

extern "C" void kernel_launch(void* const* d_in, const int* in_sizes, int n_in,
                              void* d_out, int out_size, void* d_ws, size_t ws_size,
                              hipStream_t stream){
    const float* input   = (const float*)d_in[0];
    const float* n1g     = (const float*)d_in[1];
    const float* n1b     = (const float*)d_in[2];
    const float* map_w   = (const float*)d_in[3];
    const float* map_b   = (const float*)d_in[4];
    const float* gconv   = (const float*)d_in[5];
    const float* tconv_w = (const float*)d_in[6];
    const float* tconv_b = (const float*)d_in[7];
    const float* qkv_w0  = (const float*)d_in[8];
    const float* qkv_b0  = (const float*)d_in[9];
    const float* aproj_w0= (const float*)d_in[10];
    const float* aproj_b0= (const float*)d_in[11];
    const float* tcl_w0  = (const float*)d_in[12];
    const float* tcl_b0  = (const float*)d_in[13];
    const float* qkv_w1  = (const float*)d_in[14];
    const float* qkv_b1  = (const float*)d_in[15];
    const float* aproj_w1= (const float*)d_in[16];
    const float* aproj_b1= (const float*)d_in[17];
    const float* tcl_w1  = (const float*)d_in[18];
    const float* tcl_b1  = (const float*)d_in[19];
    const float* proj_w  = (const float*)d_in[20];
    const float* proj_b  = (const float*)d_in[21];
    const float* n2g     = (const float*)d_in[22];
    const float* n2b     = (const float*)d_in[23];
    const float* mlp_w1  = (const float*)d_in[24];
    const float* mlp_b1  = (const float*)d_in[25];
    const float* mlp_w2  = (const float*)d_in[26];
    const float* mlp_b2  = (const float*)d_in[27];

    const size_t Nt = NTOK;
    if (ws_size < 354050048ull) return;

    char* base = (char*)d_ws;
    unsigned short* outtH  = (unsigned short*)base;                  //  50 MB (bf16 outt)
    unsigned short* fbf    = (unsigned short*)(base + 100663296);    //  50 MB
    unsigned short* a0p    = (unsigned short*)(base + 150994944);    //  40 MB
    unsigned short* qkvbuf = (unsigned short*)(base + 191102976);    //  75 MB
    unsigned short* attnout= (unsigned short*)(base + 266600448);    //  25 MB
    unsigned short* A1     = (unsigned short*)(base + 301989888);    //  50 MB
    char* wp = base + 352321536;
    float* gct            = (float*)wp;
    unsigned short* mapT  = (unsigned short*)(wp + 73728);
    unsigned short* projT = mapT + 65536;
    unsigned short* w1T   = projT + 65536;
    unsigned char* w2T8   = (unsigned char*)(w1T + 262144);
    unsigned short* tclT0 = w1T + 262144 + 262144;   // w2T region reused as fp8
    unsigned short* tclT1 = tclT0 + 61440;
    unsigned short* qkvT  = tclT1 + 61440;
    unsigned short* aprojT= qkvT + 24576;

    unsigned char* h8   = (unsigned char*)fbf;   // fp8 Nt x 1024 = 100 MB, spans fbf+a0p+part of qkvbuf (dead)
    unsigned short* xn  = A1;
    unsigned short* ybf = (unsigned short*)d_out;
    unsigned short* xskip = ybf + (size_t)256*Nt;
    float* dout = (float*)d_out;

    prep_weights<<<256, 256, 0, stream>>>(gconv, tcl_w0, tcl_w1, map_w, proj_w, mlp_w1, mlp_w2,
                                          qkv_w0, qkv_w1, aproj_w0, aproj_w1,
                                          gct, mapT, projT, w1T, w2T8, tclT0, tclT1, qkvT, aprojT);
    xpose_ln1<<<NB*TT, 256, 0, stream>>>(input, n1g, n1b, A1, xskip);
    mfma_gemm<256,4><<<1024, 512, 0, stream>>>(A1, mapT, map_b, fbf, nullptr, 256, 2);
    hipMemsetAsync(a0p, 0, A0P_USH*sizeof(unsigned short), stream);
    gemm_k64<0><<<1024, 256, 0, stream>>>(fbf + 128, 512, qkvT,         qkv_b0, qkvbuf);
    gemm_k64<0><<<1024, 256, 0, stream>>>(fbf + 192, 512, qkvT + 12288, qkv_b1, qkvbuf + (size_t)Nt*192);
    attn_win<<<dim3(2048,2), 192, 0, stream>>>(qkvbuf, attnout);
    y0_kernel<<<NB*TT, 256, 0, stream>>>(fbf, gct, ybf);
    y1_kernel<<<NB*TT, 256, 0, stream>>>(fbf, tconv_w, tconv_b, ybf);
    gemm_k64<1><<<1024, 256, 0, stream>>>(attnout,                 128, aprojT,         aproj_b0, a0p);
    tcl_mfma<<<NTOK/192, 256, 0, stream>>>(a0p, tclT0, tcl_b0, ybf, 128);
    gemm_k64<1><<<1024, 256, 0, stream>>>(attnout + (size_t)Nt*64, 128, aprojT + 12288, aproj_b1, a0p);
    tcl_mfma<<<NTOK/192, 256, 0, stream>>>(a0p, tclT1, tcl_b1, ybf, 192);
    proj_ln2<<<512, 512, 0, stream>>>(ybf, projT, proj_b, xskip, n2g, n2b, outtH, xn);
    mfma_gemm<256,2><<<4096, 512, 0, stream>>>(xn, w1T, mlp_b1, nullptr, h8, 1024, 8);
    mfma_final_fp8<<<1024, 512, 0, stream>>>(h8, w2T8, mlp_b2, outtH, dout);
}

// Round 22
// 530.085 us; speedup vs baseline: 1.0494x; 1.0250x over previous
//
#include <hip/hip_runtime.h>
#include <hip/hip_bf16.h>
#include <math.h>

#define NB 32
#define CC 256
#define TT 64
#define VV 48
#define NTOK (NB*TT*VV)   // 98304
#define LNE 1e-5f
#define PROWS 3264        // (4+64)*48
#define A0P_USH ((size_t)NB*PROWS*192)

typedef __attribute__((ext_vector_type(8))) __bf16 bf16x8;
typedef __attribute__((ext_vector_type(4))) float f32x4;

__device__ inline float bfbits2f(unsigned int bits){
    union{unsigned int u; float f;} c; c.u = bits<<16; return c.f;
}
__device__ inline unsigned short f2bf(float x){
    union{ __bf16 h; unsigned short u; } c; c.h = (__bf16)x; return c.u;
}
__device__ inline unsigned char f2fp8(float x){
    int p = __builtin_amdgcn_cvt_pk_fp8_f32(x, x, 0, false);
    return (unsigned char)(p & 0xff);
}
__device__ __forceinline__ void unpk8(uint4 u, float* d){
    d[0]=bfbits2f(u.x&0xffffu); d[1]=bfbits2f(u.x>>16);
    d[2]=bfbits2f(u.y&0xffffu); d[3]=bfbits2f(u.y>>16);
    d[4]=bfbits2f(u.z&0xffffu); d[5]=bfbits2f(u.z>>16);
    d[6]=bfbits2f(u.w&0xffffu); d[7]=bfbits2f(u.w>>16);
}
// 4*gelu(x) via sigmoid form: 4x * rcp(1 + exp(-1.702x)).
__device__ __forceinline__ float gelu4_fast(float x){
    float e = __expf(-1.702f * x);
    return (4.f * x) * __builtin_amdgcn_rcpf(1.f + e);
}

__device__ __forceinline__ void gll16(const char* g, char* l){
    __builtin_amdgcn_global_load_lds(
        (const __attribute__((address_space(1))) unsigned int*)g,
        (__attribute__((address_space(3))) unsigned int*)l, 16, 0, 0);
}

// ---------------- weight prep ----------------
__global__ void prep_weights(const float* gconv, const float* tcl0, const float* tcl1,
                             const float* map_w, const float* proj_w,
                             const float* mlp_w1, const float* mlp_w2,
                             const float* qkv_w0, const float* qkv_w1,
                             const float* aproj_w0, const float* aproj_w1,
                             float* gct,
                             unsigned short* mapT, unsigned short* projT,
                             unsigned short* w1T, unsigned char* w2T8,
                             unsigned short* tclT0, unsigned short* tclT1,
                             unsigned short* qkvT, unsigned short* aprojT){
    int tid = blockIdx.x*blockDim.x + threadIdx.x;
    int stride = gridDim.x*blockDim.x;
    for (int i = tid; i < 8*48*48; i += stride){
        int g = i/(48*48); int r = i%(48*48); int u = r/48; int v = r%48;
        gct[i] = gconv[(g*48+v)*48+u];
    }
    for (int i = tid; i < 64*960; i += stride){
        int o = i/960, col = i%960, kh = col/192, c = col%192;
        tclT0[i] = f2bf(tcl0[(o*192+c)*5+kh]);
        tclT1[i] = f2bf(tcl1[(o*192+c)*5+kh]);
    }
    for (int i = tid; i < 65536; i += stride){
        int n = i>>8, k = i&255;
        mapT[i] = f2bf(map_w[k*256+n]);
        projT[i] = f2bf(proj_w[k*256+n]);
    }
    for (int i = tid; i < 262144; i += stride){
        int n = i>>8, k = i&255;
        w1T[i] = f2bf(mlp_w1[k*1024+n]);
    }
    // w2T8[n][k] = fp8(mlp_w2[k][n] * 32)
    for (int i = tid; i < 262144; i += stride){
        int n = i>>10, k = i&1023;
        w2T8[i] = f2fp8(mlp_w2[k*256+n] * 32.f);
    }
    for (int i = tid; i < 12288; i += stride){
        int n = i/64, k = i%64;
        qkvT[i]          = f2bf(qkv_w0[k*192+n]);
        qkvT[12288+i]    = f2bf(qkv_w1[k*192+n]);
        aprojT[i]        = f2bf(aproj_w0[k*192+n]);
        aprojT[12288+i]  = f2bf(aproj_w1[k*192+n]);
    }
}

// ---------------- LN1 + transpose -> A1 bf16 [N][256] + raw skip copy ----------------
__global__ __launch_bounds__(256) void xpose_ln1(const float* __restrict__ x,
        const float* __restrict__ g, const float* __restrict__ bb,
        unsigned short* __restrict__ A1, unsigned short* __restrict__ xskip){
    int bt = blockIdx.x; int b = bt/TT, t = bt%TT;
    __shared__ float X[48*257];
    __shared__ float S[4][48], SS[4][48], sm[48], sv[48];
    int tid = threadIdx.x;
    const float* xb = x + (size_t)b*256*3072 + (size_t)t*48;
    for (int it = 0; it < 12; it++){
        int idx = it*256 + tid;
        int c = idx/12, q = idx%12;
        float4 v = *(const float4*)(xb + (size_t)c*3072 + q*4);
        X[(q*4+0)*257 + c] = v.x;
        X[(q*4+1)*257 + c] = v.y;
        X[(q*4+2)*257 + c] = v.z;
        X[(q*4+3)*257 + c] = v.w;
    }
    __syncthreads();
    if (tid < 192){
        int v = tid % 48, w = tid / 48;
        float s = 0.f, ss = 0.f;
        for (int c = w*64; c < w*64+64; c++){
            float val = X[v*257 + c];
            s += val; ss += val*val;
        }
        S[w][v] = s; SS[w][v] = ss;
    }
    __syncthreads();
    if (tid < 48){
        float s = S[0][tid]+S[1][tid]+S[2][tid]+S[3][tid];
        float q = SS[0][tid]+SS[1][tid]+SS[2][tid]+SS[3][tid];
        float m = s*(1.f/256);
        sm[tid] = m; sv[tid] = rsqrtf(q*(1.f/256) - m*m + LNE);
    }
    __syncthreads();
    int nb = bt*48;
    for (int it = 0; it < 12; it++){
        int idx = it*256 + tid;
        int v = idx>>6, cq = idx&63;
        float m = sm[v], rs = sv[v];
        float4 g4 = *(const float4*)(g + cq*4);
        float4 b4 = *(const float4*)(bb + cq*4);
        float x0 = X[v*257 + cq*4+0], x1 = X[v*257 + cq*4+1];
        float x2 = X[v*257 + cq*4+2], x3 = X[v*257 + cq*4+3];
        ushort4 u;
        u.x = f2bf((x0-m)*rs*g4.x + b4.x);
        u.y = f2bf((x1-m)*rs*g4.y + b4.y);
        u.z = f2bf((x2-m)*rs*g4.z + b4.z);
        u.w = f2bf((x3-m)*rs*g4.w + b4.w);
        *(ushort4*)(A1 + (size_t)(nb+v)*256 + cq*4) = u;
        ushort4 s;
        s.x = f2bf(x0); s.y = f2bf(x1); s.z = f2bf(x2); s.w = f2bf(x3);
        *(ushort4*)(xskip + (size_t)(nb+v)*256 + cq*4) = s;
    }
}

// ---------------- swizzled staging (single-shot, for k64 GEMM) ----------------
__device__ __forceinline__ void stage_swz(const char* src, size_t rowbytes, char* lds,
                                          int nchunks, int tid){
    for (int c = tid; c < nchunks; c += 256){
        int p = c << 4;
        int r = p >> 7;
        int kl = (p & 127) ^ ((r & 7) << 4);
        gll16(src + (size_t)r*rowbytes + kl, lds + p);
    }
}

__device__ __forceinline__ bf16x8 frag_ld(const char* lds, int R, int kb){
    return *(const bf16x8*)(lds + R*128 + (kb ^ ((R & 7) << 4)));
}
__device__ __forceinline__ long frag_ld8(const char* lds, int R, int kb){
    return *(const long*)(lds + R*128 + (kb ^ ((R & 7) << 4)));
}

// ---------------- MFMA GEMM: BM=192, BN=128, 8 waves, dbuf + counted vmcnt ----------------
// EPI 2: outH8 = fp8(gelu4(acc + bias))      [LDS repack, 16B stores]
// EPI 4: outH  = bf16(acc + bias)            [LDS repack, 16B stores]
template<int KTOT, int EPI>
__global__ __launch_bounds__(512, 4) void mfma_gemm(
    const unsigned short* __restrict__ A, const unsigned short* __restrict__ BT,
    const float* __restrict__ bias,
    unsigned short* __restrict__ outH, unsigned char* __restrict__ outH8,
    int ncols, int nx){

    constexpr int BM = 192, BN = 128;
    constexpr int HALF = (BM+BN)*128;           // 40960
    __shared__ __align__(16) char smem[2*HALF]; // 81920 -> 2 blocks/CU
    int tid = threadIdx.x, lane = tid & 63;
    int wid = tid >> 6;
    int wm = wid >> 1, wn = wid & 1;
    int l15 = lane & 15, lq = lane >> 4;
    int bid = blockIdx.x;
    int per = gridDim.x >> 3;
    int wkid = (bid & 7)*per + (bid >> 3);
    int m0 = (wkid / nx) * BM, n0 = (wkid % nx) * BN;
    const size_t arb = KTOT*2, brb = KTOT*2;
    constexpr int KT = KTOT/64;

    const char* gA[3]; int loA[3];
    const char* gB[2]; int loB[2];
    {
        const char* Ab = (const char*)A + (size_t)m0*arb;
        const char* Bb = (const char*)BT + (size_t)n0*brb;
        #pragma unroll
        for (int i = 0; i < 3; i++){
            int c = tid + i*512;
            int p = c << 4, r = p >> 7;
            int kl = (p & 127) ^ ((r & 7) << 4);
            gA[i] = Ab + (size_t)r*arb + kl; loA[i] = p;
        }
        #pragma unroll
        for (int i = 0; i < 2; i++){
            int c = tid + i*512;
            int p = c << 4, r = p >> 7;
            int kl = (p & 127) ^ ((r & 7) << 4);
            gB[i] = Bb + (size_t)r*brb + kl; loB[i] = BM*128 + p;
        }
    }

    f32x4 acc[3][4];
    #pragma unroll
    for (int i = 0; i < 3; i++)
        #pragma unroll
        for (int j = 0; j < 4; j++){ f32x4 z = {0.f,0.f,0.f,0.f}; acc[i][j] = z; }

    #pragma unroll
    for (int i = 0; i < 3; i++) gll16(gA[i], smem + loA[i]);
    #pragma unroll
    for (int i = 0; i < 2; i++) gll16(gB[i], smem + loB[i]);

    int koff = 128;
    for (int kt = 0; kt < KT; kt++){
        char* cur = smem + (kt & 1)*HALF;
        if (kt + 1 < KT){
            char* nxt = smem + ((kt + 1) & 1)*HALF;
            #pragma unroll
            for (int i = 0; i < 3; i++) gll16(gA[i] + koff, nxt + loA[i]);
            #pragma unroll
            for (int i = 0; i < 2; i++) gll16(gB[i] + koff, nxt + loB[i]);
            koff += 128;
            asm volatile("s_waitcnt vmcnt(5)" ::: "memory");
        } else {
            asm volatile("s_waitcnt vmcnt(0)" ::: "memory");
        }
        __builtin_amdgcn_s_barrier();
        __builtin_amdgcn_sched_barrier(0);
        char* ldsA = cur;
        char* ldsB = cur + BM*128;
        #pragma unroll
        for (int ks = 0; ks < 2; ks++){
            bf16x8 a[3], b[4];
            int kb = ks*64 + lq*16;
            #pragma unroll
            for (int mf = 0; mf < 3; mf++) a[mf] = frag_ld(ldsA, wm*48 + mf*16 + l15, kb);
            #pragma unroll
            for (int nf = 0; nf < 4; nf++) b[nf] = frag_ld(ldsB, wn*64 + nf*16 + l15, kb);
            #pragma unroll
            for (int mf = 0; mf < 3; mf++)
                #pragma unroll
                for (int nf = 0; nf < 4; nf++)
                    acc[mf][nf] = __builtin_amdgcn_mfma_f32_16x16x32_bf16(a[mf], b[nf], acc[mf][nf], 0, 0, 0);
        }
        __builtin_amdgcn_sched_barrier(0);
        __builtin_amdgcn_s_barrier();
    }

    if constexpr (EPI == 4){
        unsigned short* Hs = (unsigned short*)smem;   // [192][136]
        #pragma unroll
        for (int nf = 0; nf < 4; nf++){
            int col = wn*64 + nf*16 + l15;
            float bb = bias[n0 + col];
            #pragma unroll
            for (int mf = 0; mf < 3; mf++){
                int row = wm*48 + mf*16 + lq*4;
                f32x4 v = acc[mf][nf];
                #pragma unroll
                for (int r = 0; r < 4; r++)
                    Hs[(row+r)*136 + col] = f2bf(v[r] + bb);
            }
        }
        __syncthreads();
        for (int idx = tid; idx < 192*16; idx += 512){
            int row = idx >> 4, c8 = idx & 15;
            *(uint4*)(outH + (size_t)(m0+row)*ncols + n0 + c8*8) =
                *(const uint4*)(Hs + row*136 + c8*8);
        }
    }
    if constexpr (EPI == 2){
        unsigned char* Hc = (unsigned char*)smem;     // [192][144] fp8
        #pragma unroll
        for (int nf = 0; nf < 4; nf++){
            int col = wn*64 + nf*16 + l15;
            float bb = bias[n0 + col];
            #pragma unroll
            for (int mf = 0; mf < 3; mf++){
                int row = wm*48 + mf*16 + lq*4;
                f32x4 v = acc[mf][nf];
                #pragma unroll
                for (int r = 0; r < 4; r++){
                    float t0 = gelu4_fast(v[r] + bb);
                    Hc[(row+r)*144 + col] = f2fp8(t0);
                }
            }
        }
        __syncthreads();
        for (int idx = tid; idx < 192*8; idx += 512){
            int row = idx >> 3, c16 = idx & 7;
            *(uint4*)(outH8 + (size_t)(m0+row)*ncols + n0 + c16*16) =
                *(const uint4*)(Hc + row*144 + c16*16);
        }
    }
}

// ---------------- final GEMM in fp8: K=1024 as 8 tiles of K=128 (128B rows) ----------------
__global__ __launch_bounds__(512, 4) void mfma_final_fp8(
    const unsigned char* __restrict__ A, const unsigned char* __restrict__ BT,
    const float* __restrict__ bias, const unsigned short* __restrict__ extraH,
    float* __restrict__ outF){

    constexpr int BM = 192, BN = 128, NX = 2;
    constexpr int HALF = (BM+BN)*128;           // 40960
    __shared__ __align__(16) char smem[2*HALF]; // 81920 -> 2 blocks/CU
    int tid = threadIdx.x, lane = tid & 63;
    int wid = tid >> 6;
    int wm = wid >> 1, wn = wid & 1;
    int l15 = lane & 15, lq = lane >> 4;
    int bid = blockIdx.x;
    int per = gridDim.x >> 3;
    int wkid = (bid & 7)*per + (bid >> 3);
    int m0 = (wkid / NX) * BM, n0 = (wkid % NX) * BN;
    const size_t arb = 1024, brb = 1024;
    constexpr int KT = 8;

    const char* gA[3]; int loA[3];
    const char* gB[2]; int loB[2];
    {
        const char* Ab = (const char*)A + (size_t)m0*arb;
        const char* Bb = (const char*)BT + (size_t)n0*brb;
        #pragma unroll
        for (int i = 0; i < 3; i++){
            int c = tid + i*512;
            int p = c << 4, r = p >> 7;
            int kl = (p & 127) ^ ((r & 7) << 4);
            gA[i] = Ab + (size_t)r*arb + kl; loA[i] = p;
        }
        #pragma unroll
        for (int i = 0; i < 2; i++){
            int c = tid + i*512;
            int p = c << 4, r = p >> 7;
            int kl = (p & 127) ^ ((r & 7) << 4);
            gB[i] = Bb + (size_t)r*brb + kl; loB[i] = BM*128 + p;
        }
    }

    f32x4 acc[3][4];
    #pragma unroll
    for (int i = 0; i < 3; i++)
        #pragma unroll
        for (int j = 0; j < 4; j++){ f32x4 z = {0.f,0.f,0.f,0.f}; acc[i][j] = z; }

    #pragma unroll
    for (int i = 0; i < 3; i++) gll16(gA[i], smem + loA[i]);
    #pragma unroll
    for (int i = 0; i < 2; i++) gll16(gB[i], smem + loB[i]);

    int koff = 128;
    for (int kt = 0; kt < KT; kt++){
        char* cur = smem + (kt & 1)*HALF;
        if (kt + 1 < KT){
            char* nxt = smem + ((kt + 1) & 1)*HALF;
            #pragma unroll
            for (int i = 0; i < 3; i++) gll16(gA[i] + koff, nxt + loA[i]);
            #pragma unroll
            for (int i = 0; i < 2; i++) gll16(gB[i] + koff, nxt + loB[i]);
            koff += 128;
            asm volatile("s_waitcnt vmcnt(5)" ::: "memory");
        } else {
            asm volatile("s_waitcnt vmcnt(0)" ::: "memory");
        }
        __builtin_amdgcn_s_barrier();
        __builtin_amdgcn_sched_barrier(0);
        char* ldsA = cur;
        char* ldsB = cur + BM*128;
        #pragma unroll
        for (int ks = 0; ks < 4; ks++){
            long a[3], b[4];
            int kb = ks*32 + lq*8;
            #pragma unroll
            for (int mf = 0; mf < 3; mf++) a[mf] = frag_ld8(ldsA, wm*48 + mf*16 + l15, kb);
            #pragma unroll
            for (int nf = 0; nf < 4; nf++) b[nf] = frag_ld8(ldsB, wn*64 + nf*16 + l15, kb);
            #pragma unroll
            for (int mf = 0; mf < 3; mf++)
                #pragma unroll
                for (int nf = 0; nf < 4; nf++)
                    acc[mf][nf] = __builtin_amdgcn_mfma_f32_16x16x32_fp8_fp8(a[mf], b[nf], acc[mf][nf], 0, 0, 0);
        }
        __builtin_amdgcn_sched_barrier(0);
        __builtin_amdgcn_s_barrier();
    }

    // epilogue: dout NCHW = acc/128 + bias + resid (bf16 outtH), two-pass transpose
    float* Tt = (float*)smem;  // [64 cols][196]
    #pragma unroll
    for (int ph = 0; ph < 2; ph++){
        __syncthreads();
        if (wn == ph){
            #pragma unroll
            for (int nf = 0; nf < 4; nf++){
                int lc = nf*16 + l15;
                float bb = bias[n0 + ph*64 + lc];
                #pragma unroll
                for (int mf = 0; mf < 3; mf++){
                    int tl = wm*48 + mf*16 + lq*4;
                    f32x4 v = acc[mf][nf];
                    #pragma unroll
                    for (int r = 0; r < 4; r++){
                        float resid = bfbits2f(extraH[(size_t)(m0+tl+r)*256 + n0 + ph*64 + lc]);
                        Tt[lc*196 + tl + r] = v[r]*0.0078125f + bb + resid;
                    }
                }
            }
        }
        __syncthreads();
        {
            int lc = tid & 63, btl = (tid>>6)&3, dup = tid>>8;
            int gtok = m0 + btl*48;
            int bg = gtok/3072, t = (gtok%3072)/48;
            float* dst = outF + ((size_t)(bg*256 + n0 + ph*64 + lc)*64 + t)*48 + dup*24;
            const float* tr = Tt + lc*196 + btl*48 + dup*24;
            #pragma unroll
            for (int j = 0; j < 6; j++)
                *(float4*)(dst + j*4) = *(const float4*)(tr + j*4);
        }
    }
}

// ---------------- proj GEMM fused with skip-add + LN2: BM=192, BN=256, K=256 ----------------
__global__ __launch_bounds__(512, 2) void proj_ln2(
    const unsigned short* __restrict__ A, const unsigned short* __restrict__ BT,
    const float* __restrict__ bias, const unsigned short* __restrict__ xskip,
    const float* __restrict__ n2g, const float* __restrict__ n2b,
    unsigned short* __restrict__ outtH, unsigned short* __restrict__ xn){

    constexpr int BM = 192, BN = 256, KTOT = 256;
    constexpr int HALF = (BM+BN)*128;
    __shared__ __align__(16) char smem[2*HALF];
    int tid = threadIdx.x, lane = tid & 63;
    int wid = tid >> 6;
    int wm = wid >> 1, wn = wid & 1;
    int l15 = lane & 15, lq = lane >> 4;
    int bid = blockIdx.x;
    int per = gridDim.x >> 3;
    int wkid = (bid & 7)*per + (bid >> 3);
    int m0 = wkid * BM;
    const size_t arb = KTOT*2, brb = KTOT*2;
    constexpr int KT = KTOT/64;

    const char* gA[3]; int loA[3];
    const char* gB[4]; int loB[4];
    {
        const char* Ab = (const char*)A + (size_t)m0*arb;
        const char* Bb = (const char*)BT;
        #pragma unroll
        for (int i = 0; i < 3; i++){
            int c = tid + i*512;
            int p = c << 4, r = p >> 7;
            int kl = (p & 127) ^ ((r & 7) << 4);
            gA[i] = Ab + (size_t)r*arb + kl; loA[i] = p;
        }
        #pragma unroll
        for (int i = 0; i < 4; i++){
            int c = tid + i*512;
            int p = c << 4, r = p >> 7;
            int kl = (p & 127) ^ ((r & 7) << 4);
            gB[i] = Bb + (size_t)r*brb + kl; loB[i] = BM*128 + p;
        }
    }

    f32x4 acc[3][8];
    #pragma unroll
    for (int i = 0; i < 3; i++)
        #pragma unroll
        for (int j = 0; j < 8; j++){ f32x4 z = {0.f,0.f,0.f,0.f}; acc[i][j] = z; }

    #pragma unroll
    for (int i = 0; i < 3; i++) gll16(gA[i], smem + loA[i]);
    #pragma unroll
    for (int i = 0; i < 4; i++) gll16(gB[i], smem + loB[i]);

    int koff = 128;
    for (int kt = 0; kt < KT; kt++){
        char* cur = smem + (kt & 1)*HALF;
        if (kt + 1 < KT){
            char* nxt = smem + ((kt + 1) & 1)*HALF;
            #pragma unroll
            for (int i = 0; i < 3; i++) gll16(gA[i] + koff, nxt + loA[i]);
            #pragma unroll
            for (int i = 0; i < 4; i++) gll16(gB[i] + koff, nxt + loB[i]);
            koff += 128;
            asm volatile("s_waitcnt vmcnt(7)" ::: "memory");
        } else {
            asm volatile("s_waitcnt vmcnt(0)" ::: "memory");
        }
        __builtin_amdgcn_s_barrier();
        __builtin_amdgcn_sched_barrier(0);
        char* ldsA = cur;
        char* ldsB = cur + BM*128;
        #pragma unroll
        for (int ks = 0; ks < 2; ks++){
            bf16x8 a[3], b[8];
            int kb = ks*64 + lq*16;
            #pragma unroll
            for (int mf = 0; mf < 3; mf++) a[mf] = frag_ld(ldsA, wm*48 + mf*16 + l15, kb);
            #pragma unroll
            for (int nf = 0; nf < 8; nf++) b[nf] = frag_ld(ldsB, wn*128 + nf*16 + l15, kb);
            #pragma unroll
            for (int mf = 0; mf < 3; mf++)
                #pragma unroll
                for (int nf = 0; nf < 8; nf++)
                    acc[mf][nf] = __builtin_amdgcn_mfma_f32_16x16x32_bf16(a[mf], b[nf], acc[mf][nf], 0, 0, 0);
        }
        __builtin_amdgcn_sched_barrier(0);
        __builtin_amdgcn_s_barrier();
    }

    unsigned short* Hs = (unsigned short*)smem;
    float* Sred = (float*)(smem + 101376);
    float s_acc[3][4], ss_acc[3][4];
    #pragma unroll
    for (int i = 0; i < 3; i++)
        #pragma unroll
        for (int r = 0; r < 4; r++){ s_acc[i][r] = 0.f; ss_acc[i][r] = 0.f; }

    #pragma unroll
    for (int nf = 0; nf < 8; nf++){
        int col = wn*128 + nf*16 + l15;
        float bb = bias[col];
        #pragma unroll
        for (int mf = 0; mf < 3; mf++){
            int row = wm*48 + mf*16 + lq*4;
            f32x4 v = acc[mf][nf];
            #pragma unroll
            for (int r = 0; r < 4; r++){
                float sk = bfbits2f(xskip[(size_t)(m0+row+r)*256 + col]);
                unsigned short us = f2bf(v[r] + bb + sk);
                Hs[(row+r)*264 + col] = us;
                float tf = bfbits2f(us);
                s_acc[mf][r] += tf; ss_acc[mf][r] += tf*tf;
            }
        }
    }
    #pragma unroll
    for (int mf = 0; mf < 3; mf++)
        #pragma unroll
        for (int r = 0; r < 4; r++){
            float s = s_acc[mf][r], ss = ss_acc[mf][r];
            #pragma unroll
            for (int d = 1; d < 16; d <<= 1){
                s  += __shfl_xor(s, d);
                ss += __shfl_xor(ss, d);
            }
            if (l15 == 0){
                int row = wm*48 + mf*16 + lq*4 + r;
                Sred[wn*192 + row] = s;
                Sred[384 + wn*192 + row] = ss;
            }
        }
    __syncthreads();
    if (tid < 192){
        float s  = Sred[tid] + Sred[192+tid];
        float ss = Sred[384+tid] + Sred[576+tid];
        float m = s*(1.f/256);
        Sred[tid] = m;
        Sred[192+tid] = rsqrtf(ss*(1.f/256) - m*m + LNE);
    }
    __syncthreads();
    for (int idx = tid; idx < 192*32; idx += 512){
        int row = idx >> 5, c8 = idx & 31;
        uint4 hv = *(const uint4*)(Hs + row*264 + c8*8);
        *(uint4*)(outtH + (size_t)(m0+row)*256 + c8*8) = hv;
        float v[8]; unpk8(hv, v);
        float m = Sred[row], rs = Sred[192+row];
        unsigned int w[4];
        #pragma unroll
        for (int j = 0; j < 4; j++){
            float g0 = n2g[c8*8 + j*2],   b0 = n2b[c8*8 + j*2];
            float g1 = n2g[c8*8 + j*2+1], b1 = n2b[c8*8 + j*2+1];
            unsigned int lo = f2bf((v[j*2]  -m)*rs*g0 + b0);
            unsigned int hi = f2bf((v[j*2+1]-m)*rs*g1 + b1);
            w[j] = lo | (hi << 16);
        }
        uint4 o; o.x=w[0]; o.y=w[1]; o.z=w[2]; o.w=w[3];
        *(uint4*)(xn + (size_t)(m0+row)*256 + c8*8) = o;
    }
}

// ---------------- K=64 MFMA GEMM: BM=96, BN=192, 4 waves ----------------
template<int EPI>
__global__ __launch_bounds__(256) void gemm_k64(
    const unsigned short* __restrict__ A, int arb,
    const unsigned short* __restrict__ BT,
    const float* __restrict__ bias,
    unsigned short* __restrict__ out){
    __shared__ __align__(16) char smem[96*128 + 192*128];
    char* ldsA = smem;
    char* ldsB = smem + 96*128;
    int tid = threadIdx.x, lane = tid & 63;
    int wid = tid >> 6, wm = wid >> 1, wn = wid & 1;
    int l15 = lane & 15, lq = lane >> 4;
    int m0 = blockIdx.x * 96;

    stage_swz((const char*)A + (size_t)m0*arb, arb, ldsA, 96*8, tid);
    stage_swz((const char*)BT, 128, ldsB, 192*8, tid);
    __syncthreads();

    f32x4 acc[3][6];
    #pragma unroll
    for (int i = 0; i < 3; i++)
        #pragma unroll
        for (int j = 0; j < 6; j++){ f32x4 z = {0.f,0.f,0.f,0.f}; acc[i][j] = z; }

    #pragma unroll
    for (int ks = 0; ks < 2; ks++){
        bf16x8 a[3], b[6];
        int kb = ks*64 + lq*16;
        #pragma unroll
        for (int mf = 0; mf < 3; mf++) a[mf] = frag_ld(ldsA, wm*48 + mf*16 + l15, kb);
        #pragma unroll
        for (int nf = 0; nf < 6; nf++) b[nf] = frag_ld(ldsB, wn*96 + nf*16 + l15, kb);
        #pragma unroll
        for (int mf = 0; mf < 3; mf++)
            #pragma unroll
            for (int nf = 0; nf < 6; nf++)
                acc[mf][nf] = __builtin_amdgcn_mfma_f32_16x16x32_bf16(a[mf], b[nf], acc[mf][nf], 0, 0, 0);
    }

    size_t row0;
    if constexpr (EPI == 0) row0 = (size_t)m0;
    else {
        int b = m0/3072;
        row0 = (size_t)b*PROWS + 192 + (m0 - b*3072);
    }
    #pragma unroll
    for (int nf = 0; nf < 6; nf++){
        int col = wn*96 + nf*16 + l15;
        float bb = bias[col];
        #pragma unroll
        for (int mf = 0; mf < 3; mf++){
            size_t rr = row0 + wm*48 + mf*16 + lq*4;
            f32x4 v = acc[mf][nf];
            #pragma unroll
            for (int r = 0; r < 4; r++)
                out[(rr+r)*192 + col] = f2bf(v[r] + bb);
        }
    }
}

// ---------------- windowed attention ----------------
__global__ __launch_bounds__(192) void attn_win(
        const unsigned short* __restrict__ qkvbuf,
        unsigned short* __restrict__ attnout){
    int win = blockIdx.x, br = blockIdx.y;
    size_t base = (size_t)br*NTOK + (size_t)win*48;
    __shared__ float Q[48*196];
    int tid = threadIdx.x;
    const unsigned short* src = qkvbuf + base*192;
    for (int i = 0; i < 6; i++){
        int ch = i*192 + tid;
        int v = ch/24, c8 = ch%24;
        uint4 u = *(const uint4*)(src + (size_t)v*192 + c8*8);
        unpk8(u, &Q[v*196 + c8*8]);
    }
    __syncthreads();
    int u = tid & 15, gh = tid >> 4, g = gh >> 2, h = gh & 3;
    int ru = g*16 + u;
    float qreg[16];
    #pragma unroll
    for (int d = 0; d < 16; d++) qreg[d] = Q[ru*196 + h*16 + d];
    float sc[16]; float mx = -1e30f;
    #pragma unroll
    for (int w = 0; w < 16; w++){
        float s = 0.f;
        #pragma unroll
        for (int d = 0; d < 16; d++) s += qreg[d]*Q[(g*16+w)*196 + 64 + h*16 + d];
        s *= 0.5f; sc[w] = s; mx = fmaxf(mx, s);
    }
    float sum = 0.f;
    #pragma unroll
    for (int w = 0; w < 16; w++){ sc[w] = __expf(sc[w]-mx); sum += sc[w]; }
    float inv = __builtin_amdgcn_rcpf(sum);
    unsigned int w32[8];
    #pragma unroll
    for (int dp = 0; dp < 8; dp++){
        float o0 = 0.f, o1 = 0.f;
        #pragma unroll
        for (int w = 0; w < 16; w++){
            float p = sc[w];
            o0 += p*Q[(g*16+w)*196 + 128 + h*16 + dp*2];
            o1 += p*Q[(g*16+w)*196 + 128 + h*16 + dp*2+1];
        }
        w32[dp] = (unsigned int)f2bf(o0*inv) | ((unsigned int)f2bf(o1*inv) << 16);
    }
    unsigned short* dst = attnout + (base + ru)*64 + h*16;
    uint4 q0; q0.x=w32[0]; q0.y=w32[1]; q0.z=w32[2]; q0.w=w32[3];
    uint4 q1; q1.x=w32[4]; q1.y=w32[5]; q1.z=w32[6]; q1.w=w32[7];
    *(uint4*)(dst)   = q0;
    *(uint4*)(dst+8) = q1;
}

// ---------------- tcl as MFMA GEMM: K=960 (15 tiles), dbuf + counted vmcnt ----------------
__global__ __launch_bounds__(256) void tcl_mfma(const unsigned short* __restrict__ A0p,
        const unsigned short* __restrict__ BT, const float* __restrict__ tb,
        unsigned short* __restrict__ ybf, int outoff){
    constexpr int HALF = (192+64)*128;
    __shared__ __align__(16) char smem[2*HALF];
    int tid = threadIdx.x, lane = tid & 63;
    int wid = tid >> 6;
    int l15 = lane & 15, lq = lane >> 4;
    int bid = blockIdx.x;
    int per = gridDim.x >> 3;
    int wkid = (bid & 7)*per + (bid >> 3);
    int m0 = wkid * 192;
    int b = m0 / 3072;
    long brow0 = (long)b*PROWS + 192 + (m0 - b*3072);

    const char* gA[6]; int loA[6];
    const char* gB[2]; int loB[2];
    {
        const char* Ab = (const char*)A0p + (brow0 - 192)*384;
        #pragma unroll
        for (int i = 0; i < 6; i++){
            int c = tid + i*256;
            int p = c << 4, r = p >> 7;
            int kl = (p & 127) ^ ((r & 7) << 4);
            gA[i] = Ab + (size_t)r*384 + kl; loA[i] = p;
        }
        #pragma unroll
        for (int i = 0; i < 2; i++){
            int c = tid + i*256;
            int p = c << 4, r = p >> 7;
            int kl = (p & 127) ^ ((r & 7) << 4);
            gB[i] = (const char*)BT + (size_t)r*1920 + kl; loB[i] = 192*128 + p;
        }
    }

    f32x4 acc[3][4];
    #pragma unroll
    for (int i = 0; i < 3; i++)
        #pragma unroll
        for (int j = 0; j < 4; j++){ f32x4 z = {0.f,0.f,0.f,0.f}; acc[i][j] = z; }

    #pragma unroll
    for (int i = 0; i < 6; i++) gll16(gA[i], smem + loA[i]);
    #pragma unroll
    for (int i = 0; i < 2; i++) gll16(gB[i], smem + loB[i]);

    long offA = 0; int kc3 = 0; int offB = 0;
    for (int kt = 0; kt < 15; kt++){
        char* cur = smem + (kt & 1)*HALF;
        if (kt + 1 < 15){
            char* nxt = smem + ((kt + 1) & 1)*HALF;
            if (kc3 == 2){ offA += 18432 - 256; kc3 = 0; }
            else         { offA += 128; kc3++; }
            offB += 128;
            #pragma unroll
            for (int i = 0; i < 6; i++) gll16(gA[i] + offA, nxt + loA[i]);
            #pragma unroll
            for (int i = 0; i < 2; i++) gll16(gB[i] + offB, nxt + loB[i]);
            asm volatile("s_waitcnt vmcnt(8)" ::: "memory");
        } else {
            asm volatile("s_waitcnt vmcnt(0)" ::: "memory");
        }
        __builtin_amdgcn_s_barrier();
        __builtin_amdgcn_sched_barrier(0);
        char* ldsA = cur;
        char* ldsB = cur + 192*128;
        #pragma unroll
        for (int ks = 0; ks < 2; ks++){
            bf16x8 a[3], bb[4];
            int kb = ks*64 + lq*16;
            #pragma unroll
            for (int mf = 0; mf < 3; mf++) a[mf] = frag_ld(ldsA, wid*48 + mf*16 + l15, kb);
            #pragma unroll
            for (int nf = 0; nf < 4; nf++) bb[nf] = frag_ld(ldsB, nf*16 + l15, kb);
            #pragma unroll
            for (int mf = 0; mf < 3; mf++)
                #pragma unroll
                for (int nf = 0; nf < 4; nf++)
                    acc[mf][nf] = __builtin_amdgcn_mfma_f32_16x16x32_bf16(a[mf], bb[nf], acc[mf][nf], 0, 0, 0);
        }
        __builtin_amdgcn_sched_barrier(0);
        __builtin_amdgcn_s_barrier();
    }
    #pragma unroll
    for (int nf = 0; nf < 4; nf++){
        int col = nf*16 + l15;
        float bb = tb[col];
        #pragma unroll
        for (int mf = 0; mf < 3; mf++){
            int tok = m0 + wid*48 + mf*16 + lq*4;
            f32x4 v = acc[mf][nf];
            #pragma unroll
            for (int r = 0; r < 4; r++)
                ybf[(size_t)(tok+r)*256 + outoff + col] = f2bf(v[r] + bb);
        }
    }
}

// ---------------- y0: grouped V-mix -> ybf cols 0..63 ----------------
__global__ __launch_bounds__(256) void y0_kernel(const unsigned short* __restrict__ fbf,
        const float* __restrict__ gct, unsigned short* __restrict__ ybf){
    int bt = blockIdx.x; int nb = bt*VV;
    __shared__ float X[48*68];
    for (int it = 0; it < 2; it++){
        int idx = it*256 + threadIdx.x;
        if (idx < 384){
            int v = idx >> 3, c8 = idx & 7;
            uint4 u = *(const uint4*)(fbf + (size_t)(nb+v)*256 + c8*8);
            unpk8(u, &X[v*68 + c8*8]);
        }
    }
    __syncthreads();
    int c = threadIdx.x % 64, vv = threadIdx.x / 64;
    int g = c >> 3;
    float acc[12] = {};
    for (int u = 0; u < 48; u++){
        float xv = X[u*68 + c];
        const float* gr = gct + (size_t)(g*48+u)*48 + vv*12;
        float4 g0 = *(const float4*)(gr);
        float4 g1 = *(const float4*)(gr+4);
        float4 g2 = *(const float4*)(gr+8);
        acc[0]+=xv*g0.x; acc[1]+=xv*g0.y; acc[2]+=xv*g0.z;  acc[3]+=xv*g0.w;
        acc[4]+=xv*g1.x; acc[5]+=xv*g1.y; acc[6]+=xv*g1.z;  acc[7]+=xv*g1.w;
        acc[8]+=xv*g2.x; acc[9]+=xv*g2.y; acc[10]+=xv*g2.z; acc[11]+=xv*g2.w;
    }
    #pragma unroll
    for (int j = 0; j < 12; j++)
        ybf[(size_t)(nb + vv*12 + j)*256 + c] = f2bf(acc[j]);
}

// ---------------- y1: grouped temporal conv (k=7), LDS-staged taps -> ybf cols 64..127 ----------------
__global__ __launch_bounds__(256) void y1_kernel(const unsigned short* __restrict__ fbf,
        const float* __restrict__ tw, const float* __restrict__ tb, unsigned short* __restrict__ ybf){
    int bt = blockIdx.x; int b = bt/TT, t = bt%TT;
    __shared__ unsigned short W[7*48*64];   // 43 KB: [kh][v][ch 64..127]
    int tid = threadIdx.x;
    // coalesced staging: chunk idx -> LDS ushort index 8*idx (linear), zero-pad invalid taps
    for (int idx = tid; idx < 2688; idx += 256){
        int kh = idx/384, rem = idx - kh*384;
        int v = rem >> 3, c8 = rem & 7;
        int tt = t + kh - 3;
        uint4 u; u.x = 0; u.y = 0; u.z = 0; u.w = 0;
        if (tt >= 0 && tt < TT)
            u = *(const uint4*)(fbf + ((size_t)(b*TT+tt)*VV + v)*256 + 64 + c8*8);
        *(uint4*)(&W[idx*8]) = u;
    }
    __syncthreads();
    int o = tid & 63, vv = tid >> 6;
    int g = o >> 3;
    float bv = tb[o];
    float acc[12];
    #pragma unroll
    for (int j = 0; j < 12; j++) acc[j] = bv;
    for (int kh = 0; kh < 7; kh++){
        float wk[8];
        #pragma unroll
        for (int ci = 0; ci < 8; ci++) wk[ci] = tw[(o*8+ci)*7 + kh];
        const unsigned short* base = &W[kh*3072 + g*8];
        #pragma unroll
        for (int j = 0; j < 12; j++){
            uint4 u = *(const uint4*)(base + (vv*12 + j)*64);
            float fv[8]; unpk8(u, fv);
            acc[j] += fv[0]*wk[0]+fv[1]*wk[1]+fv[2]*wk[2]+fv[3]*wk[3]
                    + fv[4]*wk[4]+fv[5]*wk[5]+fv[6]*wk[6]+fv[7]*wk[7];
        }
    }
    int nb = bt*VV;
    #pragma unroll
    for (int j = 0; j < 12; j++)
        ybf[(size_t)(nb + vv*12 + j)*256 + 64 + o] = f2bf(acc[j]);
}

extern "C" void kernel_launch(void* const* d_in, const int* in_sizes, int n_in,
                              void* d_out, int out_size, void* d_ws, size_t ws_size,
                              hipStream_t stream){
    const float* input   = (const float*)d_in[0];
    const float* n1g     = (const float*)d_in[1];
    const float* n1b     = (const float*)d_in[2];
    const float* map_w   = (const float*)d_in[3];
    const float* map_b   = (const float*)d_in[4];
    const float* gconv   = (const float*)d_in[5];
    const float* tconv_w = (const float*)d_in[6];
    const float* tconv_b = (const float*)d_in[7];
    const float* qkv_w0  = (const float*)d_in[8];
    const float* qkv_b0  = (const float*)d_in[9];
    const float* aproj_w0= (const float*)d_in[10];
    const float* aproj_b0= (const float*)d_in[11];
    const float* tcl_w0  = (const float*)d_in[12];
    const float* tcl_b0  = (const float*)d_in[13];
    const float* qkv_w1  = (const float*)d_in[14];
    const float* qkv_b1  = (const float*)d_in[15];
    const float* aproj_w1= (const float*)d_in[16];
    const float* aproj_b1= (const float*)d_in[17];
    const float* tcl_w1  = (const float*)d_in[18];
    const float* tcl_b1  = (const float*)d_in[19];
    const float* proj_w  = (const float*)d_in[20];
    const float* proj_b  = (const float*)d_in[21];
    const float* n2g     = (const float*)d_in[22];
    const float* n2b     = (const float*)d_in[23];
    const float* mlp_w1  = (const float*)d_in[24];
    const float* mlp_b1  = (const float*)d_in[25];
    const float* mlp_w2  = (const float*)d_in[26];
    const float* mlp_b2  = (const float*)d_in[27];

    const size_t Nt = NTOK;
    if (ws_size < 354050048ull) return;

    char* base = (char*)d_ws;
    unsigned short* outtH  = (unsigned short*)base;                  //  50 MB (bf16 outt)
    unsigned short* fbf    = (unsigned short*)(base + 100663296);    //  50 MB
    unsigned short* a0p    = (unsigned short*)(base + 150994944);    //  40 MB
    unsigned short* qkvbuf = (unsigned short*)(base + 191102976);    //  75 MB
    unsigned short* attnout= (unsigned short*)(base + 266600448);    //  25 MB
    unsigned short* A1     = (unsigned short*)(base + 301989888);    //  50 MB
    char* wp = base + 352321536;
    float* gct            = (float*)wp;
    unsigned short* mapT  = (unsigned short*)(wp + 73728);
    unsigned short* projT = mapT + 65536;
    unsigned short* w1T   = projT + 65536;
    unsigned char* w2T8   = (unsigned char*)(w1T + 262144);
    unsigned short* tclT0 = w1T + 262144 + 262144;   // w2T region reused as fp8
    unsigned short* tclT1 = tclT0 + 61440;
    unsigned short* qkvT  = tclT1 + 61440;
    unsigned short* aprojT= qkvT + 24576;

    unsigned char* h8   = (unsigned char*)fbf;   // fp8 Nt x 1024 = 100 MB, spans fbf+a0p+part of qkvbuf (dead)
    unsigned short* xn  = A1;
    unsigned short* ybf = (unsigned short*)d_out;
    unsigned short* xskip = ybf + (size_t)256*Nt;
    float* dout = (float*)d_out;

    prep_weights<<<256, 256, 0, stream>>>(gconv, tcl_w0, tcl_w1, map_w, proj_w, mlp_w1, mlp_w2,
                                          qkv_w0, qkv_w1, aproj_w0, aproj_w1,
                                          gct, mapT, projT, w1T, w2T8, tclT0, tclT1, qkvT, aprojT);
    xpose_ln1<<<NB*TT, 256, 0, stream>>>(input, n1g, n1b, A1, xskip);
    mfma_gemm<256,4><<<1024, 512, 0, stream>>>(A1, mapT, map_b, fbf, nullptr, 256, 2);
    hipMemsetAsync(a0p, 0, A0P_USH*sizeof(unsigned short), stream);
    gemm_k64<0><<<1024, 256, 0, stream>>>(fbf + 128, 512, qkvT,         qkv_b0, qkvbuf);
    gemm_k64<0><<<1024, 256, 0, stream>>>(fbf + 192, 512, qkvT + 12288, qkv_b1, qkvbuf + (size_t)Nt*192);
    attn_win<<<dim3(2048,2), 192, 0, stream>>>(qkvbuf, attnout);
    y0_kernel<<<NB*TT, 256, 0, stream>>>(fbf, gct, ybf);
    y1_kernel<<<NB*TT, 256, 0, stream>>>(fbf, tconv_w, tconv_b, ybf);
    gemm_k64<1><<<1024, 256, 0, stream>>>(attnout,                 128, aprojT,         aproj_b0, a0p);
    tcl_mfma<<<NTOK/192, 256, 0, stream>>>(a0p, tclT0, tcl_b0, ybf, 128);
    gemm_k64<1><<<1024, 256, 0, stream>>>(attnout + (size_t)Nt*64, 128, aprojT + 12288, aproj_b1, a0p);
    tcl_mfma<<<NTOK/192, 256, 0, stream>>>(a0p, tclT1, tcl_b1, ybf, 192);
    proj_ln2<<<512, 512, 0, stream>>>(ybf, projT, proj_b, xskip, n2g, n2b, outtH, xn);
    mfma_gemm<256,2><<<4096, 512, 0, stream>>>(xn, w1T, mlp_b1, nullptr, h8, 1024, 8);
    mfma_final_fp8<<<1024, 512, 0, stream>>>(h8, w2T8, mlp_b2, outtH, dout);
}

// Round 23
// 520.627 us; speedup vs baseline: 1.0685x; 1.0182x over previous
//
#include <hip/hip_runtime.h>
#include <hip/hip_bf16.h>
#include <math.h>

#define NB 32
#define CC 256
#define TT 64
#define VV 48
#define NTOK (NB*TT*VV)   // 98304
#define LNE 1e-5f
#define PROWS 3264        // (4+64)*48
#define A0P_USH ((size_t)NB*PROWS*192)

typedef __attribute__((ext_vector_type(8))) __bf16 bf16x8;
typedef __attribute__((ext_vector_type(4))) float f32x4;

__device__ inline float bfbits2f(unsigned int bits){
    union{unsigned int u; float f;} c; c.u = bits<<16; return c.f;
}
__device__ inline unsigned short f2bf(float x){
    union{ __bf16 h; unsigned short u; } c; c.h = (__bf16)x; return c.u;
}
__device__ inline unsigned char f2fp8(float x){
    int p = __builtin_amdgcn_cvt_pk_fp8_f32(x, x, 0, false);
    return (unsigned char)(p & 0xff);
}
__device__ inline unsigned int pk4fp8(float a, float b, float c, float d){
    int w = 0;
    w = __builtin_amdgcn_cvt_pk_fp8_f32(a, b, w, false);
    w = __builtin_amdgcn_cvt_pk_fp8_f32(c, d, w, true);
    return (unsigned int)w;
}
__device__ __forceinline__ void unpk8(uint4 u, float* d){
    d[0]=bfbits2f(u.x&0xffffu); d[1]=bfbits2f(u.x>>16);
    d[2]=bfbits2f(u.y&0xffffu); d[3]=bfbits2f(u.y>>16);
    d[4]=bfbits2f(u.z&0xffffu); d[5]=bfbits2f(u.z>>16);
    d[6]=bfbits2f(u.w&0xffffu); d[7]=bfbits2f(u.w>>16);
}
// 4*gelu(x) via sigmoid form: 4x * rcp(1 + exp(-1.702x)).
__device__ __forceinline__ float gelu4_fast(float x){
    float e = __expf(-1.702f * x);
    return (4.f * x) * __builtin_amdgcn_rcpf(1.f + e);
}

__device__ __forceinline__ void gll16(const char* g, char* l){
    __builtin_amdgcn_global_load_lds(
        (const __attribute__((address_space(1))) unsigned int*)g,
        (__attribute__((address_space(3))) unsigned int*)l, 16, 0, 0);
}

// ---------------- weight prep ----------------
__global__ void prep_weights(const float* gconv, const float* tcl0, const float* tcl1,
                             const float* map_w, const float* proj_w,
                             const float* mlp_w1, const float* mlp_w2,
                             const float* qkv_w0, const float* qkv_w1,
                             const float* aproj_w0, const float* aproj_w1,
                             float* gct,
                             unsigned short* mapT, unsigned short* projT,
                             unsigned char* w1T8, unsigned char* w2T8,
                             unsigned short* tclT0, unsigned short* tclT1,
                             unsigned short* qkvT, unsigned short* aprojT){
    int tid = blockIdx.x*blockDim.x + threadIdx.x;
    int stride = gridDim.x*blockDim.x;
    for (int i = tid; i < 8*48*48; i += stride){
        int g = i/(48*48); int r = i%(48*48); int u = r/48; int v = r%48;
        gct[i] = gconv[(g*48+v)*48+u];
    }
    for (int i = tid; i < 64*960; i += stride){
        int o = i/960, col = i%960, kh = col/192, c = col%192;
        tclT0[i] = f2bf(tcl0[(o*192+c)*5+kh]);
        tclT1[i] = f2bf(tcl1[(o*192+c)*5+kh]);
    }
    for (int i = tid; i < 65536; i += stride){
        int n = i>>8, k = i&255;
        mapT[i] = f2bf(map_w[k*256+n]);
        projT[i] = f2bf(proj_w[k*256+n]);
    }
    // w1T8[n][k] = fp8(mlp_w1[k][n] * 64)
    for (int i = tid; i < 262144; i += stride){
        int n = i>>8, k = i&255;
        w1T8[i] = f2fp8(mlp_w1[k*1024+n] * 64.f);
    }
    // w2T8[n][k] = fp8(mlp_w2[k][n] * 32)
    for (int i = tid; i < 262144; i += stride){
        int n = i>>10, k = i&1023;
        w2T8[i] = f2fp8(mlp_w2[k*256+n] * 32.f);
    }
    for (int i = tid; i < 12288; i += stride){
        int n = i/64, k = i%64;
        qkvT[i]          = f2bf(qkv_w0[k*192+n]);
        qkvT[12288+i]    = f2bf(qkv_w1[k*192+n]);
        aprojT[i]        = f2bf(aproj_w0[k*192+n]);
        aprojT[12288+i]  = f2bf(aproj_w1[k*192+n]);
    }
}

// ---------------- LN1 + transpose -> A1 bf16 [N][256] + raw skip copy ----------------
__global__ __launch_bounds__(256) void xpose_ln1(const float* __restrict__ x,
        const float* __restrict__ g, const float* __restrict__ bb,
        unsigned short* __restrict__ A1, unsigned short* __restrict__ xskip){
    int bt = blockIdx.x; int b = bt/TT, t = bt%TT;
    __shared__ float X[48*257];
    __shared__ float S[4][48], SS[4][48], sm[48], sv[48];
    int tid = threadIdx.x;
    const float* xb = x + (size_t)b*256*3072 + (size_t)t*48;
    for (int it = 0; it < 12; it++){
        int idx = it*256 + tid;
        int c = idx/12, q = idx%12;
        float4 v = *(const float4*)(xb + (size_t)c*3072 + q*4);
        X[(q*4+0)*257 + c] = v.x;
        X[(q*4+1)*257 + c] = v.y;
        X[(q*4+2)*257 + c] = v.z;
        X[(q*4+3)*257 + c] = v.w;
    }
    __syncthreads();
    if (tid < 192){
        int v = tid % 48, w = tid / 48;
        float s = 0.f, ss = 0.f;
        for (int c = w*64; c < w*64+64; c++){
            float val = X[v*257 + c];
            s += val; ss += val*val;
        }
        S[w][v] = s; SS[w][v] = ss;
    }
    __syncthreads();
    if (tid < 48){
        float s = S[0][tid]+S[1][tid]+S[2][tid]+S[3][tid];
        float q = SS[0][tid]+SS[1][tid]+SS[2][tid]+SS[3][tid];
        float m = s*(1.f/256);
        sm[tid] = m; sv[tid] = rsqrtf(q*(1.f/256) - m*m + LNE);
    }
    __syncthreads();
    int nb = bt*48;
    for (int it = 0; it < 12; it++){
        int idx = it*256 + tid;
        int v = idx>>6, cq = idx&63;
        float m = sm[v], rs = sv[v];
        float4 g4 = *(const float4*)(g + cq*4);
        float4 b4 = *(const float4*)(bb + cq*4);
        float x0 = X[v*257 + cq*4+0], x1 = X[v*257 + cq*4+1];
        float x2 = X[v*257 + cq*4+2], x3 = X[v*257 + cq*4+3];
        ushort4 u;
        u.x = f2bf((x0-m)*rs*g4.x + b4.x);
        u.y = f2bf((x1-m)*rs*g4.y + b4.y);
        u.z = f2bf((x2-m)*rs*g4.z + b4.z);
        u.w = f2bf((x3-m)*rs*g4.w + b4.w);
        *(ushort4*)(A1 + (size_t)(nb+v)*256 + cq*4) = u;
        ushort4 s;
        s.x = f2bf(x0); s.y = f2bf(x1); s.z = f2bf(x2); s.w = f2bf(x3);
        *(ushort4*)(xskip + (size_t)(nb+v)*256 + cq*4) = s;
    }
}

// ---------------- swizzled staging (single-shot, for k64 GEMM) ----------------
__device__ __forceinline__ void stage_swz(const char* src, size_t rowbytes, char* lds,
                                          int nchunks, int tid){
    for (int c = tid; c < nchunks; c += 256){
        int p = c << 4;
        int r = p >> 7;
        int kl = (p & 127) ^ ((r & 7) << 4);
        gll16(src + (size_t)r*rowbytes + kl, lds + p);
    }
}

__device__ __forceinline__ bf16x8 frag_ld(const char* lds, int R, int kb){
    return *(const bf16x8*)(lds + R*128 + (kb ^ ((R & 7) << 4)));
}
__device__ __forceinline__ long frag_ld8(const char* lds, int R, int kb){
    return *(const long*)(lds + R*128 + (kb ^ ((R & 7) << 4)));
}

// ---------------- MFMA GEMM: BM=192, BN=128, 8 waves, dbuf + counted vmcnt ----------------
// EPI 4: outH = bf16(acc + bias)   [LDS repack, 16B stores]
template<int KTOT, int EPI>
__global__ __launch_bounds__(512, 4) void mfma_gemm(
    const unsigned short* __restrict__ A, const unsigned short* __restrict__ BT,
    const float* __restrict__ bias,
    unsigned short* __restrict__ outH, unsigned char* __restrict__ outH8,
    int ncols, int nx){

    constexpr int BM = 192, BN = 128;
    constexpr int HALF = (BM+BN)*128;           // 40960
    __shared__ __align__(16) char smem[2*HALF]; // 81920 -> 2 blocks/CU
    int tid = threadIdx.x, lane = tid & 63;
    int wid = tid >> 6;
    int wm = wid >> 1, wn = wid & 1;
    int l15 = lane & 15, lq = lane >> 4;
    int bid = blockIdx.x;
    int per = gridDim.x >> 3;
    int wkid = (bid & 7)*per + (bid >> 3);
    int m0 = (wkid / nx) * BM, n0 = (wkid % nx) * BN;
    const size_t arb = KTOT*2, brb = KTOT*2;
    constexpr int KT = KTOT/64;

    const char* gA[3]; int loA[3];
    const char* gB[2]; int loB[2];
    {
        const char* Ab = (const char*)A + (size_t)m0*arb;
        const char* Bb = (const char*)BT + (size_t)n0*brb;
        #pragma unroll
        for (int i = 0; i < 3; i++){
            int c = tid + i*512;
            int p = c << 4, r = p >> 7;
            int kl = (p & 127) ^ ((r & 7) << 4);
            gA[i] = Ab + (size_t)r*arb + kl; loA[i] = p;
        }
        #pragma unroll
        for (int i = 0; i < 2; i++){
            int c = tid + i*512;
            int p = c << 4, r = p >> 7;
            int kl = (p & 127) ^ ((r & 7) << 4);
            gB[i] = Bb + (size_t)r*brb + kl; loB[i] = BM*128 + p;
        }
    }

    f32x4 acc[3][4];
    #pragma unroll
    for (int i = 0; i < 3; i++)
        #pragma unroll
        for (int j = 0; j < 4; j++){ f32x4 z = {0.f,0.f,0.f,0.f}; acc[i][j] = z; }

    #pragma unroll
    for (int i = 0; i < 3; i++) gll16(gA[i], smem + loA[i]);
    #pragma unroll
    for (int i = 0; i < 2; i++) gll16(gB[i], smem + loB[i]);

    int koff = 128;
    for (int kt = 0; kt < KT; kt++){
        char* cur = smem + (kt & 1)*HALF;
        if (kt + 1 < KT){
            char* nxt = smem + ((kt + 1) & 1)*HALF;
            #pragma unroll
            for (int i = 0; i < 3; i++) gll16(gA[i] + koff, nxt + loA[i]);
            #pragma unroll
            for (int i = 0; i < 2; i++) gll16(gB[i] + koff, nxt + loB[i]);
            koff += 128;
            asm volatile("s_waitcnt vmcnt(5)" ::: "memory");
        } else {
            asm volatile("s_waitcnt vmcnt(0)" ::: "memory");
        }
        __builtin_amdgcn_s_barrier();
        __builtin_amdgcn_sched_barrier(0);
        char* ldsA = cur;
        char* ldsB = cur + BM*128;
        #pragma unroll
        for (int ks = 0; ks < 2; ks++){
            bf16x8 a[3], b[4];
            int kb = ks*64 + lq*16;
            #pragma unroll
            for (int mf = 0; mf < 3; mf++) a[mf] = frag_ld(ldsA, wm*48 + mf*16 + l15, kb);
            #pragma unroll
            for (int nf = 0; nf < 4; nf++) b[nf] = frag_ld(ldsB, wn*64 + nf*16 + l15, kb);
            #pragma unroll
            for (int mf = 0; mf < 3; mf++)
                #pragma unroll
                for (int nf = 0; nf < 4; nf++)
                    acc[mf][nf] = __builtin_amdgcn_mfma_f32_16x16x32_bf16(a[mf], b[nf], acc[mf][nf], 0, 0, 0);
        }
        __builtin_amdgcn_sched_barrier(0);
        __builtin_amdgcn_s_barrier();
    }

    if constexpr (EPI == 4){
        unsigned short* Hs = (unsigned short*)smem;   // [192][136]
        #pragma unroll
        for (int nf = 0; nf < 4; nf++){
            int col = wn*64 + nf*16 + l15;
            float bb = bias[n0 + col];
            #pragma unroll
            for (int mf = 0; mf < 3; mf++){
                int row = wm*48 + mf*16 + lq*4;
                f32x4 v = acc[mf][nf];
                #pragma unroll
                for (int r = 0; r < 4; r++)
                    Hs[(row+r)*136 + col] = f2bf(v[r] + bb);
            }
        }
        __syncthreads();
        for (int idx = tid; idx < 192*16; idx += 512){
            int row = idx >> 4, c8 = idx & 15;
            *(uint4*)(outH + (size_t)(m0+row)*ncols + n0 + c8*8) =
                *(const uint4*)(Hs + row*136 + c8*8);
        }
    }
}

// ---------------- MLP1 GEMM in fp8: K=256 as 2 tiles of K=128 (128B rows) ----------------
// outH8 = fp8(gelu4((acc/64) + bias)), direct-from-acc epilogue (rd18-proven form)
__global__ __launch_bounds__(512, 4) void mfma_mlp1_fp8(
    const unsigned char* __restrict__ A, const unsigned char* __restrict__ BT,
    const float* __restrict__ bias, unsigned char* __restrict__ outH8){

    constexpr int BM = 192, BN = 128, NX = 8;
    constexpr int HALF = (BM+BN)*128;           // 40960
    __shared__ __align__(16) char smem[2*HALF]; // 81920 -> 2 blocks/CU
    int tid = threadIdx.x, lane = tid & 63;
    int wid = tid >> 6;
    int wm = wid >> 1, wn = wid & 1;
    int l15 = lane & 15, lq = lane >> 4;
    int bid = blockIdx.x;
    int per = gridDim.x >> 3;
    int wkid = (bid & 7)*per + (bid >> 3);
    int m0 = (wkid / NX) * BM, n0 = (wkid % NX) * BN;
    const size_t arb = 256, brb = 256;
    constexpr int KT = 2;

    const char* gA[3]; int loA[3];
    const char* gB[2]; int loB[2];
    {
        const char* Ab = (const char*)A + (size_t)m0*arb;
        const char* Bb = (const char*)BT + (size_t)n0*brb;
        #pragma unroll
        for (int i = 0; i < 3; i++){
            int c = tid + i*512;
            int p = c << 4, r = p >> 7;
            int kl = (p & 127) ^ ((r & 7) << 4);
            gA[i] = Ab + (size_t)r*arb + kl; loA[i] = p;
        }
        #pragma unroll
        for (int i = 0; i < 2; i++){
            int c = tid + i*512;
            int p = c << 4, r = p >> 7;
            int kl = (p & 127) ^ ((r & 7) << 4);
            gB[i] = Bb + (size_t)r*brb + kl; loB[i] = BM*128 + p;
        }
    }

    f32x4 acc[3][4];
    #pragma unroll
    for (int i = 0; i < 3; i++)
        #pragma unroll
        for (int j = 0; j < 4; j++){ f32x4 z = {0.f,0.f,0.f,0.f}; acc[i][j] = z; }

    #pragma unroll
    for (int i = 0; i < 3; i++) gll16(gA[i], smem + loA[i]);
    #pragma unroll
    for (int i = 0; i < 2; i++) gll16(gB[i], smem + loB[i]);

    int koff = 128;
    for (int kt = 0; kt < KT; kt++){
        char* cur = smem + (kt & 1)*HALF;
        if (kt + 1 < KT){
            char* nxt = smem + ((kt + 1) & 1)*HALF;
            #pragma unroll
            for (int i = 0; i < 3; i++) gll16(gA[i] + koff, nxt + loA[i]);
            #pragma unroll
            for (int i = 0; i < 2; i++) gll16(gB[i] + koff, nxt + loB[i]);
            koff += 128;
            asm volatile("s_waitcnt vmcnt(5)" ::: "memory");
        } else {
            asm volatile("s_waitcnt vmcnt(0)" ::: "memory");
        }
        __builtin_amdgcn_s_barrier();
        __builtin_amdgcn_sched_barrier(0);
        char* ldsA = cur;
        char* ldsB = cur + BM*128;
        #pragma unroll
        for (int ks = 0; ks < 4; ks++){
            long a[3], b[4];
            int kb = ks*32 + lq*8;
            #pragma unroll
            for (int mf = 0; mf < 3; mf++) a[mf] = frag_ld8(ldsA, wm*48 + mf*16 + l15, kb);
            #pragma unroll
            for (int nf = 0; nf < 4; nf++) b[nf] = frag_ld8(ldsB, wn*64 + nf*16 + l15, kb);
            #pragma unroll
            for (int mf = 0; mf < 3; mf++)
                #pragma unroll
                for (int nf = 0; nf < 4; nf++)
                    acc[mf][nf] = __builtin_amdgcn_mfma_f32_16x16x32_fp8_fp8(a[mf], b[nf], acc[mf][nf], 0, 0, 0);
        }
        __builtin_amdgcn_sched_barrier(0);
        __builtin_amdgcn_s_barrier();
    }

    unsigned char* Hc = (unsigned char*)smem;     // [192][144] fp8
    #pragma unroll
    for (int nf = 0; nf < 4; nf++){
        int col = wn*64 + nf*16 + l15;
        float bb = bias[n0 + col];
        #pragma unroll
        for (int mf = 0; mf < 3; mf++){
            int row = wm*48 + mf*16 + lq*4;
            f32x4 v = acc[mf][nf];
            #pragma unroll
            for (int r = 0; r < 4; r++){
                float t0 = gelu4_fast(v[r]*0.015625f + bb);
                Hc[(row+r)*144 + col] = f2fp8(t0);
            }
        }
    }
    __syncthreads();
    for (int idx = tid; idx < 192*8; idx += 512){
        int row = idx >> 3, c16 = idx & 7;
        *(uint4*)(outH8 + (size_t)(m0+row)*1024 + n0 + c16*16) =
            *(const uint4*)(Hc + row*144 + c16*16);
    }
}

// ---------------- final GEMM in fp8: K=1024 as 8 tiles of K=128 (128B rows) ----------------
__global__ __launch_bounds__(512, 4) void mfma_final_fp8(
    const unsigned char* __restrict__ A, const unsigned char* __restrict__ BT,
    const float* __restrict__ bias, const unsigned short* __restrict__ extraH,
    float* __restrict__ outF){

    constexpr int BM = 192, BN = 128, NX = 2;
    constexpr int HALF = (BM+BN)*128;           // 40960
    __shared__ __align__(16) char smem[2*HALF]; // 81920 -> 2 blocks/CU
    int tid = threadIdx.x, lane = tid & 63;
    int wid = tid >> 6;
    int wm = wid >> 1, wn = wid & 1;
    int l15 = lane & 15, lq = lane >> 4;
    int bid = blockIdx.x;
    int per = gridDim.x >> 3;
    int wkid = (bid & 7)*per + (bid >> 3);
    int m0 = (wkid / NX) * BM, n0 = (wkid % NX) * BN;
    const size_t arb = 1024, brb = 1024;
    constexpr int KT = 8;

    const char* gA[3]; int loA[3];
    const char* gB[2]; int loB[2];
    {
        const char* Ab = (const char*)A + (size_t)m0*arb;
        const char* Bb = (const char*)BT + (size_t)n0*brb;
        #pragma unroll
        for (int i = 0; i < 3; i++){
            int c = tid + i*512;
            int p = c << 4, r = p >> 7;
            int kl = (p & 127) ^ ((r & 7) << 4);
            gA[i] = Ab + (size_t)r*arb + kl; loA[i] = p;
        }
        #pragma unroll
        for (int i = 0; i < 2; i++){
            int c = tid + i*512;
            int p = c << 4, r = p >> 7;
            int kl = (p & 127) ^ ((r & 7) << 4);
            gB[i] = Bb + (size_t)r*brb + kl; loB[i] = BM*128 + p;
        }
    }

    f32x4 acc[3][4];
    #pragma unroll
    for (int i = 0; i < 3; i++)
        #pragma unroll
        for (int j = 0; j < 4; j++){ f32x4 z = {0.f,0.f,0.f,0.f}; acc[i][j] = z; }

    #pragma unroll
    for (int i = 0; i < 3; i++) gll16(gA[i], smem + loA[i]);
    #pragma unroll
    for (int i = 0; i < 2; i++) gll16(gB[i], smem + loB[i]);

    int koff = 128;
    for (int kt = 0; kt < KT; kt++){
        char* cur = smem + (kt & 1)*HALF;
        if (kt + 1 < KT){
            char* nxt = smem + ((kt + 1) & 1)*HALF;
            #pragma unroll
            for (int i = 0; i < 3; i++) gll16(gA[i] + koff, nxt + loA[i]);
            #pragma unroll
            for (int i = 0; i < 2; i++) gll16(gB[i] + koff, nxt + loB[i]);
            koff += 128;
            asm volatile("s_waitcnt vmcnt(5)" ::: "memory");
        } else {
            asm volatile("s_waitcnt vmcnt(0)" ::: "memory");
        }
        __builtin_amdgcn_s_barrier();
        __builtin_amdgcn_sched_barrier(0);
        char* ldsA = cur;
        char* ldsB = cur + BM*128;
        #pragma unroll
        for (int ks = 0; ks < 4; ks++){
            long a[3], b[4];
            int kb = ks*32 + lq*8;
            #pragma unroll
            for (int mf = 0; mf < 3; mf++) a[mf] = frag_ld8(ldsA, wm*48 + mf*16 + l15, kb);
            #pragma unroll
            for (int nf = 0; nf < 4; nf++) b[nf] = frag_ld8(ldsB, wn*64 + nf*16 + l15, kb);
            #pragma unroll
            for (int mf = 0; mf < 3; mf++)
                #pragma unroll
                for (int nf = 0; nf < 4; nf++)
                    acc[mf][nf] = __builtin_amdgcn_mfma_f32_16x16x32_fp8_fp8(a[mf], b[nf], acc[mf][nf], 0, 0, 0);
        }
        __builtin_amdgcn_sched_barrier(0);
        __builtin_amdgcn_s_barrier();
    }

    // epilogue: dout NCHW = acc/128 + bias + resid (bf16 outtH), two-pass transpose
    float* Tt = (float*)smem;  // [64 cols][196]
    #pragma unroll
    for (int ph = 0; ph < 2; ph++){
        __syncthreads();
        if (wn == ph){
            #pragma unroll
            for (int nf = 0; nf < 4; nf++){
                int lc = nf*16 + l15;
                float bb = bias[n0 + ph*64 + lc];
                #pragma unroll
                for (int mf = 0; mf < 3; mf++){
                    int tl = wm*48 + mf*16 + lq*4;
                    f32x4 v = acc[mf][nf];
                    #pragma unroll
                    for (int r = 0; r < 4; r++){
                        float resid = bfbits2f(extraH[(size_t)(m0+tl+r)*256 + n0 + ph*64 + lc]);
                        Tt[lc*196 + tl + r] = v[r]*0.0078125f + bb + resid;
                    }
                }
            }
        }
        __syncthreads();
        {
            int lc = tid & 63, btl = (tid>>6)&3, dup = tid>>8;
            int gtok = m0 + btl*48;
            int bg = gtok/3072, t = (gtok%3072)/48;
            float* dst = outF + ((size_t)(bg*256 + n0 + ph*64 + lc)*64 + t)*48 + dup*24;
            const float* tr = Tt + lc*196 + btl*48 + dup*24;
            #pragma unroll
            for (int j = 0; j < 6; j++)
                *(float4*)(dst + j*4) = *(const float4*)(tr + j*4);
        }
    }
}

// ---------------- proj GEMM fused with skip-add + LN2: BM=192, BN=256, K=256 ----------------
// xn output now fp8 (input to fp8 MLP1)
__global__ __launch_bounds__(512, 2) void proj_ln2(
    const unsigned short* __restrict__ A, const unsigned short* __restrict__ BT,
    const float* __restrict__ bias, const unsigned short* __restrict__ xskip,
    const float* __restrict__ n2g, const float* __restrict__ n2b,
    unsigned short* __restrict__ outtH, unsigned char* __restrict__ xn8){

    constexpr int BM = 192, BN = 256, KTOT = 256;
    constexpr int HALF = (BM+BN)*128;
    __shared__ __align__(16) char smem[2*HALF];
    int tid = threadIdx.x, lane = tid & 63;
    int wid = tid >> 6;
    int wm = wid >> 1, wn = wid & 1;
    int l15 = lane & 15, lq = lane >> 4;
    int bid = blockIdx.x;
    int per = gridDim.x >> 3;
    int wkid = (bid & 7)*per + (bid >> 3);
    int m0 = wkid * BM;
    const size_t arb = KTOT*2, brb = KTOT*2;
    constexpr int KT = KTOT/64;

    const char* gA[3]; int loA[3];
    const char* gB[4]; int loB[4];
    {
        const char* Ab = (const char*)A + (size_t)m0*arb;
        const char* Bb = (const char*)BT;
        #pragma unroll
        for (int i = 0; i < 3; i++){
            int c = tid + i*512;
            int p = c << 4, r = p >> 7;
            int kl = (p & 127) ^ ((r & 7) << 4);
            gA[i] = Ab + (size_t)r*arb + kl; loA[i] = p;
        }
        #pragma unroll
        for (int i = 0; i < 4; i++){
            int c = tid + i*512;
            int p = c << 4, r = p >> 7;
            int kl = (p & 127) ^ ((r & 7) << 4);
            gB[i] = Bb + (size_t)r*brb + kl; loB[i] = BM*128 + p;
        }
    }

    f32x4 acc[3][8];
    #pragma unroll
    for (int i = 0; i < 3; i++)
        #pragma unroll
        for (int j = 0; j < 8; j++){ f32x4 z = {0.f,0.f,0.f,0.f}; acc[i][j] = z; }

    #pragma unroll
    for (int i = 0; i < 3; i++) gll16(gA[i], smem + loA[i]);
    #pragma unroll
    for (int i = 0; i < 4; i++) gll16(gB[i], smem + loB[i]);

    int koff = 128;
    for (int kt = 0; kt < KT; kt++){
        char* cur = smem + (kt & 1)*HALF;
        if (kt + 1 < KT){
            char* nxt = smem + ((kt + 1) & 1)*HALF;
            #pragma unroll
            for (int i = 0; i < 3; i++) gll16(gA[i] + koff, nxt + loA[i]);
            #pragma unroll
            for (int i = 0; i < 4; i++) gll16(gB[i] + koff, nxt + loB[i]);
            koff += 128;
            asm volatile("s_waitcnt vmcnt(7)" ::: "memory");
        } else {
            asm volatile("s_waitcnt vmcnt(0)" ::: "memory");
        }
        __builtin_amdgcn_s_barrier();
        __builtin_amdgcn_sched_barrier(0);
        char* ldsA = cur;
        char* ldsB = cur + BM*128;
        #pragma unroll
        for (int ks = 0; ks < 2; ks++){
            bf16x8 a[3], b[8];
            int kb = ks*64 + lq*16;
            #pragma unroll
            for (int mf = 0; mf < 3; mf++) a[mf] = frag_ld(ldsA, wm*48 + mf*16 + l15, kb);
            #pragma unroll
            for (int nf = 0; nf < 8; nf++) b[nf] = frag_ld(ldsB, wn*128 + nf*16 + l15, kb);
            #pragma unroll
            for (int mf = 0; mf < 3; mf++)
                #pragma unroll
                for (int nf = 0; nf < 8; nf++)
                    acc[mf][nf] = __builtin_amdgcn_mfma_f32_16x16x32_bf16(a[mf], b[nf], acc[mf][nf], 0, 0, 0);
        }
        __builtin_amdgcn_sched_barrier(0);
        __builtin_amdgcn_s_barrier();
    }

    unsigned short* Hs = (unsigned short*)smem;
    float* Sred = (float*)(smem + 101376);
    float s_acc[3][4], ss_acc[3][4];
    #pragma unroll
    for (int i = 0; i < 3; i++)
        #pragma unroll
        for (int r = 0; r < 4; r++){ s_acc[i][r] = 0.f; ss_acc[i][r] = 0.f; }

    #pragma unroll
    for (int nf = 0; nf < 8; nf++){
        int col = wn*128 + nf*16 + l15;
        float bb = bias[col];
        #pragma unroll
        for (int mf = 0; mf < 3; mf++){
            int row = wm*48 + mf*16 + lq*4;
            f32x4 v = acc[mf][nf];
            #pragma unroll
            for (int r = 0; r < 4; r++){
                float sk = bfbits2f(xskip[(size_t)(m0+row+r)*256 + col]);
                unsigned short us = f2bf(v[r] + bb + sk);
                Hs[(row+r)*264 + col] = us;
                float tf = bfbits2f(us);
                s_acc[mf][r] += tf; ss_acc[mf][r] += tf*tf;
            }
        }
    }
    #pragma unroll
    for (int mf = 0; mf < 3; mf++)
        #pragma unroll
        for (int r = 0; r < 4; r++){
            float s = s_acc[mf][r], ss = ss_acc[mf][r];
            #pragma unroll
            for (int d = 1; d < 16; d <<= 1){
                s  += __shfl_xor(s, d);
                ss += __shfl_xor(ss, d);
            }
            if (l15 == 0){
                int row = wm*48 + mf*16 + lq*4 + r;
                Sred[wn*192 + row] = s;
                Sred[384 + wn*192 + row] = ss;
            }
        }
    __syncthreads();
    if (tid < 192){
        float s  = Sred[tid] + Sred[192+tid];
        float ss = Sred[384+tid] + Sred[576+tid];
        float m = s*(1.f/256);
        Sred[tid] = m;
        Sred[192+tid] = rsqrtf(ss*(1.f/256) - m*m + LNE);
    }
    __syncthreads();
    for (int idx = tid; idx < 192*32; idx += 512){
        int row = idx >> 5, c8 = idx & 31;
        uint4 hv = *(const uint4*)(Hs + row*264 + c8*8);
        *(uint4*)(outtH + (size_t)(m0+row)*256 + c8*8) = hv;
        float v[8]; unpk8(hv, v);
        float m = Sred[row], rs = Sred[192+row];
        float xv[8];
        #pragma unroll
        for (int j = 0; j < 8; j++)
            xv[j] = (v[j]-m)*rs*n2g[c8*8 + j] + n2b[c8*8 + j];
        uint2 o;
        o.x = pk4fp8(xv[0], xv[1], xv[2], xv[3]);
        o.y = pk4fp8(xv[4], xv[5], xv[6], xv[7]);
        *(uint2*)(xn8 + (size_t)(m0+row)*256 + c8*8) = o;
    }
}

// ---------------- K=64 MFMA GEMM: BM=96, BN=192, 4 waves ----------------
template<int EPI>
__global__ __launch_bounds__(256) void gemm_k64(
    const unsigned short* __restrict__ A, int arb,
    const unsigned short* __restrict__ BT,
    const float* __restrict__ bias,
    unsigned short* __restrict__ out){
    __shared__ __align__(16) char smem[96*128 + 192*128];
    char* ldsA = smem;
    char* ldsB = smem + 96*128;
    int tid = threadIdx.x, lane = tid & 63;
    int wid = tid >> 6, wm = wid >> 1, wn = wid & 1;
    int l15 = lane & 15, lq = lane >> 4;
    int m0 = blockIdx.x * 96;

    stage_swz((const char*)A + (size_t)m0*arb, arb, ldsA, 96*8, tid);
    stage_swz((const char*)BT, 128, ldsB, 192*8, tid);
    __syncthreads();

    f32x4 acc[3][6];
    #pragma unroll
    for (int i = 0; i < 3; i++)
        #pragma unroll
        for (int j = 0; j < 6; j++){ f32x4 z = {0.f,0.f,0.f,0.f}; acc[i][j] = z; }

    #pragma unroll
    for (int ks = 0; ks < 2; ks++){
        bf16x8 a[3], b[6];
        int kb = ks*64 + lq*16;
        #pragma unroll
        for (int mf = 0; mf < 3; mf++) a[mf] = frag_ld(ldsA, wm*48 + mf*16 + l15, kb);
        #pragma unroll
        for (int nf = 0; nf < 6; nf++) b[nf] = frag_ld(ldsB, wn*96 + nf*16 + l15, kb);
        #pragma unroll
        for (int mf = 0; mf < 3; mf++)
            #pragma unroll
            for (int nf = 0; nf < 6; nf++)
                acc[mf][nf] = __builtin_amdgcn_mfma_f32_16x16x32_bf16(a[mf], b[nf], acc[mf][nf], 0, 0, 0);
    }

    size_t row0;
    if constexpr (EPI == 0) row0 = (size_t)m0;
    else {
        int b = m0/3072;
        row0 = (size_t)b*PROWS + 192 + (m0 - b*3072);
    }
    #pragma unroll
    for (int nf = 0; nf < 6; nf++){
        int col = wn*96 + nf*16 + l15;
        float bb = bias[col];
        #pragma unroll
        for (int mf = 0; mf < 3; mf++){
            size_t rr = row0 + wm*48 + mf*16 + lq*4;
            f32x4 v = acc[mf][nf];
            #pragma unroll
            for (int r = 0; r < 4; r++)
                out[(rr+r)*192 + col] = f2bf(v[r] + bb);
        }
    }
}

// ---------------- windowed attention ----------------
__global__ __launch_bounds__(192) void attn_win(
        const unsigned short* __restrict__ qkvbuf,
        unsigned short* __restrict__ attnout){
    int win = blockIdx.x, br = blockIdx.y;
    size_t base = (size_t)br*NTOK + (size_t)win*48;
    __shared__ float Q[48*196];
    int tid = threadIdx.x;
    const unsigned short* src = qkvbuf + base*192;
    for (int i = 0; i < 6; i++){
        int ch = i*192 + tid;
        int v = ch/24, c8 = ch%24;
        uint4 u = *(const uint4*)(src + (size_t)v*192 + c8*8);
        unpk8(u, &Q[v*196 + c8*8]);
    }
    __syncthreads();
    int u = tid & 15, gh = tid >> 4, g = gh >> 2, h = gh & 3;
    int ru = g*16 + u;
    float qreg[16];
    #pragma unroll
    for (int d = 0; d < 16; d++) qreg[d] = Q[ru*196 + h*16 + d];
    float sc[16]; float mx = -1e30f;
    #pragma unroll
    for (int w = 0; w < 16; w++){
        float s = 0.f;
        #pragma unroll
        for (int d = 0; d < 16; d++) s += qreg[d]*Q[(g*16+w)*196 + 64 + h*16 + d];
        s *= 0.5f; sc[w] = s; mx = fmaxf(mx, s);
    }
    float sum = 0.f;
    #pragma unroll
    for (int w = 0; w < 16; w++){ sc[w] = __expf(sc[w]-mx); sum += sc[w]; }
    float inv = __builtin_amdgcn_rcpf(sum);
    unsigned int w32[8];
    #pragma unroll
    for (int dp = 0; dp < 8; dp++){
        float o0 = 0.f, o1 = 0.f;
        #pragma unroll
        for (int w = 0; w < 16; w++){
            float p = sc[w];
            o0 += p*Q[(g*16+w)*196 + 128 + h*16 + dp*2];
            o1 += p*Q[(g*16+w)*196 + 128 + h*16 + dp*2+1];
        }
        w32[dp] = (unsigned int)f2bf(o0*inv) | ((unsigned int)f2bf(o1*inv) << 16);
    }
    unsigned short* dst = attnout + (base + ru)*64 + h*16;
    uint4 q0; q0.x=w32[0]; q0.y=w32[1]; q0.z=w32[2]; q0.w=w32[3];
    uint4 q1; q1.x=w32[4]; q1.y=w32[5]; q1.z=w32[6]; q1.w=w32[7];
    *(uint4*)(dst)   = q0;
    *(uint4*)(dst+8) = q1;
}

// ---------------- tcl as MFMA GEMM: K=960 (15 tiles), dbuf + counted vmcnt ----------------
__global__ __launch_bounds__(256) void tcl_mfma(const unsigned short* __restrict__ A0p,
        const unsigned short* __restrict__ BT, const float* __restrict__ tb,
        unsigned short* __restrict__ ybf, int outoff){
    constexpr int HALF = (192+64)*128;
    __shared__ __align__(16) char smem[2*HALF];
    int tid = threadIdx.x, lane = tid & 63;
    int wid = tid >> 6;
    int l15 = lane & 15, lq = lane >> 4;
    int bid = blockIdx.x;
    int per = gridDim.x >> 3;
    int wkid = (bid & 7)*per + (bid >> 3);
    int m0 = wkid * 192;
    int b = m0 / 3072;
    long brow0 = (long)b*PROWS + 192 + (m0 - b*3072);

    const char* gA[6]; int loA[6];
    const char* gB[2]; int loB[2];
    {
        const char* Ab = (const char*)A0p + (brow0 - 192)*384;
        #pragma unroll
        for (int i = 0; i < 6; i++){
            int c = tid + i*256;
            int p = c << 4, r = p >> 7;
            int kl = (p & 127) ^ ((r & 7) << 4);
            gA[i] = Ab + (size_t)r*384 + kl; loA[i] = p;
        }
        #pragma unroll
        for (int i = 0; i < 2; i++){
            int c = tid + i*256;
            int p = c << 4, r = p >> 7;
            int kl = (p & 127) ^ ((r & 7) << 4);
            gB[i] = (const char*)BT + (size_t)r*1920 + kl; loB[i] = 192*128 + p;
        }
    }

    f32x4 acc[3][4];
    #pragma unroll
    for (int i = 0; i < 3; i++)
        #pragma unroll
        for (int j = 0; j < 4; j++){ f32x4 z = {0.f,0.f,0.f,0.f}; acc[i][j] = z; }

    #pragma unroll
    for (int i = 0; i < 6; i++) gll16(gA[i], smem + loA[i]);
    #pragma unroll
    for (int i = 0; i < 2; i++) gll16(gB[i], smem + loB[i]);

    long offA = 0; int kc3 = 0; int offB = 0;
    for (int kt = 0; kt < 15; kt++){
        char* cur = smem + (kt & 1)*HALF;
        if (kt + 1 < 15){
            char* nxt = smem + ((kt + 1) & 1)*HALF;
            if (kc3 == 2){ offA += 18432 - 256; kc3 = 0; }
            else         { offA += 128; kc3++; }
            offB += 128;
            #pragma unroll
            for (int i = 0; i < 6; i++) gll16(gA[i] + offA, nxt + loA[i]);
            #pragma unroll
            for (int i = 0; i < 2; i++) gll16(gB[i] + offB, nxt + loB[i]);
            asm volatile("s_waitcnt vmcnt(8)" ::: "memory");
        } else {
            asm volatile("s_waitcnt vmcnt(0)" ::: "memory");
        }
        __builtin_amdgcn_s_barrier();
        __builtin_amdgcn_sched_barrier(0);
        char* ldsA = cur;
        char* ldsB = cur + 192*128;
        #pragma unroll
        for (int ks = 0; ks < 2; ks++){
            bf16x8 a[3], bb[4];
            int kb = ks*64 + lq*16;
            #pragma unroll
            for (int mf = 0; mf < 3; mf++) a[mf] = frag_ld(ldsA, wid*48 + mf*16 + l15, kb);
            #pragma unroll
            for (int nf = 0; nf < 4; nf++) bb[nf] = frag_ld(ldsB, nf*16 + l15, kb);
            #pragma unroll
            for (int mf = 0; mf < 3; mf++)
                #pragma unroll
                for (int nf = 0; nf < 4; nf++)
                    acc[mf][nf] = __builtin_amdgcn_mfma_f32_16x16x32_bf16(a[mf], bb[nf], acc[mf][nf], 0, 0, 0);
        }
        __builtin_amdgcn_sched_barrier(0);
        __builtin_amdgcn_s_barrier();
    }
    #pragma unroll
    for (int nf = 0; nf < 4; nf++){
        int col = nf*16 + l15;
        float bb = tb[col];
        #pragma unroll
        for (int mf = 0; mf < 3; mf++){
            int tok = m0 + wid*48 + mf*16 + lq*4;
            f32x4 v = acc[mf][nf];
            #pragma unroll
            for (int r = 0; r < 4; r++)
                ybf[(size_t)(tok+r)*256 + outoff + col] = f2bf(v[r] + bb);
        }
    }
}

// ---------------- y0: grouped V-mix -> ybf cols 0..63 ----------------
__global__ __launch_bounds__(256) void y0_kernel(const unsigned short* __restrict__ fbf,
        const float* __restrict__ gct, unsigned short* __restrict__ ybf){
    int bt = blockIdx.x; int nb = bt*VV;
    __shared__ float X[48*68];
    for (int it = 0; it < 2; it++){
        int idx = it*256 + threadIdx.x;
        if (idx < 384){
            int v = idx >> 3, c8 = idx & 7;
            uint4 u = *(const uint4*)(fbf + (size_t)(nb+v)*256 + c8*8);
            unpk8(u, &X[v*68 + c8*8]);
        }
    }
    __syncthreads();
    int c = threadIdx.x % 64, vv = threadIdx.x / 64;
    int g = c >> 3;
    float acc[12] = {};
    for (int u = 0; u < 48; u++){
        float xv = X[u*68 + c];
        const float* gr = gct + (size_t)(g*48+u)*48 + vv*12;
        float4 g0 = *(const float4*)(gr);
        float4 g1 = *(const float4*)(gr+4);
        float4 g2 = *(const float4*)(gr+8);
        acc[0]+=xv*g0.x; acc[1]+=xv*g0.y; acc[2]+=xv*g0.z;  acc[3]+=xv*g0.w;
        acc[4]+=xv*g1.x; acc[5]+=xv*g1.y; acc[6]+=xv*g1.z;  acc[7]+=xv*g1.w;
        acc[8]+=xv*g2.x; acc[9]+=xv*g2.y; acc[10]+=xv*g2.z; acc[11]+=xv*g2.w;
    }
    #pragma unroll
    for (int j = 0; j < 12; j++)
        ybf[(size_t)(nb + vv*12 + j)*256 + c] = f2bf(acc[j]);
}

// ---------------- y1: grouped temporal conv (k=7), LDS-staged taps -> ybf cols 64..127 ----------------
__global__ __launch_bounds__(256) void y1_kernel(const unsigned short* __restrict__ fbf,
        const float* __restrict__ tw, const float* __restrict__ tb, unsigned short* __restrict__ ybf){
    int bt = blockIdx.x; int b = bt/TT, t = bt%TT;
    __shared__ unsigned short W[7*48*64];   // 43 KB: [kh][v][ch 64..127]
    int tid = threadIdx.x;
    // coalesced staging: chunk idx -> LDS ushort index 8*idx (linear), zero-pad invalid taps
    for (int idx = tid; idx < 2688; idx += 256){
        int kh = idx/384, rem = idx - kh*384;
        int v = rem >> 3, c8 = rem & 7;
        int tt = t + kh - 3;
        uint4 u; u.x = 0; u.y = 0; u.z = 0; u.w = 0;
        if (tt >= 0 && tt < TT)
            u = *(const uint4*)(fbf + ((size_t)(b*TT+tt)*VV + v)*256 + 64 + c8*8);
        *(uint4*)(&W[idx*8]) = u;
    }
    __syncthreads();
    int o = tid & 63, vv = tid >> 6;
    int g = o >> 3;
    float bv = tb[o];
    float acc[12];
    #pragma unroll
    for (int j = 0; j < 12; j++) acc[j] = bv;
    for (int kh = 0; kh < 7; kh++){
        float wk[8];
        #pragma unroll
        for (int ci = 0; ci < 8; ci++) wk[ci] = tw[(o*8+ci)*7 + kh];
        const unsigned short* base = &W[kh*3072 + g*8];
        #pragma unroll
        for (int j = 0; j < 12; j++){
            uint4 u = *(const uint4*)(base + (vv*12 + j)*64);
            float fv[8]; unpk8(u, fv);
            acc[j] += fv[0]*wk[0]+fv[1]*wk[1]+fv[2]*wk[2]+fv[3]*wk[3]
                    + fv[4]*wk[4]+fv[5]*wk[5]+fv[6]*wk[6]+fv[7]*wk[7];
        }
    }
    int nb = bt*VV;
    #pragma unroll
    for (int j = 0; j < 12; j++)
        ybf[(size_t)(nb + vv*12 + j)*256 + 64 + o] = f2bf(acc[j]);
}

extern "C" void kernel_launch(void* const* d_in, const int* in_sizes, int n_in,
                              void* d_out, int out_size, void* d_ws, size_t ws_size,
                              hipStream_t stream){
    const float* input   = (const float*)d_in[0];
    const float* n1g     = (const float*)d_in[1];
    const float* n1b     = (const float*)d_in[2];
    const float* map_w   = (const float*)d_in[3];
    const float* map_b   = (const float*)d_in[4];
    const float* gconv   = (const float*)d_in[5];
    const float* tconv_w = (const float*)d_in[6];
    const float* tconv_b = (const float*)d_in[7];
    const float* qkv_w0  = (const float*)d_in[8];
    const float* qkv_b0  = (const float*)d_in[9];
    const float* aproj_w0= (const float*)d_in[10];
    const float* aproj_b0= (const float*)d_in[11];
    const float* tcl_w0  = (const float*)d_in[12];
    const float* tcl_b0  = (const float*)d_in[13];
    const float* qkv_w1  = (const float*)d_in[14];
    const float* qkv_b1  = (const float*)d_in[15];
    const float* aproj_w1= (const float*)d_in[16];
    const float* aproj_b1= (const float*)d_in[17];
    const float* tcl_w1  = (const float*)d_in[18];
    const float* tcl_b1  = (const float*)d_in[19];
    const float* proj_w  = (const float*)d_in[20];
    const float* proj_b  = (const float*)d_in[21];
    const float* n2g     = (const float*)d_in[22];
    const float* n2b     = (const float*)d_in[23];
    const float* mlp_w1  = (const float*)d_in[24];
    const float* mlp_b1  = (const float*)d_in[25];
    const float* mlp_w2  = (const float*)d_in[26];
    const float* mlp_b2  = (const float*)d_in[27];

    const size_t Nt = NTOK;
    if (ws_size < 354050048ull) return;

    char* base = (char*)d_ws;
    unsigned short* outtH  = (unsigned short*)base;                  //  50 MB (bf16 outt)
    unsigned short* fbf    = (unsigned short*)(base + 100663296);    //  50 MB
    unsigned short* a0p    = (unsigned short*)(base + 150994944);    //  40 MB
    unsigned short* qkvbuf = (unsigned short*)(base + 191102976);    //  75 MB
    unsigned short* attnout= (unsigned short*)(base + 266600448);    //  25 MB
    unsigned short* A1     = (unsigned short*)(base + 301989888);    //  50 MB
    char* wp = base + 352321536;
    float* gct            = (float*)wp;
    unsigned short* mapT  = (unsigned short*)(wp + 73728);
    unsigned short* projT = mapT + 65536;
    unsigned short* w1T   = projT + 65536;            // layout anchor (1 MB region)
    unsigned char* w2T8   = (unsigned char*)(w1T + 262144);
    unsigned char* w1T8   = w2T8 + 262144;            // fits in former w2T bf16 gap
    unsigned short* tclT0 = w1T + 262144 + 262144;
    unsigned short* tclT1 = tclT0 + 61440;
    unsigned short* qkvT  = tclT1 + 61440;
    unsigned short* aprojT= qkvT + 24576;

    unsigned char* h8   = (unsigned char*)fbf;   // fp8 Nt x 1024 = 100 MB, spans fbf+a0p+part of qkvbuf (dead)
    unsigned char* xn8  = (unsigned char*)A1;    // fp8 Nt x 256 = 25 MB (A1 region dead by then)
    unsigned short* ybf = (unsigned short*)d_out;
    unsigned short* xskip = ybf + (size_t)256*Nt;
    float* dout = (float*)d_out;

    prep_weights<<<256, 256, 0, stream>>>(gconv, tcl_w0, tcl_w1, map_w, proj_w, mlp_w1, mlp_w2,
                                          qkv_w0, qkv_w1, aproj_w0, aproj_w1,
                                          gct, mapT, projT, w1T8, w2T8, tclT0, tclT1, qkvT, aprojT);
    xpose_ln1<<<NB*TT, 256, 0, stream>>>(input, n1g, n1b, A1, xskip);
    mfma_gemm<256,4><<<1024, 512, 0, stream>>>(A1, mapT, map_b, fbf, nullptr, 256, 2);
    hipMemsetAsync(a0p, 0, A0P_USH*sizeof(unsigned short), stream);
    gemm_k64<0><<<1024, 256, 0, stream>>>(fbf + 128, 512, qkvT,         qkv_b0, qkvbuf);
    gemm_k64<0><<<1024, 256, 0, stream>>>(fbf + 192, 512, qkvT + 12288, qkv_b1, qkvbuf + (size_t)Nt*192);
    attn_win<<<dim3(2048,2), 192, 0, stream>>>(qkvbuf, attnout);
    y0_kernel<<<NB*TT, 256, 0, stream>>>(fbf, gct, ybf);
    y1_kernel<<<NB*TT, 256, 0, stream>>>(fbf, tconv_w, tconv_b, ybf);
    gemm_k64<1><<<1024, 256, 0, stream>>>(attnout,                 128, aprojT,         aproj_b0, a0p);
    tcl_mfma<<<NTOK/192, 256, 0, stream>>>(a0p, tclT0, tcl_b0, ybf, 128);
    gemm_k64<1><<<1024, 256, 0, stream>>>(attnout + (size_t)Nt*64, 128, aprojT + 12288, aproj_b1, a0p);
    tcl_mfma<<<NTOK/192, 256, 0, stream>>>(a0p, tclT1, tcl_b1, ybf, 192);
    proj_ln2<<<512, 512, 0, stream>>>(ybf, projT, proj_b, xskip, n2g, n2b, outtH, xn8);
    mfma_mlp1_fp8<<<4096, 512, 0, stream>>>(xn8, w1T8, mlp_b1, h8);
    mfma_final_fp8<<<1024, 512, 0, stream>>>(h8, w2T8, mlp_b2, outtH, dout);
}

// Round 24
// 514.824 us; speedup vs baseline: 1.0805x; 1.0113x over previous
//
#include <hip/hip_runtime.h>
#include <hip/hip_bf16.h>
#include <math.h>

#define NB 32
#define CC 256
#define TT 64
#define VV 48
#define NTOK (NB*TT*VV)   // 98304
#define LNE 1e-5f
#define PROWS 3264        // (4+64)*48
#define A0P_USH ((size_t)NB*PROWS*192)

typedef __attribute__((ext_vector_type(8))) __bf16 bf16x8;
typedef __attribute__((ext_vector_type(4))) float f32x4;
typedef __attribute__((ext_vector_type(2))) long long2v;

__device__ inline float bfbits2f(unsigned int bits){
    union{unsigned int u; float f;} c; c.u = bits<<16; return c.f;
}
__device__ inline unsigned short f2bf(float x){
    union{ __bf16 h; unsigned short u; } c; c.h = (__bf16)x; return c.u;
}
__device__ inline unsigned char f2fp8(float x){
    int p = __builtin_amdgcn_cvt_pk_fp8_f32(x, x, 0, false);
    return (unsigned char)(p & 0xff);
}
__device__ inline unsigned int pk4fp8(float a, float b, float c, float d){
    int w = 0;
    w = __builtin_amdgcn_cvt_pk_fp8_f32(a, b, w, false);
    w = __builtin_amdgcn_cvt_pk_fp8_f32(c, d, w, true);
    return (unsigned int)w;
}
__device__ __forceinline__ void unpk8(uint4 u, float* d){
    d[0]=bfbits2f(u.x&0xffffu); d[1]=bfbits2f(u.x>>16);
    d[2]=bfbits2f(u.y&0xffffu); d[3]=bfbits2f(u.y>>16);
    d[4]=bfbits2f(u.z&0xffffu); d[5]=bfbits2f(u.z>>16);
    d[6]=bfbits2f(u.w&0xffffu); d[7]=bfbits2f(u.w>>16);
}
// 4*gelu(x) via sigmoid form: 4x * rcp(1 + exp(-1.702x)).
__device__ __forceinline__ float gelu4_fast(float x){
    float e = __expf(-1.702f * x);
    return (4.f * x) * __builtin_amdgcn_rcpf(1.f + e);
}

__device__ __forceinline__ void gll16(const char* g, char* l){
    __builtin_amdgcn_global_load_lds(
        (const __attribute__((address_space(1))) unsigned int*)g,
        (__attribute__((address_space(3))) unsigned int*)l, 16, 0, 0);
}

// ---------------- weight prep ----------------
__global__ void prep_weights(const float* gconv, const float* tcl0, const float* tcl1,
                             const float* map_w, const float* proj_w,
                             const float* mlp_w1, const float* mlp_w2,
                             const float* qkv_w0, const float* qkv_w1,
                             const float* aproj_w0, const float* aproj_w1,
                             float* gct,
                             unsigned short* mapT, unsigned short* projT,
                             unsigned char* w1T8, unsigned char* w2T8,
                             unsigned short* tclT0, unsigned short* tclT1,
                             unsigned short* qkvT, unsigned short* aprojT){
    int tid = blockIdx.x*blockDim.x + threadIdx.x;
    int stride = gridDim.x*blockDim.x;
    for (int i = tid; i < 8*48*48; i += stride){
        int g = i/(48*48); int r = i%(48*48); int u = r/48; int v = r%48;
        gct[i] = gconv[(g*48+v)*48+u];
    }
    for (int i = tid; i < 64*960; i += stride){
        int o = i/960, col = i%960, kh = col/192, c = col%192;
        tclT0[i] = f2bf(tcl0[(o*192+c)*5+kh]);
        tclT1[i] = f2bf(tcl1[(o*192+c)*5+kh]);
    }
    for (int i = tid; i < 65536; i += stride){
        int n = i>>8, k = i&255;
        mapT[i] = f2bf(map_w[k*256+n]);
        projT[i] = f2bf(proj_w[k*256+n]);
    }
    // w1T8[n][k] = fp8(mlp_w1[k][n] * 64)
    for (int i = tid; i < 262144; i += stride){
        int n = i>>8, k = i&255;
        w1T8[i] = f2fp8(mlp_w1[k*1024+n] * 64.f);
    }
    // w2T8[n][k] = fp8(mlp_w2[k][n] * 32)
    for (int i = tid; i < 262144; i += stride){
        int n = i>>10, k = i&1023;
        w2T8[i] = f2fp8(mlp_w2[k*256+n] * 32.f);
    }
    for (int i = tid; i < 12288; i += stride){
        int n = i/64, k = i%64;
        qkvT[i]          = f2bf(qkv_w0[k*192+n]);
        qkvT[12288+i]    = f2bf(qkv_w1[k*192+n]);
        aprojT[i]        = f2bf(aproj_w0[k*192+n]);
        aprojT[12288+i]  = f2bf(aproj_w1[k*192+n]);
    }
}

// ---------------- LN1 + transpose -> A1 bf16 [N][256] + raw skip copy ----------------
__global__ __launch_bounds__(256) void xpose_ln1(const float* __restrict__ x,
        const float* __restrict__ g, const float* __restrict__ bb,
        unsigned short* __restrict__ A1, unsigned short* __restrict__ xskip){
    int bt = blockIdx.x; int b = bt/TT, t = bt%TT;
    __shared__ float X[48*257];
    __shared__ float S[4][48], SS[4][48], sm[48], sv[48];
    int tid = threadIdx.x;
    const float* xb = x + (size_t)b*256*3072 + (size_t)t*48;
    for (int it = 0; it < 12; it++){
        int idx = it*256 + tid;
        int c = idx/12, q = idx%12;
        float4 v = *(const float4*)(xb + (size_t)c*3072 + q*4);
        X[(q*4+0)*257 + c] = v.x;
        X[(q*4+1)*257 + c] = v.y;
        X[(q*4+2)*257 + c] = v.z;
        X[(q*4+3)*257 + c] = v.w;
    }
    __syncthreads();
    if (tid < 192){
        int v = tid % 48, w = tid / 48;
        float s = 0.f, ss = 0.f;
        for (int c = w*64; c < w*64+64; c++){
            float val = X[v*257 + c];
            s += val; ss += val*val;
        }
        S[w][v] = s; SS[w][v] = ss;
    }
    __syncthreads();
    if (tid < 48){
        float s = S[0][tid]+S[1][tid]+S[2][tid]+S[3][tid];
        float q = SS[0][tid]+SS[1][tid]+SS[2][tid]+SS[3][tid];
        float m = s*(1.f/256);
        sm[tid] = m; sv[tid] = rsqrtf(q*(1.f/256) - m*m + LNE);
    }
    __syncthreads();
    int nb = bt*48;
    for (int it = 0; it < 12; it++){
        int idx = it*256 + tid;
        int v = idx>>6, cq = idx&63;
        float m = sm[v], rs = sv[v];
        float4 g4 = *(const float4*)(g + cq*4);
        float4 b4 = *(const float4*)(bb + cq*4);
        float x0 = X[v*257 + cq*4+0], x1 = X[v*257 + cq*4+1];
        float x2 = X[v*257 + cq*4+2], x3 = X[v*257 + cq*4+3];
        ushort4 u;
        u.x = f2bf((x0-m)*rs*g4.x + b4.x);
        u.y = f2bf((x1-m)*rs*g4.y + b4.y);
        u.z = f2bf((x2-m)*rs*g4.z + b4.z);
        u.w = f2bf((x3-m)*rs*g4.w + b4.w);
        *(ushort4*)(A1 + (size_t)(nb+v)*256 + cq*4) = u;
        ushort4 s;
        s.x = f2bf(x0); s.y = f2bf(x1); s.z = f2bf(x2); s.w = f2bf(x3);
        *(ushort4*)(xskip + (size_t)(nb+v)*256 + cq*4) = s;
    }
}

// ---------------- swizzled staging (single-shot, for k64 GEMM) ----------------
__device__ __forceinline__ void stage_swz(const char* src, size_t rowbytes, char* lds,
                                          int nchunks, int tid){
    for (int c = tid; c < nchunks; c += 256){
        int p = c << 4;
        int r = p >> 7;
        int kl = (p & 127) ^ ((r & 7) << 4);
        gll16(src + (size_t)r*rowbytes + kl, lds + p);
    }
}

__device__ __forceinline__ bf16x8 frag_ld(const char* lds, int R, int kb){
    return *(const bf16x8*)(lds + R*128 + (kb ^ ((R & 7) << 4)));
}
// 16-byte fp8 fragment read (conflict-free b128 pattern); the two 8-byte
// halves feed two MFMAs. K-permutation is identical for A and B -> exact.
__device__ __forceinline__ long2v frag_ld16(const char* lds, int R, int kb){
    return *(const long2v*)(lds + R*128 + (kb ^ ((R & 7) << 4)));
}

// ---------------- MFMA GEMM: BM=192, BN=128, 8 waves, dbuf + counted vmcnt ----------------
// EPI 4: outH = bf16(acc + bias)   [LDS repack, 16B stores]
template<int KTOT, int EPI>
__global__ __launch_bounds__(512, 4) void mfma_gemm(
    const unsigned short* __restrict__ A, const unsigned short* __restrict__ BT,
    const float* __restrict__ bias,
    unsigned short* __restrict__ outH, unsigned char* __restrict__ outH8,
    int ncols, int nx){

    constexpr int BM = 192, BN = 128;
    constexpr int HALF = (BM+BN)*128;           // 40960
    __shared__ __align__(16) char smem[2*HALF]; // 81920 -> 2 blocks/CU
    int tid = threadIdx.x, lane = tid & 63;
    int wid = tid >> 6;
    int wm = wid >> 1, wn = wid & 1;
    int l15 = lane & 15, lq = lane >> 4;
    int bid = blockIdx.x;
    int per = gridDim.x >> 3;
    int wkid = (bid & 7)*per + (bid >> 3);
    int m0 = (wkid / nx) * BM, n0 = (wkid % nx) * BN;
    const size_t arb = KTOT*2, brb = KTOT*2;
    constexpr int KT = KTOT/64;

    const char* gA[3]; int loA[3];
    const char* gB[2]; int loB[2];
    {
        const char* Ab = (const char*)A + (size_t)m0*arb;
        const char* Bb = (const char*)BT + (size_t)n0*brb;
        #pragma unroll
        for (int i = 0; i < 3; i++){
            int c = tid + i*512;
            int p = c << 4, r = p >> 7;
            int kl = (p & 127) ^ ((r & 7) << 4);
            gA[i] = Ab + (size_t)r*arb + kl; loA[i] = p;
        }
        #pragma unroll
        for (int i = 0; i < 2; i++){
            int c = tid + i*512;
            int p = c << 4, r = p >> 7;
            int kl = (p & 127) ^ ((r & 7) << 4);
            gB[i] = Bb + (size_t)r*brb + kl; loB[i] = BM*128 + p;
        }
    }

    f32x4 acc[3][4];
    #pragma unroll
    for (int i = 0; i < 3; i++)
        #pragma unroll
        for (int j = 0; j < 4; j++){ f32x4 z = {0.f,0.f,0.f,0.f}; acc[i][j] = z; }

    #pragma unroll
    for (int i = 0; i < 3; i++) gll16(gA[i], smem + loA[i]);
    #pragma unroll
    for (int i = 0; i < 2; i++) gll16(gB[i], smem + loB[i]);

    int koff = 128;
    for (int kt = 0; kt < KT; kt++){
        char* cur = smem + (kt & 1)*HALF;
        if (kt + 1 < KT){
            char* nxt = smem + ((kt + 1) & 1)*HALF;
            #pragma unroll
            for (int i = 0; i < 3; i++) gll16(gA[i] + koff, nxt + loA[i]);
            #pragma unroll
            for (int i = 0; i < 2; i++) gll16(gB[i] + koff, nxt + loB[i]);
            koff += 128;
            asm volatile("s_waitcnt vmcnt(5)" ::: "memory");
        } else {
            asm volatile("s_waitcnt vmcnt(0)" ::: "memory");
        }
        __builtin_amdgcn_s_barrier();
        __builtin_amdgcn_sched_barrier(0);
        char* ldsA = cur;
        char* ldsB = cur + BM*128;
        #pragma unroll
        for (int ks = 0; ks < 2; ks++){
            bf16x8 a[3], b[4];
            int kb = ks*64 + lq*16;
            #pragma unroll
            for (int mf = 0; mf < 3; mf++) a[mf] = frag_ld(ldsA, wm*48 + mf*16 + l15, kb);
            #pragma unroll
            for (int nf = 0; nf < 4; nf++) b[nf] = frag_ld(ldsB, wn*64 + nf*16 + l15, kb);
            #pragma unroll
            for (int mf = 0; mf < 3; mf++)
                #pragma unroll
                for (int nf = 0; nf < 4; nf++)
                    acc[mf][nf] = __builtin_amdgcn_mfma_f32_16x16x32_bf16(a[mf], b[nf], acc[mf][nf], 0, 0, 0);
        }
        __builtin_amdgcn_sched_barrier(0);
        __builtin_amdgcn_s_barrier();
    }

    if constexpr (EPI == 4){
        unsigned short* Hs = (unsigned short*)smem;   // [192][136]
        #pragma unroll
        for (int nf = 0; nf < 4; nf++){
            int col = wn*64 + nf*16 + l15;
            float bb = bias[n0 + col];
            #pragma unroll
            for (int mf = 0; mf < 3; mf++){
                int row = wm*48 + mf*16 + lq*4;
                f32x4 v = acc[mf][nf];
                #pragma unroll
                for (int r = 0; r < 4; r++)
                    Hs[(row+r)*136 + col] = f2bf(v[r] + bb);
            }
        }
        __syncthreads();
        for (int idx = tid; idx < 192*16; idx += 512){
            int row = idx >> 4, c8 = idx & 15;
            *(uint4*)(outH + (size_t)(m0+row)*ncols + n0 + c8*8) =
                *(const uint4*)(Hs + row*136 + c8*8);
        }
    }
}

// ---------------- MLP1 GEMM in fp8: K=256 as 2 tiles of K=128 (128B rows) ----------------
// outH8 = fp8(gelu4((acc/64) + bias)); b128 fragment reads (K-permuted, exact)
__global__ __launch_bounds__(512, 4) void mfma_mlp1_fp8(
    const unsigned char* __restrict__ A, const unsigned char* __restrict__ BT,
    const float* __restrict__ bias, unsigned char* __restrict__ outH8){

    constexpr int BM = 192, BN = 128, NX = 8;
    constexpr int HALF = (BM+BN)*128;           // 40960
    __shared__ __align__(16) char smem[2*HALF]; // 81920 -> 2 blocks/CU
    int tid = threadIdx.x, lane = tid & 63;
    int wid = tid >> 6;
    int wm = wid >> 1, wn = wid & 1;
    int l15 = lane & 15, lq = lane >> 4;
    int bid = blockIdx.x;
    int per = gridDim.x >> 3;
    int wkid = (bid & 7)*per + (bid >> 3);
    int m0 = (wkid / NX) * BM, n0 = (wkid % NX) * BN;
    const size_t arb = 256, brb = 256;
    constexpr int KT = 2;

    const char* gA[3]; int loA[3];
    const char* gB[2]; int loB[2];
    {
        const char* Ab = (const char*)A + (size_t)m0*arb;
        const char* Bb = (const char*)BT + (size_t)n0*brb;
        #pragma unroll
        for (int i = 0; i < 3; i++){
            int c = tid + i*512;
            int p = c << 4, r = p >> 7;
            int kl = (p & 127) ^ ((r & 7) << 4);
            gA[i] = Ab + (size_t)r*arb + kl; loA[i] = p;
        }
        #pragma unroll
        for (int i = 0; i < 2; i++){
            int c = tid + i*512;
            int p = c << 4, r = p >> 7;
            int kl = (p & 127) ^ ((r & 7) << 4);
            gB[i] = Bb + (size_t)r*brb + kl; loB[i] = BM*128 + p;
        }
    }

    f32x4 acc[3][4];
    #pragma unroll
    for (int i = 0; i < 3; i++)
        #pragma unroll
        for (int j = 0; j < 4; j++){ f32x4 z = {0.f,0.f,0.f,0.f}; acc[i][j] = z; }

    #pragma unroll
    for (int i = 0; i < 3; i++) gll16(gA[i], smem + loA[i]);
    #pragma unroll
    for (int i = 0; i < 2; i++) gll16(gB[i], smem + loB[i]);

    int koff = 128;
    for (int kt = 0; kt < KT; kt++){
        char* cur = smem + (kt & 1)*HALF;
        if (kt + 1 < KT){
            char* nxt = smem + ((kt + 1) & 1)*HALF;
            #pragma unroll
            for (int i = 0; i < 3; i++) gll16(gA[i] + koff, nxt + loA[i]);
            #pragma unroll
            for (int i = 0; i < 2; i++) gll16(gB[i] + koff, nxt + loB[i]);
            koff += 128;
            asm volatile("s_waitcnt vmcnt(5)" ::: "memory");
        } else {
            asm volatile("s_waitcnt vmcnt(0)" ::: "memory");
        }
        __builtin_amdgcn_s_barrier();
        __builtin_amdgcn_sched_barrier(0);
        char* ldsA = cur;
        char* ldsB = cur + BM*128;
        #pragma unroll
        for (int hf = 0; hf < 2; hf++){
            long2v a[3], b[4];
            int kb = hf*64 + lq*16;
            #pragma unroll
            for (int mf = 0; mf < 3; mf++) a[mf] = frag_ld16(ldsA, wm*48 + mf*16 + l15, kb);
            #pragma unroll
            for (int nf = 0; nf < 4; nf++) b[nf] = frag_ld16(ldsB, wn*64 + nf*16 + l15, kb);
            #pragma unroll
            for (int mf = 0; mf < 3; mf++)
                #pragma unroll
                for (int nf = 0; nf < 4; nf++){
                    acc[mf][nf] = __builtin_amdgcn_mfma_f32_16x16x32_fp8_fp8(a[mf][0], b[nf][0], acc[mf][nf], 0, 0, 0);
                    acc[mf][nf] = __builtin_amdgcn_mfma_f32_16x16x32_fp8_fp8(a[mf][1], b[nf][1], acc[mf][nf], 0, 0, 0);
                }
        }
        __builtin_amdgcn_sched_barrier(0);
        __builtin_amdgcn_s_barrier();
    }

    unsigned char* Hc = (unsigned char*)smem;     // [192][144] fp8
    #pragma unroll
    for (int nf = 0; nf < 4; nf++){
        int col = wn*64 + nf*16 + l15;
        float bb = bias[n0 + col];
        #pragma unroll
        for (int mf = 0; mf < 3; mf++){
            int row = wm*48 + mf*16 + lq*4;
            f32x4 v = acc[mf][nf];
            #pragma unroll
            for (int r = 0; r < 4; r++){
                float t0 = gelu4_fast(v[r]*0.015625f + bb);
                Hc[(row+r)*144 + col] = f2fp8(t0);
            }
        }
    }
    __syncthreads();
    for (int idx = tid; idx < 192*8; idx += 512){
        int row = idx >> 3, c16 = idx & 7;
        *(uint4*)(outH8 + (size_t)(m0+row)*1024 + n0 + c16*16) =
            *(const uint4*)(Hc + row*144 + c16*16);
    }
}

// ---------------- final GEMM in fp8: K=1024 as 8 tiles of K=128 (128B rows) ----------------
__global__ __launch_bounds__(512, 4) void mfma_final_fp8(
    const unsigned char* __restrict__ A, const unsigned char* __restrict__ BT,
    const float* __restrict__ bias, const unsigned short* __restrict__ extraH,
    float* __restrict__ outF){

    constexpr int BM = 192, BN = 128, NX = 2;
    constexpr int HALF = (BM+BN)*128;           // 40960
    __shared__ __align__(16) char smem[2*HALF]; // 81920 -> 2 blocks/CU
    int tid = threadIdx.x, lane = tid & 63;
    int wid = tid >> 6;
    int wm = wid >> 1, wn = wid & 1;
    int l15 = lane & 15, lq = lane >> 4;
    int bid = blockIdx.x;
    int per = gridDim.x >> 3;
    int wkid = (bid & 7)*per + (bid >> 3);
    int m0 = (wkid / NX) * BM, n0 = (wkid % NX) * BN;
    const size_t arb = 1024, brb = 1024;
    constexpr int KT = 8;

    const char* gA[3]; int loA[3];
    const char* gB[2]; int loB[2];
    {
        const char* Ab = (const char*)A + (size_t)m0*arb;
        const char* Bb = (const char*)BT + (size_t)n0*brb;
        #pragma unroll
        for (int i = 0; i < 3; i++){
            int c = tid + i*512;
            int p = c << 4, r = p >> 7;
            int kl = (p & 127) ^ ((r & 7) << 4);
            gA[i] = Ab + (size_t)r*arb + kl; loA[i] = p;
        }
        #pragma unroll
        for (int i = 0; i < 2; i++){
            int c = tid + i*512;
            int p = c << 4, r = p >> 7;
            int kl = (p & 127) ^ ((r & 7) << 4);
            gB[i] = Bb + (size_t)r*brb + kl; loB[i] = BM*128 + p;
        }
    }

    f32x4 acc[3][4];
    #pragma unroll
    for (int i = 0; i < 3; i++)
        #pragma unroll
        for (int j = 0; j < 4; j++){ f32x4 z = {0.f,0.f,0.f,0.f}; acc[i][j] = z; }

    #pragma unroll
    for (int i = 0; i < 3; i++) gll16(gA[i], smem + loA[i]);
    #pragma unroll
    for (int i = 0; i < 2; i++) gll16(gB[i], smem + loB[i]);

    int koff = 128;
    for (int kt = 0; kt < KT; kt++){
        char* cur = smem + (kt & 1)*HALF;
        if (kt + 1 < KT){
            char* nxt = smem + ((kt + 1) & 1)*HALF;
            #pragma unroll
            for (int i = 0; i < 3; i++) gll16(gA[i] + koff, nxt + loA[i]);
            #pragma unroll
            for (int i = 0; i < 2; i++) gll16(gB[i] + koff, nxt + loB[i]);
            koff += 128;
            asm volatile("s_waitcnt vmcnt(5)" ::: "memory");
        } else {
            asm volatile("s_waitcnt vmcnt(0)" ::: "memory");
        }
        __builtin_amdgcn_s_barrier();
        __builtin_amdgcn_sched_barrier(0);
        char* ldsA = cur;
        char* ldsB = cur + BM*128;
        #pragma unroll
        for (int hf = 0; hf < 2; hf++){
            long2v a[3], b[4];
            int kb = hf*64 + lq*16;
            #pragma unroll
            for (int mf = 0; mf < 3; mf++) a[mf] = frag_ld16(ldsA, wm*48 + mf*16 + l15, kb);
            #pragma unroll
            for (int nf = 0; nf < 4; nf++) b[nf] = frag_ld16(ldsB, wn*64 + nf*16 + l15, kb);
            #pragma unroll
            for (int mf = 0; mf < 3; mf++)
                #pragma unroll
                for (int nf = 0; nf < 4; nf++){
                    acc[mf][nf] = __builtin_amdgcn_mfma_f32_16x16x32_fp8_fp8(a[mf][0], b[nf][0], acc[mf][nf], 0, 0, 0);
                    acc[mf][nf] = __builtin_amdgcn_mfma_f32_16x16x32_fp8_fp8(a[mf][1], b[nf][1], acc[mf][nf], 0, 0, 0);
                }
        }
        __builtin_amdgcn_sched_barrier(0);
        __builtin_amdgcn_s_barrier();
    }

    // epilogue: dout NCHW = acc/128 + bias + resid (bf16 outtH), two-pass transpose
    float* Tt = (float*)smem;  // [64 cols][196]
    #pragma unroll
    for (int ph = 0; ph < 2; ph++){
        __syncthreads();
        if (wn == ph){
            #pragma unroll
            for (int nf = 0; nf < 4; nf++){
                int lc = nf*16 + l15;
                float bb = bias[n0 + ph*64 + lc];
                #pragma unroll
                for (int mf = 0; mf < 3; mf++){
                    int tl = wm*48 + mf*16 + lq*4;
                    f32x4 v = acc[mf][nf];
                    #pragma unroll
                    for (int r = 0; r < 4; r++){
                        float resid = bfbits2f(extraH[(size_t)(m0+tl+r)*256 + n0 + ph*64 + lc]);
                        Tt[lc*196 + tl + r] = v[r]*0.0078125f + bb + resid;
                    }
                }
            }
        }
        __syncthreads();
        {
            int lc = tid & 63, btl = (tid>>6)&3, dup = tid>>8;
            int gtok = m0 + btl*48;
            int bg = gtok/3072, t = (gtok%3072)/48;
            float* dst = outF + ((size_t)(bg*256 + n0 + ph*64 + lc)*64 + t)*48 + dup*24;
            const float* tr = Tt + lc*196 + btl*48 + dup*24;
            #pragma unroll
            for (int j = 0; j < 6; j++)
                *(float4*)(dst + j*4) = *(const float4*)(tr + j*4);
        }
    }
}

// ---------------- proj GEMM fused with skip-add + LN2: BM=192, BN=256, K=256 ----------------
// xn output fp8 (input to fp8 MLP1)
__global__ __launch_bounds__(512, 2) void proj_ln2(
    const unsigned short* __restrict__ A, const unsigned short* __restrict__ BT,
    const float* __restrict__ bias, const unsigned short* __restrict__ xskip,
    const float* __restrict__ n2g, const float* __restrict__ n2b,
    unsigned short* __restrict__ outtH, unsigned char* __restrict__ xn8){

    constexpr int BM = 192, BN = 256, KTOT = 256;
    constexpr int HALF = (BM+BN)*128;
    __shared__ __align__(16) char smem[2*HALF];
    int tid = threadIdx.x, lane = tid & 63;
    int wid = tid >> 6;
    int wm = wid >> 1, wn = wid & 1;
    int l15 = lane & 15, lq = lane >> 4;
    int bid = blockIdx.x;
    int per = gridDim.x >> 3;
    int wkid = (bid & 7)*per + (bid >> 3);
    int m0 = wkid * BM;
    const size_t arb = KTOT*2, brb = KTOT*2;
    constexpr int KT = KTOT/64;

    const char* gA[3]; int loA[3];
    const char* gB[4]; int loB[4];
    {
        const char* Ab = (const char*)A + (size_t)m0*arb;
        const char* Bb = (const char*)BT;
        #pragma unroll
        for (int i = 0; i < 3; i++){
            int c = tid + i*512;
            int p = c << 4, r = p >> 7;
            int kl = (p & 127) ^ ((r & 7) << 4);
            gA[i] = Ab + (size_t)r*arb + kl; loA[i] = p;
        }
        #pragma unroll
        for (int i = 0; i < 4; i++){
            int c = tid + i*512;
            int p = c << 4, r = p >> 7;
            int kl = (p & 127) ^ ((r & 7) << 4);
            gB[i] = Bb + (size_t)r*brb + kl; loB[i] = BM*128 + p;
        }
    }

    f32x4 acc[3][8];
    #pragma unroll
    for (int i = 0; i < 3; i++)
        #pragma unroll
        for (int j = 0; j < 8; j++){ f32x4 z = {0.f,0.f,0.f,0.f}; acc[i][j] = z; }

    #pragma unroll
    for (int i = 0; i < 3; i++) gll16(gA[i], smem + loA[i]);
    #pragma unroll
    for (int i = 0; i < 4; i++) gll16(gB[i], smem + loB[i]);

    int koff = 128;
    for (int kt = 0; kt < KT; kt++){
        char* cur = smem + (kt & 1)*HALF;
        if (kt + 1 < KT){
            char* nxt = smem + ((kt + 1) & 1)*HALF;
            #pragma unroll
            for (int i = 0; i < 3; i++) gll16(gA[i] + koff, nxt + loA[i]);
            #pragma unroll
            for (int i = 0; i < 4; i++) gll16(gB[i] + koff, nxt + loB[i]);
            koff += 128;
            asm volatile("s_waitcnt vmcnt(7)" ::: "memory");
        } else {
            asm volatile("s_waitcnt vmcnt(0)" ::: "memory");
        }
        __builtin_amdgcn_s_barrier();
        __builtin_amdgcn_sched_barrier(0);
        char* ldsA = cur;
        char* ldsB = cur + BM*128;
        #pragma unroll
        for (int ks = 0; ks < 2; ks++){
            bf16x8 a[3], b[8];
            int kb = ks*64 + lq*16;
            #pragma unroll
            for (int mf = 0; mf < 3; mf++) a[mf] = frag_ld(ldsA, wm*48 + mf*16 + l15, kb);
            #pragma unroll
            for (int nf = 0; nf < 8; nf++) b[nf] = frag_ld(ldsB, wn*128 + nf*16 + l15, kb);
            #pragma unroll
            for (int mf = 0; mf < 3; mf++)
                #pragma unroll
                for (int nf = 0; nf < 8; nf++)
                    acc[mf][nf] = __builtin_amdgcn_mfma_f32_16x16x32_bf16(a[mf], b[nf], acc[mf][nf], 0, 0, 0);
        }
        __builtin_amdgcn_sched_barrier(0);
        __builtin_amdgcn_s_barrier();
    }

    unsigned short* Hs = (unsigned short*)smem;
    float* Sred = (float*)(smem + 101376);
    float s_acc[3][4], ss_acc[3][4];
    #pragma unroll
    for (int i = 0; i < 3; i++)
        #pragma unroll
        for (int r = 0; r < 4; r++){ s_acc[i][r] = 0.f; ss_acc[i][r] = 0.f; }

    #pragma unroll
    for (int nf = 0; nf < 8; nf++){
        int col = wn*128 + nf*16 + l15;
        float bb = bias[col];
        #pragma unroll
        for (int mf = 0; mf < 3; mf++){
            int row = wm*48 + mf*16 + lq*4;
            f32x4 v = acc[mf][nf];
            #pragma unroll
            for (int r = 0; r < 4; r++){
                float sk = bfbits2f(xskip[(size_t)(m0+row+r)*256 + col]);
                unsigned short us = f2bf(v[r] + bb + sk);
                Hs[(row+r)*264 + col] = us;
                float tf = bfbits2f(us);
                s_acc[mf][r] += tf; ss_acc[mf][r] += tf*tf;
            }
        }
    }
    #pragma unroll
    for (int mf = 0; mf < 3; mf++)
        #pragma unroll
        for (int r = 0; r < 4; r++){
            float s = s_acc[mf][r], ss = ss_acc[mf][r];
            #pragma unroll
            for (int d = 1; d < 16; d <<= 1){
                s  += __shfl_xor(s, d);
                ss += __shfl_xor(ss, d);
            }
            if (l15 == 0){
                int row = wm*48 + mf*16 + lq*4 + r;
                Sred[wn*192 + row] = s;
                Sred[384 + wn*192 + row] = ss;
            }
        }
    __syncthreads();
    if (tid < 192){
        float s  = Sred[tid] + Sred[192+tid];
        float ss = Sred[384+tid] + Sred[576+tid];
        float m = s*(1.f/256);
        Sred[tid] = m;
        Sred[192+tid] = rsqrtf(ss*(1.f/256) - m*m + LNE);
    }
    __syncthreads();
    for (int idx = tid; idx < 192*32; idx += 512){
        int row = idx >> 5, c8 = idx & 31;
        uint4 hv = *(const uint4*)(Hs + row*264 + c8*8);
        *(uint4*)(outtH + (size_t)(m0+row)*256 + c8*8) = hv;
        float v[8]; unpk8(hv, v);
        float m = Sred[row], rs = Sred[192+row];
        float xv[8];
        #pragma unroll
        for (int j = 0; j < 8; j++)
            xv[j] = (v[j]-m)*rs*n2g[c8*8 + j] + n2b[c8*8 + j];
        uint2 o;
        o.x = pk4fp8(xv[0], xv[1], xv[2], xv[3]);
        o.y = pk4fp8(xv[4], xv[5], xv[6], xv[7]);
        *(uint2*)(xn8 + (size_t)(m0+row)*256 + c8*8) = o;
    }
}

// ---------------- K=64 MFMA GEMM: BM=96, BN=192, 4 waves ----------------
template<int EPI>
__global__ __launch_bounds__(256) void gemm_k64(
    const unsigned short* __restrict__ A, int arb,
    const unsigned short* __restrict__ BT,
    const float* __restrict__ bias,
    unsigned short* __restrict__ out){
    __shared__ __align__(16) char smem[96*128 + 192*128];
    char* ldsA = smem;
    char* ldsB = smem + 96*128;
    int tid = threadIdx.x, lane = tid & 63;
    int wid = tid >> 6, wm = wid >> 1, wn = wid & 1;
    int l15 = lane & 15, lq = lane >> 4;
    int m0 = blockIdx.x * 96;

    stage_swz((const char*)A + (size_t)m0*arb, arb, ldsA, 96*8, tid);
    stage_swz((const char*)BT, 128, ldsB, 192*8, tid);
    __syncthreads();

    f32x4 acc[3][6];
    #pragma unroll
    for (int i = 0; i < 3; i++)
        #pragma unroll
        for (int j = 0; j < 6; j++){ f32x4 z = {0.f,0.f,0.f,0.f}; acc[i][j] = z; }

    #pragma unroll
    for (int ks = 0; ks < 2; ks++){
        bf16x8 a[3], b[6];
        int kb = ks*64 + lq*16;
        #pragma unroll
        for (int mf = 0; mf < 3; mf++) a[mf] = frag_ld(ldsA, wm*48 + mf*16 + l15, kb);
        #pragma unroll
        for (int nf = 0; nf < 6; nf++) b[nf] = frag_ld(ldsB, wn*96 + nf*16 + l15, kb);
        #pragma unroll
        for (int mf = 0; mf < 3; mf++)
            #pragma unroll
            for (int nf = 0; nf < 6; nf++)
                acc[mf][nf] = __builtin_amdgcn_mfma_f32_16x16x32_bf16(a[mf], b[nf], acc[mf][nf], 0, 0, 0);
    }

    size_t row0;
    if constexpr (EPI == 0) row0 = (size_t)m0;
    else {
        int b = m0/3072;
        row0 = (size_t)b*PROWS + 192 + (m0 - b*3072);
    }
    #pragma unroll
    for (int nf = 0; nf < 6; nf++){
        int col = wn*96 + nf*16 + l15;
        float bb = bias[col];
        #pragma unroll
        for (int mf = 0; mf < 3; mf++){
            size_t rr = row0 + wm*48 + mf*16 + lq*4;
            f32x4 v = acc[mf][nf];
            #pragma unroll
            for (int r = 0; r < 4; r++)
                out[(rr+r)*192 + col] = f2bf(v[r] + bb);
        }
    }
}

// ---------------- windowed attention ----------------
__global__ __launch_bounds__(192) void attn_win(
        const unsigned short* __restrict__ qkvbuf,
        unsigned short* __restrict__ attnout){
    int win = blockIdx.x, br = blockIdx.y;
    size_t base = (size_t)br*NTOK + (size_t)win*48;
    __shared__ float Q[48*196];
    int tid = threadIdx.x;
    const unsigned short* src = qkvbuf + base*192;
    for (int i = 0; i < 6; i++){
        int ch = i*192 + tid;
        int v = ch/24, c8 = ch%24;
        uint4 u = *(const uint4*)(src + (size_t)v*192 + c8*8);
        unpk8(u, &Q[v*196 + c8*8]);
    }
    __syncthreads();
    int u = tid & 15, gh = tid >> 4, g = gh >> 2, h = gh & 3;
    int ru = g*16 + u;
    float qreg[16];
    #pragma unroll
    for (int d = 0; d < 16; d++) qreg[d] = Q[ru*196 + h*16 + d];
    float sc[16]; float mx = -1e30f;
    #pragma unroll
    for (int w = 0; w < 16; w++){
        float s = 0.f;
        #pragma unroll
        for (int d = 0; d < 16; d++) s += qreg[d]*Q[(g*16+w)*196 + 64 + h*16 + d];
        s *= 0.5f; sc[w] = s; mx = fmaxf(mx, s);
    }
    float sum = 0.f;
    #pragma unroll
    for (int w = 0; w < 16; w++){ sc[w] = __expf(sc[w]-mx); sum += sc[w]; }
    float inv = __builtin_amdgcn_rcpf(sum);
    unsigned int w32[8];
    #pragma unroll
    for (int dp = 0; dp < 8; dp++){
        float o0 = 0.f, o1 = 0.f;
        #pragma unroll
        for (int w = 0; w < 16; w++){
            float p = sc[w];
            o0 += p*Q[(g*16+w)*196 + 128 + h*16 + dp*2];
            o1 += p*Q[(g*16+w)*196 + 128 + h*16 + dp*2+1];
        }
        w32[dp] = (unsigned int)f2bf(o0*inv) | ((unsigned int)f2bf(o1*inv) << 16);
    }
    unsigned short* dst = attnout + (base + ru)*64 + h*16;
    uint4 q0; q0.x=w32[0]; q0.y=w32[1]; q0.z=w32[2]; q0.w=w32[3];
    uint4 q1; q1.x=w32[4]; q1.y=w32[5]; q1.z=w32[6]; q1.w=w32[7];
    *(uint4*)(dst)   = q0;
    *(uint4*)(dst+8) = q1;
}

// ---------------- tcl as MFMA GEMM: K=960 (15 tiles), dbuf + counted vmcnt ----------------
__global__ __launch_bounds__(256) void tcl_mfma(const unsigned short* __restrict__ A0p,
        const unsigned short* __restrict__ BT, const float* __restrict__ tb,
        unsigned short* __restrict__ ybf, int outoff){
    constexpr int HALF = (192+64)*128;
    __shared__ __align__(16) char smem[2*HALF];
    int tid = threadIdx.x, lane = tid & 63;
    int wid = tid >> 6;
    int l15 = lane & 15, lq = lane >> 4;
    int bid = blockIdx.x;
    int per = gridDim.x >> 3;
    int wkid = (bid & 7)*per + (bid >> 3);
    int m0 = wkid * 192;
    int b = m0 / 3072;
    long brow0 = (long)b*PROWS + 192 + (m0 - b*3072);

    const char* gA[6]; int loA[6];
    const char* gB[2]; int loB[2];
    {
        const char* Ab = (const char*)A0p + (brow0 - 192)*384;
        #pragma unroll
        for (int i = 0; i < 6; i++){
            int c = tid + i*256;
            int p = c << 4, r = p >> 7;
            int kl = (p & 127) ^ ((r & 7) << 4);
            gA[i] = Ab + (size_t)r*384 + kl; loA[i] = p;
        }
        #pragma unroll
        for (int i = 0; i < 2; i++){
            int c = tid + i*256;
            int p = c << 4, r = p >> 7;
            int kl = (p & 127) ^ ((r & 7) << 4);
            gB[i] = (const char*)BT + (size_t)r*1920 + kl; loB[i] = 192*128 + p;
        }
    }

    f32x4 acc[3][4];
    #pragma unroll
    for (int i = 0; i < 3; i++)
        #pragma unroll
        for (int j = 0; j < 4; j++){ f32x4 z = {0.f,0.f,0.f,0.f}; acc[i][j] = z; }

    #pragma unroll
    for (int i = 0; i < 6; i++) gll16(gA[i], smem + loA[i]);
    #pragma unroll
    for (int i = 0; i < 2; i++) gll16(gB[i], smem + loB[i]);

    long offA = 0; int kc3 = 0; int offB = 0;
    for (int kt = 0; kt < 15; kt++){
        char* cur = smem + (kt & 1)*HALF;
        if (kt + 1 < 15){
            char* nxt = smem + ((kt + 1) & 1)*HALF;
            if (kc3 == 2){ offA += 18432 - 256; kc3 = 0; }
            else         { offA += 128; kc3++; }
            offB += 128;
            #pragma unroll
            for (int i = 0; i < 6; i++) gll16(gA[i] + offA, nxt + loA[i]);
            #pragma unroll
            for (int i = 0; i < 2; i++) gll16(gB[i] + offB, nxt + loB[i]);
            asm volatile("s_waitcnt vmcnt(8)" ::: "memory");
        } else {
            asm volatile("s_waitcnt vmcnt(0)" ::: "memory");
        }
        __builtin_amdgcn_s_barrier();
        __builtin_amdgcn_sched_barrier(0);
        char* ldsA = cur;
        char* ldsB = cur + 192*128;
        #pragma unroll
        for (int ks = 0; ks < 2; ks++){
            bf16x8 a[3], bb[4];
            int kb = ks*64 + lq*16;
            #pragma unroll
            for (int mf = 0; mf < 3; mf++) a[mf] = frag_ld(ldsA, wid*48 + mf*16 + l15, kb);
            #pragma unroll
            for (int nf = 0; nf < 4; nf++) bb[nf] = frag_ld(ldsB, nf*16 + l15, kb);
            #pragma unroll
            for (int mf = 0; mf < 3; mf++)
                #pragma unroll
                for (int nf = 0; nf < 4; nf++)
                    acc[mf][nf] = __builtin_amdgcn_mfma_f32_16x16x32_bf16(a[mf], bb[nf], acc[mf][nf], 0, 0, 0);
        }
        __builtin_amdgcn_sched_barrier(0);
        __builtin_amdgcn_s_barrier();
    }
    #pragma unroll
    for (int nf = 0; nf < 4; nf++){
        int col = nf*16 + l15;
        float bb = tb[col];
        #pragma unroll
        for (int mf = 0; mf < 3; mf++){
            int tok = m0 + wid*48 + mf*16 + lq*4;
            f32x4 v = acc[mf][nf];
            #pragma unroll
            for (int r = 0; r < 4; r++)
                ybf[(size_t)(tok+r)*256 + outoff + col] = f2bf(v[r] + bb);
        }
    }
}

// ---------------- y0: grouped V-mix -> ybf cols 0..63 ----------------
__global__ __launch_bounds__(256) void y0_kernel(const unsigned short* __restrict__ fbf,
        const float* __restrict__ gct, unsigned short* __restrict__ ybf){
    int bt = blockIdx.x; int nb = bt*VV;
    __shared__ float X[48*68];
    for (int it = 0; it < 2; it++){
        int idx = it*256 + threadIdx.x;
        if (idx < 384){
            int v = idx >> 3, c8 = idx & 7;
            uint4 u = *(const uint4*)(fbf + (size_t)(nb+v)*256 + c8*8);
            unpk8(u, &X[v*68 + c8*8]);
        }
    }
    __syncthreads();
    int c = threadIdx.x % 64, vv = threadIdx.x / 64;
    int g = c >> 3;
    float acc[12] = {};
    for (int u = 0; u < 48; u++){
        float xv = X[u*68 + c];
        const float* gr = gct + (size_t)(g*48+u)*48 + vv*12;
        float4 g0 = *(const float4*)(gr);
        float4 g1 = *(const float4*)(gr+4);
        float4 g2 = *(const float4*)(gr+8);
        acc[0]+=xv*g0.x; acc[1]+=xv*g0.y; acc[2]+=xv*g0.z;  acc[3]+=xv*g0.w;
        acc[4]+=xv*g1.x; acc[5]+=xv*g1.y; acc[6]+=xv*g1.z;  acc[7]+=xv*g1.w;
        acc[8]+=xv*g2.x; acc[9]+=xv*g2.y; acc[10]+=xv*g2.z; acc[11]+=xv*g2.w;
    }
    #pragma unroll
    for (int j = 0; j < 12; j++)
        ybf[(size_t)(nb + vv*12 + j)*256 + c] = f2bf(acc[j]);
}

// ---------------- y1: grouped temporal conv (k=7), LDS-staged taps -> ybf cols 64..127 ----------------
__global__ __launch_bounds__(256) void y1_kernel(const unsigned short* __restrict__ fbf,
        const float* __restrict__ tw, const float* __restrict__ tb, unsigned short* __restrict__ ybf){
    int bt = blockIdx.x; int b = bt/TT, t = bt%TT;
    __shared__ unsigned short W[7*48*64];   // 43 KB: [kh][v][ch 64..127]
    int tid = threadIdx.x;
    // coalesced staging: chunk idx -> LDS ushort index 8*idx (linear), zero-pad invalid taps
    for (int idx = tid; idx < 2688; idx += 256){
        int kh = idx/384, rem = idx - kh*384;
        int v = rem >> 3, c8 = rem & 7;
        int tt = t + kh - 3;
        uint4 u; u.x = 0; u.y = 0; u.z = 0; u.w = 0;
        if (tt >= 0 && tt < TT)
            u = *(const uint4*)(fbf + ((size_t)(b*TT+tt)*VV + v)*256 + 64 + c8*8);
        *(uint4*)(&W[idx*8]) = u;
    }
    __syncthreads();
    int o = tid & 63, vv = tid >> 6;
    int g = o >> 3;
    float bv = tb[o];
    float acc[12];
    #pragma unroll
    for (int j = 0; j < 12; j++) acc[j] = bv;
    for (int kh = 0; kh < 7; kh++){
        float wk[8];
        #pragma unroll
        for (int ci = 0; ci < 8; ci++) wk[ci] = tw[(o*8+ci)*7 + kh];
        const unsigned short* base = &W[kh*3072 + g*8];
        #pragma unroll
        for (int j = 0; j < 12; j++){
            uint4 u = *(const uint4*)(base + (vv*12 + j)*64);
            float fv[8]; unpk8(u, fv);
            acc[j] += fv[0]*wk[0]+fv[1]*wk[1]+fv[2]*wk[2]+fv[3]*wk[3]
                    + fv[4]*wk[4]+fv[5]*wk[5]+fv[6]*wk[6]+fv[7]*wk[7];
        }
    }
    int nb = bt*VV;
    #pragma unroll
    for (int j = 0; j < 12; j++)
        ybf[(size_t)(nb + vv*12 + j)*256 + 64 + o] = f2bf(acc[j]);
}

extern "C" void kernel_launch(void* const* d_in, const int* in_sizes, int n_in,
                              void* d_out, int out_size, void* d_ws, size_t ws_size,
                              hipStream_t stream){
    const float* input   = (const float*)d_in[0];
    const float* n1g     = (const float*)d_in[1];
    const float* n1b     = (const float*)d_in[2];
    const float* map_w   = (const float*)d_in[3];
    const float* map_b   = (const float*)d_in[4];
    const float* gconv   = (const float*)d_in[5];
    const float* tconv_w = (const float*)d_in[6];
    const float* tconv_b = (const float*)d_in[7];
    const float* qkv_w0  = (const float*)d_in[8];
    const float* qkv_b0  = (const float*)d_in[9];
    const float* aproj_w0= (const float*)d_in[10];
    const float* aproj_b0= (const float*)d_in[11];
    const float* tcl_w0  = (const float*)d_in[12];
    const float* tcl_b0  = (const float*)d_in[13];
    const float* qkv_w1  = (const float*)d_in[14];
    const float* qkv_b1  = (const float*)d_in[15];
    const float* aproj_w1= (const float*)d_in[16];
    const float* aproj_b1= (const float*)d_in[17];
    const float* tcl_w1  = (const float*)d_in[18];
    const float* tcl_b1  = (const float*)d_in[19];
    const float* proj_w  = (const float*)d_in[20];
    const float* proj_b  = (const float*)d_in[21];
    const float* n2g     = (const float*)d_in[22];
    const float* n2b     = (const float*)d_in[23];
    const float* mlp_w1  = (const float*)d_in[24];
    const float* mlp_b1  = (const float*)d_in[25];
    const float* mlp_w2  = (const float*)d_in[26];
    const float* mlp_b2  = (const float*)d_in[27];

    const size_t Nt = NTOK;
    if (ws_size < 354050048ull) return;

    char* base = (char*)d_ws;
    unsigned short* outtH  = (unsigned short*)base;                  //  50 MB (bf16 outt)
    unsigned short* fbf    = (unsigned short*)(base + 100663296);    //  50 MB
    unsigned short* a0p    = (unsigned short*)(base + 150994944);    //  40 MB
    unsigned short* qkvbuf = (unsigned short*)(base + 191102976);    //  75 MB
    unsigned short* attnout= (unsigned short*)(base + 266600448);    //  25 MB
    unsigned short* A1     = (unsigned short*)(base + 301989888);    //  50 MB
    char* wp = base + 352321536;
    float* gct            = (float*)wp;
    unsigned short* mapT  = (unsigned short*)(wp + 73728);
    unsigned short* projT = mapT + 65536;
    unsigned short* w1T   = projT + 65536;            // layout anchor (1 MB region)
    unsigned char* w2T8   = (unsigned char*)(w1T + 262144);
    unsigned char* w1T8   = w2T8 + 262144;
    unsigned short* tclT0 = w1T + 262144 + 262144;
    unsigned short* tclT1 = tclT0 + 61440;
    unsigned short* qkvT  = tclT1 + 61440;
    unsigned short* aprojT= qkvT + 24576;

    unsigned char* h8   = (unsigned char*)fbf;   // fp8 Nt x 1024 = 100 MB, spans fbf+a0p+part of qkvbuf (dead)
    unsigned char* xn8  = (unsigned char*)A1;    // fp8 Nt x 256 = 25 MB (A1 region dead by then)
    unsigned short* ybf = (unsigned short*)d_out;
    unsigned short* xskip = ybf + (size_t)256*Nt;
    float* dout = (float*)d_out;

    prep_weights<<<256, 256, 0, stream>>>(gconv, tcl_w0, tcl_w1, map_w, proj_w, mlp_w1, mlp_w2,
                                          qkv_w0, qkv_w1, aproj_w0, aproj_w1,
                                          gct, mapT, projT, w1T8, w2T8, tclT0, tclT1, qkvT, aprojT);
    xpose_ln1<<<NB*TT, 256, 0, stream>>>(input, n1g, n1b, A1, xskip);
    mfma_gemm<256,4><<<1024, 512, 0, stream>>>(A1, mapT, map_b, fbf, nullptr, 256, 2);
    hipMemsetAsync(a0p, 0, A0P_USH*sizeof(unsigned short), stream);
    gemm_k64<0><<<1024, 256, 0, stream>>>(fbf + 128, 512, qkvT,         qkv_b0, qkvbuf);
    gemm_k64<0><<<1024, 256, 0, stream>>>(fbf + 192, 512, qkvT + 12288, qkv_b1, qkvbuf + (size_t)Nt*192);
    attn_win<<<dim3(2048,2), 192, 0, stream>>>(qkvbuf, attnout);
    y0_kernel<<<NB*TT, 256, 0, stream>>>(fbf, gct, ybf);
    y1_kernel<<<NB*TT, 256, 0, stream>>>(fbf, tconv_w, tconv_b, ybf);
    gemm_k64<1><<<1024, 256, 0, stream>>>(attnout,                 128, aprojT,         aproj_b0, a0p);
    tcl_mfma<<<NTOK/192, 256, 0, stream>>>(a0p, tclT0, tcl_b0, ybf, 128);
    gemm_k64<1><<<1024, 256, 0, stream>>>(attnout + (size_t)Nt*64, 128, aprojT + 12288, aproj_b1, a0p);
    tcl_mfma<<<NTOK/192, 256, 0, stream>>>(a0p, tclT1, tcl_b1, ybf, 192);
    proj_ln2<<<512, 512, 0, stream>>>(ybf, projT, proj_b, xskip, n2g, n2b, outtH, xn8);
    mfma_mlp1_fp8<<<4096, 512, 0, stream>>>(xn8, w1T8, mlp_b1, h8);
    mfma_final_fp8<<<1024, 512, 0, stream>>>(h8, w2T8, mlp_b2, outtH, dout);
}

// Round 25
// 508.956 us; speedup vs baseline: 1.0930x; 1.0115x over previous
//
#include <hip/hip_runtime.h>
#include <hip/hip_bf16.h>
#include <math.h>

#define NB 32
#define CC 256
#define TT 64
#define VV 48
#define NTOK (NB*TT*VV)   // 98304
#define LNE 1e-5f
#define PROWS 3264        // (4+64)*48
#define A0P_USH ((size_t)NB*PROWS*192)

typedef __attribute__((ext_vector_type(8))) __bf16 bf16x8;
typedef __attribute__((ext_vector_type(4))) float f32x4;
typedef __attribute__((ext_vector_type(2))) long long2v;

__device__ inline float bfbits2f(unsigned int bits){
    union{unsigned int u; float f;} c; c.u = bits<<16; return c.f;
}
__device__ inline unsigned short f2bf(float x){
    union{ __bf16 h; unsigned short u; } c; c.h = (__bf16)x; return c.u;
}
__device__ inline unsigned char f2fp8(float x){
    int p = __builtin_amdgcn_cvt_pk_fp8_f32(x, x, 0, false);
    return (unsigned char)(p & 0xff);
}
__device__ inline unsigned int pk4fp8(float a, float b, float c, float d){
    int w = 0;
    w = __builtin_amdgcn_cvt_pk_fp8_f32(a, b, w, false);
    w = __builtin_amdgcn_cvt_pk_fp8_f32(c, d, w, true);
    return (unsigned int)w;
}
__device__ __forceinline__ void unpk8(uint4 u, float* d){
    d[0]=bfbits2f(u.x&0xffffu); d[1]=bfbits2f(u.x>>16);
    d[2]=bfbits2f(u.y&0xffffu); d[3]=bfbits2f(u.y>>16);
    d[4]=bfbits2f(u.z&0xffffu); d[5]=bfbits2f(u.z>>16);
    d[6]=bfbits2f(u.w&0xffffu); d[7]=bfbits2f(u.w>>16);
}
// 4*gelu(x) via sigmoid form: 4x * rcp(1 + exp(-1.702x)).
__device__ __forceinline__ float gelu4_fast(float x){
    float e = __expf(-1.702f * x);
    return (4.f * x) * __builtin_amdgcn_rcpf(1.f + e);
}

__device__ __forceinline__ void gll16(const char* g, char* l){
    __builtin_amdgcn_global_load_lds(
        (const __attribute__((address_space(1))) unsigned int*)g,
        (__attribute__((address_space(3))) unsigned int*)l, 16, 0, 0);
}

// ---------------- weight prep ----------------
__global__ void prep_weights(const float* gconv, const float* tcl0, const float* tcl1,
                             const float* map_w, const float* proj_w,
                             const float* mlp_w1, const float* mlp_w2,
                             const float* qkv_w0, const float* qkv_w1,
                             const float* aproj_w0, const float* aproj_w1,
                             float* gct,
                             unsigned short* mapT, unsigned short* projT,
                             unsigned char* w1T8, unsigned char* w2T8,
                             unsigned short* tclT0, unsigned short* tclT1,
                             unsigned short* qkvT, unsigned short* aprojT){
    int tid = blockIdx.x*blockDim.x + threadIdx.x;
    int stride = gridDim.x*blockDim.x;
    for (int i = tid; i < 8*48*48; i += stride){
        int g = i/(48*48); int r = i%(48*48); int u = r/48; int v = r%48;
        gct[i] = gconv[(g*48+v)*48+u];
    }
    for (int i = tid; i < 64*960; i += stride){
        int o = i/960, col = i%960, kh = col/192, c = col%192;
        tclT0[i] = f2bf(tcl0[(o*192+c)*5+kh]);
        tclT1[i] = f2bf(tcl1[(o*192+c)*5+kh]);
    }
    for (int i = tid; i < 65536; i += stride){
        int n = i>>8, k = i&255;
        mapT[i] = f2bf(map_w[k*256+n]);
        projT[i] = f2bf(proj_w[k*256+n]);
    }
    // w1T8[n][k] = fp8(mlp_w1[k][n] * 64)
    for (int i = tid; i < 262144; i += stride){
        int n = i>>8, k = i&255;
        w1T8[i] = f2fp8(mlp_w1[k*1024+n] * 64.f);
    }
    // w2T8[n][k] = fp8(mlp_w2[k][n] * 32)
    for (int i = tid; i < 262144; i += stride){
        int n = i>>10, k = i&1023;
        w2T8[i] = f2fp8(mlp_w2[k*256+n] * 32.f);
    }
    for (int i = tid; i < 12288; i += stride){
        int n = i/64, k = i%64;
        qkvT[i]          = f2bf(qkv_w0[k*192+n]);
        qkvT[12288+i]    = f2bf(qkv_w1[k*192+n]);
        aprojT[i]        = f2bf(aproj_w0[k*192+n]);
        aprojT[12288+i]  = f2bf(aproj_w1[k*192+n]);
    }
}

// ---------------- LN1 + transpose -> A1 bf16 [N][256] + raw skip copy ----------------
__global__ __launch_bounds__(256) void xpose_ln1(const float* __restrict__ x,
        const float* __restrict__ g, const float* __restrict__ bb,
        unsigned short* __restrict__ A1, unsigned short* __restrict__ xskip){
    int bt = blockIdx.x; int b = bt/TT, t = bt%TT;
    __shared__ float X[48*257];
    __shared__ float S[4][48], SS[4][48], sm[48], sv[48];
    int tid = threadIdx.x;
    const float* xb = x + (size_t)b*256*3072 + (size_t)t*48;
    for (int it = 0; it < 12; it++){
        int idx = it*256 + tid;
        int c = idx/12, q = idx%12;
        float4 v = *(const float4*)(xb + (size_t)c*3072 + q*4);
        X[(q*4+0)*257 + c] = v.x;
        X[(q*4+1)*257 + c] = v.y;
        X[(q*4+2)*257 + c] = v.z;
        X[(q*4+3)*257 + c] = v.w;
    }
    __syncthreads();
    if (tid < 192){
        int v = tid % 48, w = tid / 48;
        float s = 0.f, ss = 0.f;
        for (int c = w*64; c < w*64+64; c++){
            float val = X[v*257 + c];
            s += val; ss += val*val;
        }
        S[w][v] = s; SS[w][v] = ss;
    }
    __syncthreads();
    if (tid < 48){
        float s = S[0][tid]+S[1][tid]+S[2][tid]+S[3][tid];
        float q = SS[0][tid]+SS[1][tid]+SS[2][tid]+SS[3][tid];
        float m = s*(1.f/256);
        sm[tid] = m; sv[tid] = rsqrtf(q*(1.f/256) - m*m + LNE);
    }
    __syncthreads();
    int nb = bt*48;
    for (int it = 0; it < 12; it++){
        int idx = it*256 + tid;
        int v = idx>>6, cq = idx&63;
        float m = sm[v], rs = sv[v];
        float4 g4 = *(const float4*)(g + cq*4);
        float4 b4 = *(const float4*)(bb + cq*4);
        float x0 = X[v*257 + cq*4+0], x1 = X[v*257 + cq*4+1];
        float x2 = X[v*257 + cq*4+2], x3 = X[v*257 + cq*4+3];
        ushort4 u;
        u.x = f2bf((x0-m)*rs*g4.x + b4.x);
        u.y = f2bf((x1-m)*rs*g4.y + b4.y);
        u.z = f2bf((x2-m)*rs*g4.z + b4.z);
        u.w = f2bf((x3-m)*rs*g4.w + b4.w);
        *(ushort4*)(A1 + (size_t)(nb+v)*256 + cq*4) = u;
        ushort4 s;
        s.x = f2bf(x0); s.y = f2bf(x1); s.z = f2bf(x2); s.w = f2bf(x3);
        *(ushort4*)(xskip + (size_t)(nb+v)*256 + cq*4) = s;
    }
}

// ---------------- swizzled staging (single-shot, for k64 GEMM) ----------------
__device__ __forceinline__ void stage_swz(const char* src, size_t rowbytes, char* lds,
                                          int nchunks, int tid){
    for (int c = tid; c < nchunks; c += 256){
        int p = c << 4;
        int r = p >> 7;
        int kl = (p & 127) ^ ((r & 7) << 4);
        gll16(src + (size_t)r*rowbytes + kl, lds + p);
    }
}

__device__ __forceinline__ bf16x8 frag_ld(const char* lds, int R, int kb){
    return *(const bf16x8*)(lds + R*128 + (kb ^ ((R & 7) << 4)));
}
// 16-byte fp8 fragment read (conflict-free b128 pattern); the two 8-byte
// halves feed two MFMAs. K-permutation is identical for A and B -> exact.
__device__ __forceinline__ long2v frag_ld16(const char* lds, int R, int kb){
    return *(const long2v*)(lds + R*128 + (kb ^ ((R & 7) << 4)));
}

// ---------------- MFMA GEMM: BM=192, BN=128, 8 waves, dbuf + counted vmcnt ----------------
// EPI 4: outH = bf16(acc + bias)   [LDS repack, 16B stores]
template<int KTOT, int EPI>
__global__ __launch_bounds__(512, 4) void mfma_gemm(
    const unsigned short* __restrict__ A, const unsigned short* __restrict__ BT,
    const float* __restrict__ bias,
    unsigned short* __restrict__ outH, unsigned char* __restrict__ outH8,
    int ncols, int nx){

    constexpr int BM = 192, BN = 128;
    constexpr int HALF = (BM+BN)*128;           // 40960
    __shared__ __align__(16) char smem[2*HALF]; // 81920 -> 2 blocks/CU
    int tid = threadIdx.x, lane = tid & 63;
    int wid = tid >> 6;
    int wm = wid >> 1, wn = wid & 1;
    int l15 = lane & 15, lq = lane >> 4;
    int bid = blockIdx.x;
    int per = gridDim.x >> 3;
    int wkid = (bid & 7)*per + (bid >> 3);
    int m0 = (wkid / nx) * BM, n0 = (wkid % nx) * BN;
    const size_t arb = KTOT*2, brb = KTOT*2;
    constexpr int KT = KTOT/64;

    const char* gA[3]; int loA[3];
    const char* gB[2]; int loB[2];
    {
        const char* Ab = (const char*)A + (size_t)m0*arb;
        const char* Bb = (const char*)BT + (size_t)n0*brb;
        #pragma unroll
        for (int i = 0; i < 3; i++){
            int c = tid + i*512;
            int p = c << 4, r = p >> 7;
            int kl = (p & 127) ^ ((r & 7) << 4);
            gA[i] = Ab + (size_t)r*arb + kl; loA[i] = p;
        }
        #pragma unroll
        for (int i = 0; i < 2; i++){
            int c = tid + i*512;
            int p = c << 4, r = p >> 7;
            int kl = (p & 127) ^ ((r & 7) << 4);
            gB[i] = Bb + (size_t)r*brb + kl; loB[i] = BM*128 + p;
        }
    }

    f32x4 acc[3][4];
    #pragma unroll
    for (int i = 0; i < 3; i++)
        #pragma unroll
        for (int j = 0; j < 4; j++){ f32x4 z = {0.f,0.f,0.f,0.f}; acc[i][j] = z; }

    #pragma unroll
    for (int i = 0; i < 3; i++) gll16(gA[i], smem + loA[i]);
    #pragma unroll
    for (int i = 0; i < 2; i++) gll16(gB[i], smem + loB[i]);

    int koff = 128;
    for (int kt = 0; kt < KT; kt++){
        char* cur = smem + (kt & 1)*HALF;
        if (kt + 1 < KT){
            char* nxt = smem + ((kt + 1) & 1)*HALF;
            #pragma unroll
            for (int i = 0; i < 3; i++) gll16(gA[i] + koff, nxt + loA[i]);
            #pragma unroll
            for (int i = 0; i < 2; i++) gll16(gB[i] + koff, nxt + loB[i]);
            koff += 128;
            asm volatile("s_waitcnt vmcnt(5)" ::: "memory");
        } else {
            asm volatile("s_waitcnt vmcnt(0)" ::: "memory");
        }
        __builtin_amdgcn_s_barrier();
        __builtin_amdgcn_sched_barrier(0);
        char* ldsA = cur;
        char* ldsB = cur + BM*128;
        #pragma unroll
        for (int ks = 0; ks < 2; ks++){
            bf16x8 a[3], b[4];
            int kb = ks*64 + lq*16;
            #pragma unroll
            for (int mf = 0; mf < 3; mf++) a[mf] = frag_ld(ldsA, wm*48 + mf*16 + l15, kb);
            #pragma unroll
            for (int nf = 0; nf < 4; nf++) b[nf] = frag_ld(ldsB, wn*64 + nf*16 + l15, kb);
            #pragma unroll
            for (int mf = 0; mf < 3; mf++)
                #pragma unroll
                for (int nf = 0; nf < 4; nf++)
                    acc[mf][nf] = __builtin_amdgcn_mfma_f32_16x16x32_bf16(a[mf], b[nf], acc[mf][nf], 0, 0, 0);
        }
        __builtin_amdgcn_sched_barrier(0);
        __builtin_amdgcn_s_barrier();
    }

    if constexpr (EPI == 4){
        unsigned short* Hs = (unsigned short*)smem;   // [192][136]
        #pragma unroll
        for (int nf = 0; nf < 4; nf++){
            int col = wn*64 + nf*16 + l15;
            float bb = bias[n0 + col];
            #pragma unroll
            for (int mf = 0; mf < 3; mf++){
                int row = wm*48 + mf*16 + lq*4;
                f32x4 v = acc[mf][nf];
                #pragma unroll
                for (int r = 0; r < 4; r++)
                    Hs[(row+r)*136 + col] = f2bf(v[r] + bb);
            }
        }
        __syncthreads();
        for (int idx = tid; idx < 192*16; idx += 512){
            int row = idx >> 4, c8 = idx & 15;
            *(uint4*)(outH + (size_t)(m0+row)*ncols + n0 + c8*8) =
                *(const uint4*)(Hs + row*136 + c8*8);
        }
    }
}

// ---------------- MLP1 GEMM in fp8: K=256 as 2 tiles of K=128 (128B rows) ----------------
// outH8 = fp8(gelu4((acc/64) + bias)); b128 fragment reads (K-permuted, exact)
__global__ __launch_bounds__(512, 4) void mfma_mlp1_fp8(
    const unsigned char* __restrict__ A, const unsigned char* __restrict__ BT,
    const float* __restrict__ bias, unsigned char* __restrict__ outH8){

    constexpr int BM = 192, BN = 128, NX = 8;
    constexpr int HALF = (BM+BN)*128;           // 40960
    __shared__ __align__(16) char smem[2*HALF]; // 81920 -> 2 blocks/CU
    int tid = threadIdx.x, lane = tid & 63;
    int wid = tid >> 6;
    int wm = wid >> 1, wn = wid & 1;
    int l15 = lane & 15, lq = lane >> 4;
    int bid = blockIdx.x;
    int per = gridDim.x >> 3;
    int wkid = (bid & 7)*per + (bid >> 3);
    int m0 = (wkid / NX) * BM, n0 = (wkid % NX) * BN;
    const size_t arb = 256, brb = 256;
    constexpr int KT = 2;

    const char* gA[3]; int loA[3];
    const char* gB[2]; int loB[2];
    {
        const char* Ab = (const char*)A + (size_t)m0*arb;
        const char* Bb = (const char*)BT + (size_t)n0*brb;
        #pragma unroll
        for (int i = 0; i < 3; i++){
            int c = tid + i*512;
            int p = c << 4, r = p >> 7;
            int kl = (p & 127) ^ ((r & 7) << 4);
            gA[i] = Ab + (size_t)r*arb + kl; loA[i] = p;
        }
        #pragma unroll
        for (int i = 0; i < 2; i++){
            int c = tid + i*512;
            int p = c << 4, r = p >> 7;
            int kl = (p & 127) ^ ((r & 7) << 4);
            gB[i] = Bb + (size_t)r*brb + kl; loB[i] = BM*128 + p;
        }
    }

    f32x4 acc[3][4];
    #pragma unroll
    for (int i = 0; i < 3; i++)
        #pragma unroll
        for (int j = 0; j < 4; j++){ f32x4 z = {0.f,0.f,0.f,0.f}; acc[i][j] = z; }

    #pragma unroll
    for (int i = 0; i < 3; i++) gll16(gA[i], smem + loA[i]);
    #pragma unroll
    for (int i = 0; i < 2; i++) gll16(gB[i], smem + loB[i]);

    int koff = 128;
    for (int kt = 0; kt < KT; kt++){
        char* cur = smem + (kt & 1)*HALF;
        if (kt + 1 < KT){
            char* nxt = smem + ((kt + 1) & 1)*HALF;
            #pragma unroll
            for (int i = 0; i < 3; i++) gll16(gA[i] + koff, nxt + loA[i]);
            #pragma unroll
            for (int i = 0; i < 2; i++) gll16(gB[i] + koff, nxt + loB[i]);
            koff += 128;
            asm volatile("s_waitcnt vmcnt(5)" ::: "memory");
        } else {
            asm volatile("s_waitcnt vmcnt(0)" ::: "memory");
        }
        __builtin_amdgcn_s_barrier();
        __builtin_amdgcn_sched_barrier(0);
        char* ldsA = cur;
        char* ldsB = cur + BM*128;
        #pragma unroll
        for (int hf = 0; hf < 2; hf++){
            long2v a[3], b[4];
            int kb = hf*64 + lq*16;
            #pragma unroll
            for (int mf = 0; mf < 3; mf++) a[mf] = frag_ld16(ldsA, wm*48 + mf*16 + l15, kb);
            #pragma unroll
            for (int nf = 0; nf < 4; nf++) b[nf] = frag_ld16(ldsB, wn*64 + nf*16 + l15, kb);
            #pragma unroll
            for (int mf = 0; mf < 3; mf++)
                #pragma unroll
                for (int nf = 0; nf < 4; nf++){
                    acc[mf][nf] = __builtin_amdgcn_mfma_f32_16x16x32_fp8_fp8(a[mf][0], b[nf][0], acc[mf][nf], 0, 0, 0);
                    acc[mf][nf] = __builtin_amdgcn_mfma_f32_16x16x32_fp8_fp8(a[mf][1], b[nf][1], acc[mf][nf], 0, 0, 0);
                }
        }
        __builtin_amdgcn_sched_barrier(0);
        __builtin_amdgcn_s_barrier();
    }

    unsigned char* Hc = (unsigned char*)smem;     // [192][144] fp8
    #pragma unroll
    for (int nf = 0; nf < 4; nf++){
        int col = wn*64 + nf*16 + l15;
        float bb = bias[n0 + col];
        #pragma unroll
        for (int mf = 0; mf < 3; mf++){
            int row = wm*48 + mf*16 + lq*4;
            f32x4 v = acc[mf][nf];
            #pragma unroll
            for (int r = 0; r < 4; r++){
                float t0 = gelu4_fast(v[r]*0.015625f + bb);
                Hc[(row+r)*144 + col] = f2fp8(t0);
            }
        }
    }
    __syncthreads();
    for (int idx = tid; idx < 192*8; idx += 512){
        int row = idx >> 3, c16 = idx & 7;
        *(uint4*)(outH8 + (size_t)(m0+row)*1024 + n0 + c16*16) =
            *(const uint4*)(Hc + row*144 + c16*16);
    }
}

// ---------------- final GEMM in fp8: K=1024 as 8 tiles of K=128 (128B rows) ----------------
// epilogue: dout NCHW = acc/128 + bias + resid; Tt stride 197 (bank-coprime),
// both wave-halves fill every pass (nf = 2p, 2p+1), ch remap in store.
__global__ __launch_bounds__(512, 4) void mfma_final_fp8(
    const unsigned char* __restrict__ A, const unsigned char* __restrict__ BT,
    const float* __restrict__ bias, const unsigned short* __restrict__ extraH,
    float* __restrict__ outF){

    constexpr int BM = 192, BN = 128, NX = 2;
    constexpr int HALF = (BM+BN)*128;           // 40960
    __shared__ __align__(16) char smem[2*HALF]; // 81920 -> 2 blocks/CU
    int tid = threadIdx.x, lane = tid & 63;
    int wid = tid >> 6;
    int wm = wid >> 1, wn = wid & 1;
    int l15 = lane & 15, lq = lane >> 4;
    int bid = blockIdx.x;
    int per = gridDim.x >> 3;
    int wkid = (bid & 7)*per + (bid >> 3);
    int m0 = (wkid / NX) * BM, n0 = (wkid % NX) * BN;
    const size_t arb = 1024, brb = 1024;
    constexpr int KT = 8;

    const char* gA[3]; int loA[3];
    const char* gB[2]; int loB[2];
    {
        const char* Ab = (const char*)A + (size_t)m0*arb;
        const char* Bb = (const char*)BT + (size_t)n0*brb;
        #pragma unroll
        for (int i = 0; i < 3; i++){
            int c = tid + i*512;
            int p = c << 4, r = p >> 7;
            int kl = (p & 127) ^ ((r & 7) << 4);
            gA[i] = Ab + (size_t)r*arb + kl; loA[i] = p;
        }
        #pragma unroll
        for (int i = 0; i < 2; i++){
            int c = tid + i*512;
            int p = c << 4, r = p >> 7;
            int kl = (p & 127) ^ ((r & 7) << 4);
            gB[i] = Bb + (size_t)r*brb + kl; loB[i] = BM*128 + p;
        }
    }

    f32x4 acc[3][4];
    #pragma unroll
    for (int i = 0; i < 3; i++)
        #pragma unroll
        for (int j = 0; j < 4; j++){ f32x4 z = {0.f,0.f,0.f,0.f}; acc[i][j] = z; }

    #pragma unroll
    for (int i = 0; i < 3; i++) gll16(gA[i], smem + loA[i]);
    #pragma unroll
    for (int i = 0; i < 2; i++) gll16(gB[i], smem + loB[i]);

    int koff = 128;
    for (int kt = 0; kt < KT; kt++){
        char* cur = smem + (kt & 1)*HALF;
        if (kt + 1 < KT){
            char* nxt = smem + ((kt + 1) & 1)*HALF;
            #pragma unroll
            for (int i = 0; i < 3; i++) gll16(gA[i] + koff, nxt + loA[i]);
            #pragma unroll
            for (int i = 0; i < 2; i++) gll16(gB[i] + koff, nxt + loB[i]);
            koff += 128;
            asm volatile("s_waitcnt vmcnt(5)" ::: "memory");
        } else {
            asm volatile("s_waitcnt vmcnt(0)" ::: "memory");
        }
        __builtin_amdgcn_s_barrier();
        __builtin_amdgcn_sched_barrier(0);
        char* ldsA = cur;
        char* ldsB = cur + BM*128;
        #pragma unroll
        for (int hf = 0; hf < 2; hf++){
            long2v a[3], b[4];
            int kb = hf*64 + lq*16;
            #pragma unroll
            for (int mf = 0; mf < 3; mf++) a[mf] = frag_ld16(ldsA, wm*48 + mf*16 + l15, kb);
            #pragma unroll
            for (int nf = 0; nf < 4; nf++) b[nf] = frag_ld16(ldsB, wn*64 + nf*16 + l15, kb);
            #pragma unroll
            for (int mf = 0; mf < 3; mf++)
                #pragma unroll
                for (int nf = 0; nf < 4; nf++){
                    acc[mf][nf] = __builtin_amdgcn_mfma_f32_16x16x32_fp8_fp8(a[mf][0], b[nf][0], acc[mf][nf], 0, 0, 0);
                    acc[mf][nf] = __builtin_amdgcn_mfma_f32_16x16x32_fp8_fp8(a[mf][1], b[nf][1], acc[mf][nf], 0, 0, 0);
                }
        }
        __builtin_amdgcn_sched_barrier(0);
        __builtin_amdgcn_s_barrier();
    }

    // epilogue: two passes; pass p covers cols {32p..32p+31} U {64+32p..64+32p+31}.
    float* Tt = (float*)smem;  // [64 virtual-rows][197]
    #pragma unroll
    for (int p = 0; p < 2; p++){
        __syncthreads();
        #pragma unroll
        for (int q = 0; q < 2; q++){
            int nf = 2*p + q;
            int col = wn*64 + nf*16 + l15;          // actual output col (0..127)
            int vc  = wn*32 + q*16 + l15;           // virtual row in Tt (0..63)
            float bb = bias[n0 + col];
            #pragma unroll
            for (int mf = 0; mf < 3; mf++){
                int tl = wm*48 + mf*16 + lq*4;
                f32x4 v = acc[mf][nf];
                #pragma unroll
                for (int r = 0; r < 4; r++){
                    float resid = bfbits2f(extraH[(size_t)(m0+tl+r)*256 + n0 + col]);
                    Tt[vc*197 + tl + r] = v[r]*0.0078125f + bb + resid;
                }
            }
        }
        __syncthreads();
        {
            int lc = tid & 63, btl = (tid>>6)&3, dup = tid>>8;
            int ch = 32*p + lc + (lc & 32);         // actual col for virtual row lc
            int gtok = m0 + btl*48;
            int bg = gtok/3072, t = (gtok%3072)/48;
            float* dst = outF + ((size_t)(bg*256 + n0 + ch)*64 + t)*48 + dup*24;
            const float* tr = Tt + lc*197 + btl*48 + dup*24;
            #pragma unroll
            for (int j = 0; j < 6; j++)
                *(float4*)(dst + j*4) = *(const float4*)(tr + j*4);
        }
    }
}

// ---------------- proj GEMM fused with skip-add + LN2: BM=192, BN=256, K=256 ----------------
// xn output fp8 (input to fp8 MLP1)
__global__ __launch_bounds__(512, 2) void proj_ln2(
    const unsigned short* __restrict__ A, const unsigned short* __restrict__ BT,
    const float* __restrict__ bias, const unsigned short* __restrict__ xskip,
    const float* __restrict__ n2g, const float* __restrict__ n2b,
    unsigned short* __restrict__ outtH, unsigned char* __restrict__ xn8){

    constexpr int BM = 192, BN = 256, KTOT = 256;
    constexpr int HALF = (BM+BN)*128;
    __shared__ __align__(16) char smem[2*HALF];
    int tid = threadIdx.x, lane = tid & 63;
    int wid = tid >> 6;
    int wm = wid >> 1, wn = wid & 1;
    int l15 = lane & 15, lq = lane >> 4;
    int bid = blockIdx.x;
    int per = gridDim.x >> 3;
    int wkid = (bid & 7)*per + (bid >> 3);
    int m0 = wkid * BM;
    const size_t arb = KTOT*2, brb = KTOT*2;
    constexpr int KT = KTOT/64;

    const char* gA[3]; int loA[3];
    const char* gB[4]; int loB[4];
    {
        const char* Ab = (const char*)A + (size_t)m0*arb;
        const char* Bb = (const char*)BT;
        #pragma unroll
        for (int i = 0; i < 3; i++){
            int c = tid + i*512;
            int p = c << 4, r = p >> 7;
            int kl = (p & 127) ^ ((r & 7) << 4);
            gA[i] = Ab + (size_t)r*arb + kl; loA[i] = p;
        }
        #pragma unroll
        for (int i = 0; i < 4; i++){
            int c = tid + i*512;
            int p = c << 4, r = p >> 7;
            int kl = (p & 127) ^ ((r & 7) << 4);
            gB[i] = Bb + (size_t)r*brb + kl; loB[i] = BM*128 + p;
        }
    }

    f32x4 acc[3][8];
    #pragma unroll
    for (int i = 0; i < 3; i++)
        #pragma unroll
        for (int j = 0; j < 8; j++){ f32x4 z = {0.f,0.f,0.f,0.f}; acc[i][j] = z; }

    #pragma unroll
    for (int i = 0; i < 3; i++) gll16(gA[i], smem + loA[i]);
    #pragma unroll
    for (int i = 0; i < 4; i++) gll16(gB[i], smem + loB[i]);

    int koff = 128;
    for (int kt = 0; kt < KT; kt++){
        char* cur = smem + (kt & 1)*HALF;
        if (kt + 1 < KT){
            char* nxt = smem + ((kt + 1) & 1)*HALF;
            #pragma unroll
            for (int i = 0; i < 3; i++) gll16(gA[i] + koff, nxt + loA[i]);
            #pragma unroll
            for (int i = 0; i < 4; i++) gll16(gB[i] + koff, nxt + loB[i]);
            koff += 128;
            asm volatile("s_waitcnt vmcnt(7)" ::: "memory");
        } else {
            asm volatile("s_waitcnt vmcnt(0)" ::: "memory");
        }
        __builtin_amdgcn_s_barrier();
        __builtin_amdgcn_sched_barrier(0);
        char* ldsA = cur;
        char* ldsB = cur + BM*128;
        #pragma unroll
        for (int ks = 0; ks < 2; ks++){
            bf16x8 a[3], b[8];
            int kb = ks*64 + lq*16;
            #pragma unroll
            for (int mf = 0; mf < 3; mf++) a[mf] = frag_ld(ldsA, wm*48 + mf*16 + l15, kb);
            #pragma unroll
            for (int nf = 0; nf < 8; nf++) b[nf] = frag_ld(ldsB, wn*128 + nf*16 + l15, kb);
            #pragma unroll
            for (int mf = 0; mf < 3; mf++)
                #pragma unroll
                for (int nf = 0; nf < 8; nf++)
                    acc[mf][nf] = __builtin_amdgcn_mfma_f32_16x16x32_bf16(a[mf], b[nf], acc[mf][nf], 0, 0, 0);
        }
        __builtin_amdgcn_sched_barrier(0);
        __builtin_amdgcn_s_barrier();
    }

    unsigned short* Hs = (unsigned short*)smem;
    float* Sred = (float*)(smem + 101376);
    float s_acc[3][4], ss_acc[3][4];
    #pragma unroll
    for (int i = 0; i < 3; i++)
        #pragma unroll
        for (int r = 0; r < 4; r++){ s_acc[i][r] = 0.f; ss_acc[i][r] = 0.f; }

    #pragma unroll
    for (int nf = 0; nf < 8; nf++){
        int col = wn*128 + nf*16 + l15;
        float bb = bias[col];
        #pragma unroll
        for (int mf = 0; mf < 3; mf++){
            int row = wm*48 + mf*16 + lq*4;
            f32x4 v = acc[mf][nf];
            #pragma unroll
            for (int r = 0; r < 4; r++){
                float sk = bfbits2f(xskip[(size_t)(m0+row+r)*256 + col]);
                unsigned short us = f2bf(v[r] + bb + sk);
                Hs[(row+r)*264 + col] = us;
                float tf = bfbits2f(us);
                s_acc[mf][r] += tf; ss_acc[mf][r] += tf*tf;
            }
        }
    }
    #pragma unroll
    for (int mf = 0; mf < 3; mf++)
        #pragma unroll
        for (int r = 0; r < 4; r++){
            float s = s_acc[mf][r], ss = ss_acc[mf][r];
            #pragma unroll
            for (int d = 1; d < 16; d <<= 1){
                s  += __shfl_xor(s, d);
                ss += __shfl_xor(ss, d);
            }
            if (l15 == 0){
                int row = wm*48 + mf*16 + lq*4 + r;
                Sred[wn*192 + row] = s;
                Sred[384 + wn*192 + row] = ss;
            }
        }
    __syncthreads();
    if (tid < 192){
        float s  = Sred[tid] + Sred[192+tid];
        float ss = Sred[384+tid] + Sred[576+tid];
        float m = s*(1.f/256);
        Sred[tid] = m;
        Sred[192+tid] = rsqrtf(ss*(1.f/256) - m*m + LNE);
    }
    __syncthreads();
    for (int idx = tid; idx < 192*32; idx += 512){
        int row = idx >> 5, c8 = idx & 31;
        uint4 hv = *(const uint4*)(Hs + row*264 + c8*8);
        *(uint4*)(outtH + (size_t)(m0+row)*256 + c8*8) = hv;
        float v[8]; unpk8(hv, v);
        float m = Sred[row], rs = Sred[192+row];
        float xv[8];
        #pragma unroll
        for (int j = 0; j < 8; j++)
            xv[j] = (v[j]-m)*rs*n2g[c8*8 + j] + n2b[c8*8 + j];
        uint2 o;
        o.x = pk4fp8(xv[0], xv[1], xv[2], xv[3]);
        o.y = pk4fp8(xv[4], xv[5], xv[6], xv[7]);
        *(uint2*)(xn8 + (size_t)(m0+row)*256 + c8*8) = o;
    }
}

// ---------------- K=64 MFMA GEMM: BM=96, BN=192, 4 waves ----------------
template<int EPI>
__global__ __launch_bounds__(256) void gemm_k64(
    const unsigned short* __restrict__ A, int arb,
    const unsigned short* __restrict__ BT,
    const float* __restrict__ bias,
    unsigned short* __restrict__ out){
    __shared__ __align__(16) char smem[96*128 + 192*128];
    char* ldsA = smem;
    char* ldsB = smem + 96*128;
    int tid = threadIdx.x, lane = tid & 63;
    int wid = tid >> 6, wm = wid >> 1, wn = wid & 1;
    int l15 = lane & 15, lq = lane >> 4;
    int m0 = blockIdx.x * 96;

    stage_swz((const char*)A + (size_t)m0*arb, arb, ldsA, 96*8, tid);
    stage_swz((const char*)BT, 128, ldsB, 192*8, tid);
    __syncthreads();

    f32x4 acc[3][6];
    #pragma unroll
    for (int i = 0; i < 3; i++)
        #pragma unroll
        for (int j = 0; j < 6; j++){ f32x4 z = {0.f,0.f,0.f,0.f}; acc[i][j] = z; }

    #pragma unroll
    for (int ks = 0; ks < 2; ks++){
        bf16x8 a[3], b[6];
        int kb = ks*64 + lq*16;
        #pragma unroll
        for (int mf = 0; mf < 3; mf++) a[mf] = frag_ld(ldsA, wm*48 + mf*16 + l15, kb);
        #pragma unroll
        for (int nf = 0; nf < 6; nf++) b[nf] = frag_ld(ldsB, wn*96 + nf*16 + l15, kb);
        #pragma unroll
        for (int mf = 0; mf < 3; mf++)
            #pragma unroll
            for (int nf = 0; nf < 6; nf++)
                acc[mf][nf] = __builtin_amdgcn_mfma_f32_16x16x32_bf16(a[mf], b[nf], acc[mf][nf], 0, 0, 0);
    }

    size_t row0;
    if constexpr (EPI == 0) row0 = (size_t)m0;
    else {
        int b = m0/3072;
        row0 = (size_t)b*PROWS + 192 + (m0 - b*3072);
    }
    #pragma unroll
    for (int nf = 0; nf < 6; nf++){
        int col = wn*96 + nf*16 + l15;
        float bb = bias[col];
        #pragma unroll
        for (int mf = 0; mf < 3; mf++){
            size_t rr = row0 + wm*48 + mf*16 + lq*4;
            f32x4 v = acc[mf][nf];
            #pragma unroll
            for (int r = 0; r < 4; r++)
                out[(rr+r)*192 + col] = f2bf(v[r] + bb);
        }
    }
}

// ---------------- windowed attention ----------------
__global__ __launch_bounds__(192) void attn_win(
        const unsigned short* __restrict__ qkvbuf,
        unsigned short* __restrict__ attnout){
    int win = blockIdx.x, br = blockIdx.y;
    size_t base = (size_t)br*NTOK + (size_t)win*48;
    __shared__ float Q[48*196];
    int tid = threadIdx.x;
    const unsigned short* src = qkvbuf + base*192;
    for (int i = 0; i < 6; i++){
        int ch = i*192 + tid;
        int v = ch/24, c8 = ch%24;
        uint4 u = *(const uint4*)(src + (size_t)v*192 + c8*8);
        unpk8(u, &Q[v*196 + c8*8]);
    }
    __syncthreads();
    int u = tid & 15, gh = tid >> 4, g = gh >> 2, h = gh & 3;
    int ru = g*16 + u;
    float qreg[16];
    #pragma unroll
    for (int d = 0; d < 16; d++) qreg[d] = Q[ru*196 + h*16 + d];
    float sc[16]; float mx = -1e30f;
    #pragma unroll
    for (int w = 0; w < 16; w++){
        float s = 0.f;
        #pragma unroll
        for (int d = 0; d < 16; d++) s += qreg[d]*Q[(g*16+w)*196 + 64 + h*16 + d];
        s *= 0.5f; sc[w] = s; mx = fmaxf(mx, s);
    }
    float sum = 0.f;
    #pragma unroll
    for (int w = 0; w < 16; w++){ sc[w] = __expf(sc[w]-mx); sum += sc[w]; }
    float inv = __builtin_amdgcn_rcpf(sum);
    unsigned int w32[8];
    #pragma unroll
    for (int dp = 0; dp < 8; dp++){
        float o0 = 0.f, o1 = 0.f;
        #pragma unroll
        for (int w = 0; w < 16; w++){
            float p = sc[w];
            o0 += p*Q[(g*16+w)*196 + 128 + h*16 + dp*2];
            o1 += p*Q[(g*16+w)*196 + 128 + h*16 + dp*2+1];
        }
        w32[dp] = (unsigned int)f2bf(o0*inv) | ((unsigned int)f2bf(o1*inv) << 16);
    }
    unsigned short* dst = attnout + (base + ru)*64 + h*16;
    uint4 q0; q0.x=w32[0]; q0.y=w32[1]; q0.z=w32[2]; q0.w=w32[3];
    uint4 q1; q1.x=w32[4]; q1.y=w32[5]; q1.z=w32[6]; q1.w=w32[7];
    *(uint4*)(dst)   = q0;
    *(uint4*)(dst+8) = q1;
}

// ---------------- tcl as MFMA GEMM: K=960 (15 tiles), dbuf + counted vmcnt ----------------
__global__ __launch_bounds__(256) void tcl_mfma(const unsigned short* __restrict__ A0p,
        const unsigned short* __restrict__ BT, const float* __restrict__ tb,
        unsigned short* __restrict__ ybf, int outoff){
    constexpr int HALF = (192+64)*128;
    __shared__ __align__(16) char smem[2*HALF];
    int tid = threadIdx.x, lane = tid & 63;
    int wid = tid >> 6;
    int l15 = lane & 15, lq = lane >> 4;
    int bid = blockIdx.x;
    int per = gridDim.x >> 3;
    int wkid = (bid & 7)*per + (bid >> 3);
    int m0 = wkid * 192;
    int b = m0 / 3072;
    long brow0 = (long)b*PROWS + 192 + (m0 - b*3072);

    const char* gA[6]; int loA[6];
    const char* gB[2]; int loB[2];
    {
        const char* Ab = (const char*)A0p + (brow0 - 192)*384;
        #pragma unroll
        for (int i = 0; i < 6; i++){
            int c = tid + i*256;
            int p = c << 4, r = p >> 7;
            int kl = (p & 127) ^ ((r & 7) << 4);
            gA[i] = Ab + (size_t)r*384 + kl; loA[i] = p;
        }
        #pragma unroll
        for (int i = 0; i < 2; i++){
            int c = tid + i*256;
            int p = c << 4, r = p >> 7;
            int kl = (p & 127) ^ ((r & 7) << 4);
            gB[i] = (const char*)BT + (size_t)r*1920 + kl; loB[i] = 192*128 + p;
        }
    }

    f32x4 acc[3][4];
    #pragma unroll
    for (int i = 0; i < 3; i++)
        #pragma unroll
        for (int j = 0; j < 4; j++){ f32x4 z = {0.f,0.f,0.f,0.f}; acc[i][j] = z; }

    #pragma unroll
    for (int i = 0; i < 6; i++) gll16(gA[i], smem + loA[i]);
    #pragma unroll
    for (int i = 0; i < 2; i++) gll16(gB[i], smem + loB[i]);

    long offA = 0; int kc3 = 0; int offB = 0;
    for (int kt = 0; kt < 15; kt++){
        char* cur = smem + (kt & 1)*HALF;
        if (kt + 1 < 15){
            char* nxt = smem + ((kt + 1) & 1)*HALF;
            if (kc3 == 2){ offA += 18432 - 256; kc3 = 0; }
            else         { offA += 128; kc3++; }
            offB += 128;
            #pragma unroll
            for (int i = 0; i < 6; i++) gll16(gA[i] + offA, nxt + loA[i]);
            #pragma unroll
            for (int i = 0; i < 2; i++) gll16(gB[i] + offB, nxt + loB[i]);
            asm volatile("s_waitcnt vmcnt(8)" ::: "memory");
        } else {
            asm volatile("s_waitcnt vmcnt(0)" ::: "memory");
        }
        __builtin_amdgcn_s_barrier();
        __builtin_amdgcn_sched_barrier(0);
        char* ldsA = cur;
        char* ldsB = cur + 192*128;
        #pragma unroll
        for (int ks = 0; ks < 2; ks++){
            bf16x8 a[3], bb[4];
            int kb = ks*64 + lq*16;
            #pragma unroll
            for (int mf = 0; mf < 3; mf++) a[mf] = frag_ld(ldsA, wid*48 + mf*16 + l15, kb);
            #pragma unroll
            for (int nf = 0; nf < 4; nf++) bb[nf] = frag_ld(ldsB, nf*16 + l15, kb);
            #pragma unroll
            for (int mf = 0; mf < 3; mf++)
                #pragma unroll
                for (int nf = 0; nf < 4; nf++)
                    acc[mf][nf] = __builtin_amdgcn_mfma_f32_16x16x32_bf16(a[mf], bb[nf], acc[mf][nf], 0, 0, 0);
        }
        __builtin_amdgcn_sched_barrier(0);
        __builtin_amdgcn_s_barrier();
    }
    #pragma unroll
    for (int nf = 0; nf < 4; nf++){
        int col = nf*16 + l15;
        float bb = tb[col];
        #pragma unroll
        for (int mf = 0; mf < 3; mf++){
            int tok = m0 + wid*48 + mf*16 + lq*4;
            f32x4 v = acc[mf][nf];
            #pragma unroll
            for (int r = 0; r < 4; r++)
                ybf[(size_t)(tok+r)*256 + outoff + col] = f2bf(v[r] + bb);
        }
    }
}

// ---------------- y0: grouped V-mix -> ybf cols 0..63 ----------------
__global__ __launch_bounds__(256) void y0_kernel(const unsigned short* __restrict__ fbf,
        const float* __restrict__ gct, unsigned short* __restrict__ ybf){
    int bt = blockIdx.x; int nb = bt*VV;
    __shared__ float X[48*68];
    for (int it = 0; it < 2; it++){
        int idx = it*256 + threadIdx.x;
        if (idx < 384){
            int v = idx >> 3, c8 = idx & 7;
            uint4 u = *(const uint4*)(fbf + (size_t)(nb+v)*256 + c8*8);
            unpk8(u, &X[v*68 + c8*8]);
        }
    }
    __syncthreads();
    int c = threadIdx.x % 64, vv = threadIdx.x / 64;
    int g = c >> 3;
    float acc[12] = {};
    for (int u = 0; u < 48; u++){
        float xv = X[u*68 + c];
        const float* gr = gct + (size_t)(g*48+u)*48 + vv*12;
        float4 g0 = *(const float4*)(gr);
        float4 g1 = *(const float4*)(gr+4);
        float4 g2 = *(const float4*)(gr+8);
        acc[0]+=xv*g0.x; acc[1]+=xv*g0.y; acc[2]+=xv*g0.z;  acc[3]+=xv*g0.w;
        acc[4]+=xv*g1.x; acc[5]+=xv*g1.y; acc[6]+=xv*g1.z;  acc[7]+=xv*g1.w;
        acc[8]+=xv*g2.x; acc[9]+=xv*g2.y; acc[10]+=xv*g2.z; acc[11]+=xv*g2.w;
    }
    #pragma unroll
    for (int j = 0; j < 12; j++)
        ybf[(size_t)(nb + vv*12 + j)*256 + c] = f2bf(acc[j]);
}

// ---------------- y1: grouped temporal conv (k=7), LDS-staged taps -> ybf cols 64..127 ----------------
__global__ __launch_bounds__(256) void y1_kernel(const unsigned short* __restrict__ fbf,
        const float* __restrict__ tw, const float* __restrict__ tb, unsigned short* __restrict__ ybf){
    int bt = blockIdx.x; int b = bt/TT, t = bt%TT;
    __shared__ unsigned short W[7*48*64];   // 43 KB: [kh][v][ch 64..127]
    int tid = threadIdx.x;
    // coalesced staging: chunk idx -> LDS ushort index 8*idx (linear), zero-pad invalid taps
    for (int idx = tid; idx < 2688; idx += 256){
        int kh = idx/384, rem = idx - kh*384;
        int v = rem >> 3, c8 = rem & 7;
        int tt = t + kh - 3;
        uint4 u; u.x = 0; u.y = 0; u.z = 0; u.w = 0;
        if (tt >= 0 && tt < TT)
            u = *(const uint4*)(fbf + ((size_t)(b*TT+tt)*VV + v)*256 + 64 + c8*8);
        *(uint4*)(&W[idx*8]) = u;
    }
    __syncthreads();
    int o = tid & 63, vv = tid >> 6;
    int g = o >> 3;
    float bv = tb[o];
    float acc[12];
    #pragma unroll
    for (int j = 0; j < 12; j++) acc[j] = bv;
    for (int kh = 0; kh < 7; kh++){
        float wk[8];
        #pragma unroll
        for (int ci = 0; ci < 8; ci++) wk[ci] = tw[(o*8+ci)*7 + kh];
        const unsigned short* base = &W[kh*3072 + g*8];
        #pragma unroll
        for (int j = 0; j < 12; j++){
            uint4 u = *(const uint4*)(base + (vv*12 + j)*64);
            float fv[8]; unpk8(u, fv);
            acc[j] += fv[0]*wk[0]+fv[1]*wk[1]+fv[2]*wk[2]+fv[3]*wk[3]
                    + fv[4]*wk[4]+fv[5]*wk[5]+fv[6]*wk[6]+fv[7]*wk[7];
        }
    }
    int nb = bt*VV;
    #pragma unroll
    for (int j = 0; j < 12; j++)
        ybf[(size_t)(nb + vv*12 + j)*256 + 64 + o] = f2bf(acc[j]);
}

extern "C" void kernel_launch(void* const* d_in, const int* in_sizes, int n_in,
                              void* d_out, int out_size, void* d_ws, size_t ws_size,
                              hipStream_t stream){
    const float* input   = (const float*)d_in[0];
    const float* n1g     = (const float*)d_in[1];
    const float* n1b     = (const float*)d_in[2];
    const float* map_w   = (const float*)d_in[3];
    const float* map_b   = (const float*)d_in[4];
    const float* gconv   = (const float*)d_in[5];
    const float* tconv_w = (const float*)d_in[6];
    const float* tconv_b = (const float*)d_in[7];
    const float* qkv_w0  = (const float*)d_in[8];
    const float* qkv_b0  = (const float*)d_in[9];
    const float* aproj_w0= (const float*)d_in[10];
    const float* aproj_b0= (const float*)d_in[11];
    const float* tcl_w0  = (const float*)d_in[12];
    const float* tcl_b0  = (const float*)d_in[13];
    const float* qkv_w1  = (const float*)d_in[14];
    const float* qkv_b1  = (const float*)d_in[15];
    const float* aproj_w1= (const float*)d_in[16];
    const float* aproj_b1= (const float*)d_in[17];
    const float* tcl_w1  = (const float*)d_in[18];
    const float* tcl_b1  = (const float*)d_in[19];
    const float* proj_w  = (const float*)d_in[20];
    const float* proj_b  = (const float*)d_in[21];
    const float* n2g     = (const float*)d_in[22];
    const float* n2b     = (const float*)d_in[23];
    const float* mlp_w1  = (const float*)d_in[24];
    const float* mlp_b1  = (const float*)d_in[25];
    const float* mlp_w2  = (const float*)d_in[26];
    const float* mlp_b2  = (const float*)d_in[27];

    const size_t Nt = NTOK;
    if (ws_size < 354050048ull) return;

    char* base = (char*)d_ws;
    unsigned short* outtH  = (unsigned short*)base;                  //  50 MB (bf16 outt)
    unsigned short* fbf    = (unsigned short*)(base + 100663296);    //  50 MB
    unsigned short* a0p    = (unsigned short*)(base + 150994944);    //  40 MB
    unsigned short* qkvbuf = (unsigned short*)(base + 191102976);    //  75 MB
    unsigned short* attnout= (unsigned short*)(base + 266600448);    //  25 MB
    unsigned short* A1     = (unsigned short*)(base + 301989888);    //  50 MB
    char* wp = base + 352321536;
    float* gct            = (float*)wp;
    unsigned short* mapT  = (unsigned short*)(wp + 73728);
    unsigned short* projT = mapT + 65536;
    unsigned short* w1T   = projT + 65536;            // layout anchor (1 MB region)
    unsigned char* w2T8   = (unsigned char*)(w1T + 262144);
    unsigned char* w1T8   = w2T8 + 262144;
    unsigned short* tclT0 = w1T + 262144 + 262144;
    unsigned short* tclT1 = tclT0 + 61440;
    unsigned short* qkvT  = tclT1 + 61440;
    unsigned short* aprojT= qkvT + 24576;

    unsigned char* h8   = (unsigned char*)fbf;   // fp8 Nt x 1024 = 100 MB, spans fbf+a0p+part of qkvbuf (dead)
    unsigned char* xn8  = (unsigned char*)A1;    // fp8 Nt x 256 = 25 MB (A1 region dead by then)
    unsigned short* ybf = (unsigned short*)d_out;
    unsigned short* xskip = ybf + (size_t)256*Nt;
    float* dout = (float*)d_out;

    prep_weights<<<256, 256, 0, stream>>>(gconv, tcl_w0, tcl_w1, map_w, proj_w, mlp_w1, mlp_w2,
                                          qkv_w0, qkv_w1, aproj_w0, aproj_w1,
                                          gct, mapT, projT, w1T8, w2T8, tclT0, tclT1, qkvT, aprojT);
    xpose_ln1<<<NB*TT, 256, 0, stream>>>(input, n1g, n1b, A1, xskip);
    mfma_gemm<256,4><<<1024, 512, 0, stream>>>(A1, mapT, map_b, fbf, nullptr, 256, 2);
    hipMemsetAsync(a0p, 0, A0P_USH*sizeof(unsigned short), stream);
    gemm_k64<0><<<1024, 256, 0, stream>>>(fbf + 128, 512, qkvT,         qkv_b0, qkvbuf);
    gemm_k64<0><<<1024, 256, 0, stream>>>(fbf + 192, 512, qkvT + 12288, qkv_b1, qkvbuf + (size_t)Nt*192);
    attn_win<<<dim3(2048,2), 192, 0, stream>>>(qkvbuf, attnout);
    y0_kernel<<<NB*TT, 256, 0, stream>>>(fbf, gct, ybf);
    y1_kernel<<<NB*TT, 256, 0, stream>>>(fbf, tconv_w, tconv_b, ybf);
    gemm_k64<1><<<1024, 256, 0, stream>>>(attnout,                 128, aprojT,         aproj_b0, a0p);
    tcl_mfma<<<NTOK/192, 256, 0, stream>>>(a0p, tclT0, tcl_b0, ybf, 128);
    gemm_k64<1><<<1024, 256, 0, stream>>>(attnout + (size_t)Nt*64, 128, aprojT + 12288, aproj_b1, a0p);
    tcl_mfma<<<NTOK/192, 256, 0, stream>>>(a0p, tclT1, tcl_b1, ybf, 192);
    proj_ln2<<<512, 512, 0, stream>>>(ybf, projT, proj_b, xskip, n2g, n2b, outtH, xn8);
    mfma_mlp1_fp8<<<4096, 512, 0, stream>>>(xn8, w1T8, mlp_b1, h8);
    mfma_final_fp8<<<1024, 512, 0, stream>>>(h8, w2T8, mlp_b2, outtH, dout);
}

// Round 26
// 458.544 us; speedup vs baseline: 1.2131x; 1.1099x over previous
//
#include <hip/hip_runtime.h>
#include <hip/hip_bf16.h>
#include <math.h>

#define NB 32
#define CC 256
#define TT 64
#define VV 48
#define NTOK (NB*TT*VV)   // 98304
#define LNE 1e-5f
#define PROWS 3264        // (4+64)*48  (tcl pad rows per b)
#define PR7 3360          // (6+64)*48  (y1 pad rows per b)
#define A0P_USH ((size_t)NB*PROWS*192)

typedef __attribute__((ext_vector_type(8))) __bf16 bf16x8;
typedef __attribute__((ext_vector_type(4))) float f32x4;
typedef __attribute__((ext_vector_type(2))) long long2v;

__device__ inline float bfbits2f(unsigned int bits){
    union{unsigned int u; float f;} c; c.u = bits<<16; return c.f;
}
__device__ inline unsigned short f2bf(float x){
    union{ __bf16 h; unsigned short u; } c; c.h = (__bf16)x; return c.u;
}
__device__ inline unsigned char f2fp8(float x){
    int p = __builtin_amdgcn_cvt_pk_fp8_f32(x, x, 0, false);
    return (unsigned char)(p & 0xff);
}
__device__ inline unsigned int pk4fp8(float a, float b, float c, float d){
    int w = 0;
    w = __builtin_amdgcn_cvt_pk_fp8_f32(a, b, w, false);
    w = __builtin_amdgcn_cvt_pk_fp8_f32(c, d, w, true);
    return (unsigned int)w;
}
__device__ __forceinline__ void unpk8(uint4 u, float* d){
    d[0]=bfbits2f(u.x&0xffffu); d[1]=bfbits2f(u.x>>16);
    d[2]=bfbits2f(u.y&0xffffu); d[3]=bfbits2f(u.y>>16);
    d[4]=bfbits2f(u.z&0xffffu); d[5]=bfbits2f(u.z>>16);
    d[6]=bfbits2f(u.w&0xffffu); d[7]=bfbits2f(u.w>>16);
}
// 4*gelu(x) via sigmoid form: 4x * rcp(1 + exp(-1.702x)).
__device__ __forceinline__ float gelu4_fast(float x){
    float e = __expf(-1.702f * x);
    return (4.f * x) * __builtin_amdgcn_rcpf(1.f + e);
}

__device__ __forceinline__ void gll16(const char* g, char* l){
    __builtin_amdgcn_global_load_lds(
        (const __attribute__((address_space(1))) unsigned int*)g,
        (__attribute__((address_space(3))) unsigned int*)l, 16, 0, 0);
}

// ---------------- weight prep ----------------
__global__ void prep_weights(const float* gconv, const float* tcl0, const float* tcl1,
                             const float* map_w, const float* proj_w,
                             const float* mlp_w1, const float* mlp_w2,
                             const float* qkv_w0, const float* qkv_w1,
                             const float* aproj_w0, const float* aproj_w1,
                             const float* tconv,
                             float* gct,
                             unsigned short* mapT, unsigned short* projT,
                             unsigned char* w1T8, unsigned char* w2T8,
                             unsigned short* tclT0, unsigned short* tclT1,
                             unsigned short* qkvT, unsigned short* aprojT,
                             unsigned short* w1yT){
    int tid = blockIdx.x*blockDim.x + threadIdx.x;
    int stride = gridDim.x*blockDim.x;
    for (int i = tid; i < 8*48*48; i += stride){
        int g = i/(48*48); int r = i%(48*48); int u = r/48; int v = r%48;
        gct[i] = gconv[(g*48+v)*48+u];
    }
    for (int i = tid; i < 64*960; i += stride){
        int o = i/960, col = i%960, kh = col/192, c = col%192;
        tclT0[i] = f2bf(tcl0[(o*192+c)*5+kh]);
        tclT1[i] = f2bf(tcl1[(o*192+c)*5+kh]);
    }
    for (int i = tid; i < 65536; i += stride){
        int n = i>>8, k = i&255;
        mapT[i] = f2bf(map_w[k*256+n]);
        projT[i] = f2bf(proj_w[k*256+n]);
    }
    // w1T8[n][k] = fp8(mlp_w1[k][n] * 64)
    for (int i = tid; i < 262144; i += stride){
        int n = i>>8, k = i&255;
        w1T8[i] = f2fp8(mlp_w1[k*1024+n] * 64.f);
    }
    // w2T8[n][k] = fp8(mlp_w2[k][n] * 32)
    for (int i = tid; i < 262144; i += stride){
        int n = i>>10, k = i&1023;
        w2T8[i] = f2fp8(mlp_w2[k*256+n] * 32.f);
    }
    for (int i = tid; i < 12288; i += stride){
        int n = i/64, k = i%64;
        qkvT[i]          = f2bf(qkv_w0[k*192+n]);
        qkvT[12288+i]    = f2bf(qkv_w1[k*192+n]);
        aprojT[i]        = f2bf(aproj_w0[k*192+n]);
        aprojT[12288+i]  = f2bf(aproj_w1[k*192+n]);
    }
    // y1 conv as block-diag GEMM weights: w1yT[o][kh*64+ch]
    for (int i = tid; i < 64*448; i += stride){
        int o = i/448, k = i%448, kh = k>>6, ch = k&63;
        w1yT[i] = (ch>>3 == o>>3) ? f2bf(tconv[(o*8 + (ch&7))*7 + kh]) : (unsigned short)0;
    }
}

// ---------------- LN1 + transpose -> A1 bf16 [N][256] + raw skip copy ----------------
__global__ __launch_bounds__(256) void xpose_ln1(const float* __restrict__ x,
        const float* __restrict__ g, const float* __restrict__ bb,
        unsigned short* __restrict__ A1, unsigned short* __restrict__ xskip){
    int bt = blockIdx.x; int b = bt/TT, t = bt%TT;
    __shared__ float X[48*257];
    __shared__ float S[4][48], SS[4][48], sm[48], sv[48];
    int tid = threadIdx.x;
    const float* xb = x + (size_t)b*256*3072 + (size_t)t*48;
    for (int it = 0; it < 12; it++){
        int idx = it*256 + tid;
        int c = idx/12, q = idx%12;
        float4 v = *(const float4*)(xb + (size_t)c*3072 + q*4);
        X[(q*4+0)*257 + c] = v.x;
        X[(q*4+1)*257 + c] = v.y;
        X[(q*4+2)*257 + c] = v.z;
        X[(q*4+3)*257 + c] = v.w;
    }
    __syncthreads();
    if (tid < 192){
        int v = tid % 48, w = tid / 48;
        float s = 0.f, ss = 0.f;
        for (int c = w*64; c < w*64+64; c++){
            float val = X[v*257 + c];
            s += val; ss += val*val;
        }
        S[w][v] = s; SS[w][v] = ss;
    }
    __syncthreads();
    if (tid < 48){
        float s = S[0][tid]+S[1][tid]+S[2][tid]+S[3][tid];
        float q = SS[0][tid]+SS[1][tid]+SS[2][tid]+SS[3][tid];
        float m = s*(1.f/256);
        sm[tid] = m; sv[tid] = rsqrtf(q*(1.f/256) - m*m + LNE);
    }
    __syncthreads();
    int nb = bt*48;
    for (int it = 0; it < 12; it++){
        int idx = it*256 + tid;
        int v = idx>>6, cq = idx&63;
        float m = sm[v], rs = sv[v];
        float4 g4 = *(const float4*)(g + cq*4);
        float4 b4 = *(const float4*)(bb + cq*4);
        float x0 = X[v*257 + cq*4+0], x1 = X[v*257 + cq*4+1];
        float x2 = X[v*257 + cq*4+2], x3 = X[v*257 + cq*4+3];
        ushort4 u;
        u.x = f2bf((x0-m)*rs*g4.x + b4.x);
        u.y = f2bf((x1-m)*rs*g4.y + b4.y);
        u.z = f2bf((x2-m)*rs*g4.z + b4.z);
        u.w = f2bf((x3-m)*rs*g4.w + b4.w);
        *(ushort4*)(A1 + (size_t)(nb+v)*256 + cq*4) = u;
        ushort4 s;
        s.x = f2bf(x0); s.y = f2bf(x1); s.z = f2bf(x2); s.w = f2bf(x3);
        *(ushort4*)(xskip + (size_t)(nb+v)*256 + cq*4) = s;
    }
}

// ---------------- swizzled staging (single-shot, for k64 GEMM) ----------------
__device__ __forceinline__ void stage_swz(const char* src, size_t rowbytes, char* lds,
                                          int nchunks, int tid){
    for (int c = tid; c < nchunks; c += 256){
        int p = c << 4;
        int r = p >> 7;
        int kl = (p & 127) ^ ((r & 7) << 4);
        gll16(src + (size_t)r*rowbytes + kl, lds + p);
    }
}

__device__ __forceinline__ bf16x8 frag_ld(const char* lds, int R, int kb){
    return *(const bf16x8*)(lds + R*128 + (kb ^ ((R & 7) << 4)));
}
// 16-byte fp8 fragment read (conflict-free b128 pattern); the two 8-byte
// halves feed two MFMAs. K-permutation is identical for A and B -> exact.
__device__ __forceinline__ long2v frag_ld16(const char* lds, int R, int kb){
    return *(const long2v*)(lds + R*128 + (kb ^ ((R & 7) << 4)));
}

// ---------------- MFMA GEMM: BM=192, BN=128, 8 waves, dbuf + counted vmcnt ----------------
// EPI 4: outH = bf16(acc + bias)   [LDS repack, 16B stores]
template<int KTOT, int EPI>
__global__ __launch_bounds__(512, 4) void mfma_gemm(
    const unsigned short* __restrict__ A, const unsigned short* __restrict__ BT,
    const float* __restrict__ bias,
    unsigned short* __restrict__ outH, unsigned char* __restrict__ outH8,
    int ncols, int nx){

    constexpr int BM = 192, BN = 128;
    constexpr int HALF = (BM+BN)*128;           // 40960
    __shared__ __align__(16) char smem[2*HALF]; // 81920 -> 2 blocks/CU
    int tid = threadIdx.x, lane = tid & 63;
    int wid = tid >> 6;
    int wm = wid >> 1, wn = wid & 1;
    int l15 = lane & 15, lq = lane >> 4;
    int bid = blockIdx.x;
    int per = gridDim.x >> 3;
    int wkid = (bid & 7)*per + (bid >> 3);
    int m0 = (wkid / nx) * BM, n0 = (wkid % nx) * BN;
    const size_t arb = KTOT*2, brb = KTOT*2;
    constexpr int KT = KTOT/64;

    const char* gA[3]; int loA[3];
    const char* gB[2]; int loB[2];
    {
        const char* Ab = (const char*)A + (size_t)m0*arb;
        const char* Bb = (const char*)BT + (size_t)n0*brb;
        #pragma unroll
        for (int i = 0; i < 3; i++){
            int c = tid + i*512;
            int p = c << 4, r = p >> 7;
            int kl = (p & 127) ^ ((r & 7) << 4);
            gA[i] = Ab + (size_t)r*arb + kl; loA[i] = p;
        }
        #pragma unroll
        for (int i = 0; i < 2; i++){
            int c = tid + i*512;
            int p = c << 4, r = p >> 7;
            int kl = (p & 127) ^ ((r & 7) << 4);
            gB[i] = Bb + (size_t)r*brb + kl; loB[i] = BM*128 + p;
        }
    }

    f32x4 acc[3][4];
    #pragma unroll
    for (int i = 0; i < 3; i++)
        #pragma unroll
        for (int j = 0; j < 4; j++){ f32x4 z = {0.f,0.f,0.f,0.f}; acc[i][j] = z; }

    #pragma unroll
    for (int i = 0; i < 3; i++) gll16(gA[i], smem + loA[i]);
    #pragma unroll
    for (int i = 0; i < 2; i++) gll16(gB[i], smem + loB[i]);

    int koff = 128;
    for (int kt = 0; kt < KT; kt++){
        char* cur = smem + (kt & 1)*HALF;
        if (kt + 1 < KT){
            char* nxt = smem + ((kt + 1) & 1)*HALF;
            #pragma unroll
            for (int i = 0; i < 3; i++) gll16(gA[i] + koff, nxt + loA[i]);
            #pragma unroll
            for (int i = 0; i < 2; i++) gll16(gB[i] + koff, nxt + loB[i]);
            koff += 128;
            asm volatile("s_waitcnt vmcnt(5)" ::: "memory");
        } else {
            asm volatile("s_waitcnt vmcnt(0)" ::: "memory");
        }
        __builtin_amdgcn_s_barrier();
        __builtin_amdgcn_sched_barrier(0);
        char* ldsA = cur;
        char* ldsB = cur + BM*128;
        #pragma unroll
        for (int ks = 0; ks < 2; ks++){
            bf16x8 a[3], b[4];
            int kb = ks*64 + lq*16;
            #pragma unroll
            for (int mf = 0; mf < 3; mf++) a[mf] = frag_ld(ldsA, wm*48 + mf*16 + l15, kb);
            #pragma unroll
            for (int nf = 0; nf < 4; nf++) b[nf] = frag_ld(ldsB, wn*64 + nf*16 + l15, kb);
            #pragma unroll
            for (int mf = 0; mf < 3; mf++)
                #pragma unroll
                for (int nf = 0; nf < 4; nf++)
                    acc[mf][nf] = __builtin_amdgcn_mfma_f32_16x16x32_bf16(a[mf], b[nf], acc[mf][nf], 0, 0, 0);
        }
        __builtin_amdgcn_sched_barrier(0);
        __builtin_amdgcn_s_barrier();
    }

    if constexpr (EPI == 4){
        unsigned short* Hs = (unsigned short*)smem;   // [192][136]
        #pragma unroll
        for (int nf = 0; nf < 4; nf++){
            int col = wn*64 + nf*16 + l15;
            float bb = bias[n0 + col];
            #pragma unroll
            for (int mf = 0; mf < 3; mf++){
                int row = wm*48 + mf*16 + lq*4;
                f32x4 v = acc[mf][nf];
                #pragma unroll
                for (int r = 0; r < 4; r++)
                    Hs[(row+r)*136 + col] = f2bf(v[r] + bb);
            }
        }
        __syncthreads();
        for (int idx = tid; idx < 192*16; idx += 512){
            int row = idx >> 4, c8 = idx & 15;
            *(uint4*)(outH + (size_t)(m0+row)*ncols + n0 + c8*8) =
                *(const uint4*)(Hs + row*136 + c8*8);
        }
    }
}

// ---------------- MLP1 GEMM in fp8: K=256 as 2 tiles of K=128 (128B rows) ----------------
// outH8 = fp8(gelu4((acc/64) + bias)); b128 fragment reads (K-permuted, exact)
__global__ __launch_bounds__(512, 4) void mfma_mlp1_fp8(
    const unsigned char* __restrict__ A, const unsigned char* __restrict__ BT,
    const float* __restrict__ bias, unsigned char* __restrict__ outH8){

    constexpr int BM = 192, BN = 128, NX = 8;
    constexpr int HALF = (BM+BN)*128;           // 40960
    __shared__ __align__(16) char smem[2*HALF]; // 81920 -> 2 blocks/CU
    int tid = threadIdx.x, lane = tid & 63;
    int wid = tid >> 6;
    int wm = wid >> 1, wn = wid & 1;
    int l15 = lane & 15, lq = lane >> 4;
    int bid = blockIdx.x;
    int per = gridDim.x >> 3;
    int wkid = (bid & 7)*per + (bid >> 3);
    int m0 = (wkid / NX) * BM, n0 = (wkid % NX) * BN;
    const size_t arb = 256, brb = 256;
    constexpr int KT = 2;

    const char* gA[3]; int loA[3];
    const char* gB[2]; int loB[2];
    {
        const char* Ab = (const char*)A + (size_t)m0*arb;
        const char* Bb = (const char*)BT + (size_t)n0*brb;
        #pragma unroll
        for (int i = 0; i < 3; i++){
            int c = tid + i*512;
            int p = c << 4, r = p >> 7;
            int kl = (p & 127) ^ ((r & 7) << 4);
            gA[i] = Ab + (size_t)r*arb + kl; loA[i] = p;
        }
        #pragma unroll
        for (int i = 0; i < 2; i++){
            int c = tid + i*512;
            int p = c << 4, r = p >> 7;
            int kl = (p & 127) ^ ((r & 7) << 4);
            gB[i] = Bb + (size_t)r*brb + kl; loB[i] = BM*128 + p;
        }
    }

    f32x4 acc[3][4];
    #pragma unroll
    for (int i = 0; i < 3; i++)
        #pragma unroll
        for (int j = 0; j < 4; j++){ f32x4 z = {0.f,0.f,0.f,0.f}; acc[i][j] = z; }

    #pragma unroll
    for (int i = 0; i < 3; i++) gll16(gA[i], smem + loA[i]);
    #pragma unroll
    for (int i = 0; i < 2; i++) gll16(gB[i], smem + loB[i]);

    int koff = 128;
    for (int kt = 0; kt < KT; kt++){
        char* cur = smem + (kt & 1)*HALF;
        if (kt + 1 < KT){
            char* nxt = smem + ((kt + 1) & 1)*HALF;
            #pragma unroll
            for (int i = 0; i < 3; i++) gll16(gA[i] + koff, nxt + loA[i]);
            #pragma unroll
            for (int i = 0; i < 2; i++) gll16(gB[i] + koff, nxt + loB[i]);
            koff += 128;
            asm volatile("s_waitcnt vmcnt(5)" ::: "memory");
        } else {
            asm volatile("s_waitcnt vmcnt(0)" ::: "memory");
        }
        __builtin_amdgcn_s_barrier();
        __builtin_amdgcn_sched_barrier(0);
        char* ldsA = cur;
        char* ldsB = cur + BM*128;
        #pragma unroll
        for (int hf = 0; hf < 2; hf++){
            long2v a[3], b[4];
            int kb = hf*64 + lq*16;
            #pragma unroll
            for (int mf = 0; mf < 3; mf++) a[mf] = frag_ld16(ldsA, wm*48 + mf*16 + l15, kb);
            #pragma unroll
            for (int nf = 0; nf < 4; nf++) b[nf] = frag_ld16(ldsB, wn*64 + nf*16 + l15, kb);
            #pragma unroll
            for (int mf = 0; mf < 3; mf++)
                #pragma unroll
                for (int nf = 0; nf < 4; nf++){
                    acc[mf][nf] = __builtin_amdgcn_mfma_f32_16x16x32_fp8_fp8(a[mf][0], b[nf][0], acc[mf][nf], 0, 0, 0);
                    acc[mf][nf] = __builtin_amdgcn_mfma_f32_16x16x32_fp8_fp8(a[mf][1], b[nf][1], acc[mf][nf], 0, 0, 0);
                }
        }
        __builtin_amdgcn_sched_barrier(0);
        __builtin_amdgcn_s_barrier();
    }

    unsigned char* Hc = (unsigned char*)smem;     // [192][144] fp8
    #pragma unroll
    for (int nf = 0; nf < 4; nf++){
        int col = wn*64 + nf*16 + l15;
        float bb = bias[n0 + col];
        #pragma unroll
        for (int mf = 0; mf < 3; mf++){
            int row = wm*48 + mf*16 + lq*4;
            f32x4 v = acc[mf][nf];
            #pragma unroll
            for (int r = 0; r < 4; r++){
                float t0 = gelu4_fast(v[r]*0.015625f + bb);
                Hc[(row+r)*144 + col] = f2fp8(t0);
            }
        }
    }
    __syncthreads();
    for (int idx = tid; idx < 192*8; idx += 512){
        int row = idx >> 3, c16 = idx & 7;
        *(uint4*)(outH8 + (size_t)(m0+row)*1024 + n0 + c16*16) =
            *(const uint4*)(Hc + row*144 + c16*16);
    }
}

// ---------------- final GEMM in fp8: K=1024 as 8 tiles of K=128 (128B rows) ----------------
// epilogue: dout NCHW = acc/128 + bias + resid; Tt stride 197 (bank-coprime),
// both wave-halves fill every pass (nf = 2p, 2p+1), ch remap in store.
__global__ __launch_bounds__(512, 4) void mfma_final_fp8(
    const unsigned char* __restrict__ A, const unsigned char* __restrict__ BT,
    const float* __restrict__ bias, const unsigned short* __restrict__ extraH,
    float* __restrict__ outF){

    constexpr int BM = 192, BN = 128, NX = 2;
    constexpr int HALF = (BM+BN)*128;           // 40960
    __shared__ __align__(16) char smem[2*HALF]; // 81920 -> 2 blocks/CU
    int tid = threadIdx.x, lane = tid & 63;
    int wid = tid >> 6;
    int wm = wid >> 1, wn = wid & 1;
    int l15 = lane & 15, lq = lane >> 4;
    int bid = blockIdx.x;
    int per = gridDim.x >> 3;
    int wkid = (bid & 7)*per + (bid >> 3);
    int m0 = (wkid / NX) * BM, n0 = (wkid % NX) * BN;
    const size_t arb = 1024, brb = 1024;
    constexpr int KT = 8;

    const char* gA[3]; int loA[3];
    const char* gB[2]; int loB[2];
    {
        const char* Ab = (const char*)A + (size_t)m0*arb;
        const char* Bb = (const char*)BT + (size_t)n0*brb;
        #pragma unroll
        for (int i = 0; i < 3; i++){
            int c = tid + i*512;
            int p = c << 4, r = p >> 7;
            int kl = (p & 127) ^ ((r & 7) << 4);
            gA[i] = Ab + (size_t)r*arb + kl; loA[i] = p;
        }
        #pragma unroll
        for (int i = 0; i < 2; i++){
            int c = tid + i*512;
            int p = c << 4, r = p >> 7;
            int kl = (p & 127) ^ ((r & 7) << 4);
            gB[i] = Bb + (size_t)r*brb + kl; loB[i] = BM*128 + p;
        }
    }

    f32x4 acc[3][4];
    #pragma unroll
    for (int i = 0; i < 3; i++)
        #pragma unroll
        for (int j = 0; j < 4; j++){ f32x4 z = {0.f,0.f,0.f,0.f}; acc[i][j] = z; }

    #pragma unroll
    for (int i = 0; i < 3; i++) gll16(gA[i], smem + loA[i]);
    #pragma unroll
    for (int i = 0; i < 2; i++) gll16(gB[i], smem + loB[i]);

    int koff = 128;
    for (int kt = 0; kt < KT; kt++){
        char* cur = smem + (kt & 1)*HALF;
        if (kt + 1 < KT){
            char* nxt = smem + ((kt + 1) & 1)*HALF;
            #pragma unroll
            for (int i = 0; i < 3; i++) gll16(gA[i] + koff, nxt + loA[i]);
            #pragma unroll
            for (int i = 0; i < 2; i++) gll16(gB[i] + koff, nxt + loB[i]);
            koff += 128;
            asm volatile("s_waitcnt vmcnt(5)" ::: "memory");
        } else {
            asm volatile("s_waitcnt vmcnt(0)" ::: "memory");
        }
        __builtin_amdgcn_s_barrier();
        __builtin_amdgcn_sched_barrier(0);
        char* ldsA = cur;
        char* ldsB = cur + BM*128;
        #pragma unroll
        for (int hf = 0; hf < 2; hf++){
            long2v a[3], b[4];
            int kb = hf*64 + lq*16;
            #pragma unroll
            for (int mf = 0; mf < 3; mf++) a[mf] = frag_ld16(ldsA, wm*48 + mf*16 + l15, kb);
            #pragma unroll
            for (int nf = 0; nf < 4; nf++) b[nf] = frag_ld16(ldsB, wn*64 + nf*16 + l15, kb);
            #pragma unroll
            for (int mf = 0; mf < 3; mf++)
                #pragma unroll
                for (int nf = 0; nf < 4; nf++){
                    acc[mf][nf] = __builtin_amdgcn_mfma_f32_16x16x32_fp8_fp8(a[mf][0], b[nf][0], acc[mf][nf], 0, 0, 0);
                    acc[mf][nf] = __builtin_amdgcn_mfma_f32_16x16x32_fp8_fp8(a[mf][1], b[nf][1], acc[mf][nf], 0, 0, 0);
                }
        }
        __builtin_amdgcn_sched_barrier(0);
        __builtin_amdgcn_s_barrier();
    }

    // epilogue: two passes; pass p covers cols {32p..32p+31} U {64+32p..64+32p+31}.
    float* Tt = (float*)smem;  // [64 virtual-rows][197]
    #pragma unroll
    for (int p = 0; p < 2; p++){
        __syncthreads();
        #pragma unroll
        for (int q = 0; q < 2; q++){
            int nf = 2*p + q;
            int col = wn*64 + nf*16 + l15;          // actual output col (0..127)
            int vc  = wn*32 + q*16 + l15;           // virtual row in Tt (0..63)
            float bb = bias[n0 + col];
            #pragma unroll
            for (int mf = 0; mf < 3; mf++){
                int tl = wm*48 + mf*16 + lq*4;
                f32x4 v = acc[mf][nf];
                #pragma unroll
                for (int r = 0; r < 4; r++){
                    float resid = bfbits2f(extraH[(size_t)(m0+tl+r)*256 + n0 + col]);
                    Tt[vc*197 + tl + r] = v[r]*0.0078125f + bb + resid;
                }
            }
        }
        __syncthreads();
        {
            int lc = tid & 63, btl = (tid>>6)&3, dup = tid>>8;
            int ch = 32*p + lc + (lc & 32);         // actual col for virtual row lc
            int gtok = m0 + btl*48;
            int bg = gtok/3072, t = (gtok%3072)/48;
            float* dst = outF + ((size_t)(bg*256 + n0 + ch)*64 + t)*48 + dup*24;
            const float* tr = Tt + lc*197 + btl*48 + dup*24;
            #pragma unroll
            for (int j = 0; j < 6; j++)
                *(float4*)(dst + j*4) = *(const float4*)(tr + j*4);
        }
    }
}

// ---------------- proj GEMM fused with skip-add + LN2: BM=192, BN=256, K=256 ----------------
// xn output fp8 (input to fp8 MLP1)
__global__ __launch_bounds__(512, 2) void proj_ln2(
    const unsigned short* __restrict__ A, const unsigned short* __restrict__ BT,
    const float* __restrict__ bias, const unsigned short* __restrict__ xskip,
    const float* __restrict__ n2g, const float* __restrict__ n2b,
    unsigned short* __restrict__ outtH, unsigned char* __restrict__ xn8){

    constexpr int BM = 192, BN = 256, KTOT = 256;
    constexpr int HALF = (BM+BN)*128;
    __shared__ __align__(16) char smem[2*HALF];
    int tid = threadIdx.x, lane = tid & 63;
    int wid = tid >> 6;
    int wm = wid >> 1, wn = wid & 1;
    int l15 = lane & 15, lq = lane >> 4;
    int bid = blockIdx.x;
    int per = gridDim.x >> 3;
    int wkid = (bid & 7)*per + (bid >> 3);
    int m0 = wkid * BM;
    const size_t arb = KTOT*2, brb = KTOT*2;
    constexpr int KT = KTOT/64;

    const char* gA[3]; int loA[3];
    const char* gB[4]; int loB[4];
    {
        const char* Ab = (const char*)A + (size_t)m0*arb;
        const char* Bb = (const char*)BT;
        #pragma unroll
        for (int i = 0; i < 3; i++){
            int c = tid + i*512;
            int p = c << 4, r = p >> 7;
            int kl = (p & 127) ^ ((r & 7) << 4);
            gA[i] = Ab + (size_t)r*arb + kl; loA[i] = p;
        }
        #pragma unroll
        for (int i = 0; i < 4; i++){
            int c = tid + i*512;
            int p = c << 4, r = p >> 7;
            int kl = (p & 127) ^ ((r & 7) << 4);
            gB[i] = Bb + (size_t)r*brb + kl; loB[i] = BM*128 + p;
        }
    }

    f32x4 acc[3][8];
    #pragma unroll
    for (int i = 0; i < 3; i++)
        #pragma unroll
        for (int j = 0; j < 8; j++){ f32x4 z = {0.f,0.f,0.f,0.f}; acc[i][j] = z; }

    #pragma unroll
    for (int i = 0; i < 3; i++) gll16(gA[i], smem + loA[i]);
    #pragma unroll
    for (int i = 0; i < 4; i++) gll16(gB[i], smem + loB[i]);

    int koff = 128;
    for (int kt = 0; kt < KT; kt++){
        char* cur = smem + (kt & 1)*HALF;
        if (kt + 1 < KT){
            char* nxt = smem + ((kt + 1) & 1)*HALF;
            #pragma unroll
            for (int i = 0; i < 3; i++) gll16(gA[i] + koff, nxt + loA[i]);
            #pragma unroll
            for (int i = 0; i < 4; i++) gll16(gB[i] + koff, nxt + loB[i]);
            koff += 128;
            asm volatile("s_waitcnt vmcnt(7)" ::: "memory");
        } else {
            asm volatile("s_waitcnt vmcnt(0)" ::: "memory");
        }
        __builtin_amdgcn_s_barrier();
        __builtin_amdgcn_sched_barrier(0);
        char* ldsA = cur;
        char* ldsB = cur + BM*128;
        #pragma unroll
        for (int ks = 0; ks < 2; ks++){
            bf16x8 a[3], b[8];
            int kb = ks*64 + lq*16;
            #pragma unroll
            for (int mf = 0; mf < 3; mf++) a[mf] = frag_ld(ldsA, wm*48 + mf*16 + l15, kb);
            #pragma unroll
            for (int nf = 0; nf < 8; nf++) b[nf] = frag_ld(ldsB, wn*128 + nf*16 + l15, kb);
            #pragma unroll
            for (int mf = 0; mf < 3; mf++)
                #pragma unroll
                for (int nf = 0; nf < 8; nf++)
                    acc[mf][nf] = __builtin_amdgcn_mfma_f32_16x16x32_bf16(a[mf], b[nf], acc[mf][nf], 0, 0, 0);
        }
        __builtin_amdgcn_sched_barrier(0);
        __builtin_amdgcn_s_barrier();
    }

    unsigned short* Hs = (unsigned short*)smem;
    float* Sred = (float*)(smem + 101376);
    float s_acc[3][4], ss_acc[3][4];
    #pragma unroll
    for (int i = 0; i < 3; i++)
        #pragma unroll
        for (int r = 0; r < 4; r++){ s_acc[i][r] = 0.f; ss_acc[i][r] = 0.f; }

    #pragma unroll
    for (int nf = 0; nf < 8; nf++){
        int col = wn*128 + nf*16 + l15;
        float bb = bias[col];
        #pragma unroll
        for (int mf = 0; mf < 3; mf++){
            int row = wm*48 + mf*16 + lq*4;
            f32x4 v = acc[mf][nf];
            #pragma unroll
            for (int r = 0; r < 4; r++){
                float sk = bfbits2f(xskip[(size_t)(m0+row+r)*256 + col]);
                unsigned short us = f2bf(v[r] + bb + sk);
                Hs[(row+r)*264 + col] = us;
                float tf = bfbits2f(us);
                s_acc[mf][r] += tf; ss_acc[mf][r] += tf*tf;
            }
        }
    }
    #pragma unroll
    for (int mf = 0; mf < 3; mf++)
        #pragma unroll
        for (int r = 0; r < 4; r++){
            float s = s_acc[mf][r], ss = ss_acc[mf][r];
            #pragma unroll
            for (int d = 1; d < 16; d <<= 1){
                s  += __shfl_xor(s, d);
                ss += __shfl_xor(ss, d);
            }
            if (l15 == 0){
                int row = wm*48 + mf*16 + lq*4 + r;
                Sred[wn*192 + row] = s;
                Sred[384 + wn*192 + row] = ss;
            }
        }
    __syncthreads();
    if (tid < 192){
        float s  = Sred[tid] + Sred[192+tid];
        float ss = Sred[384+tid] + Sred[576+tid];
        float m = s*(1.f/256);
        Sred[tid] = m;
        Sred[192+tid] = rsqrtf(ss*(1.f/256) - m*m + LNE);
    }
    __syncthreads();
    for (int idx = tid; idx < 192*32; idx += 512){
        int row = idx >> 5, c8 = idx & 31;
        uint4 hv = *(const uint4*)(Hs + row*264 + c8*8);
        *(uint4*)(outtH + (size_t)(m0+row)*256 + c8*8) = hv;
        float v[8]; unpk8(hv, v);
        float m = Sred[row], rs = Sred[192+row];
        float xv[8];
        #pragma unroll
        for (int j = 0; j < 8; j++)
            xv[j] = (v[j]-m)*rs*n2g[c8*8 + j] + n2b[c8*8 + j];
        uint2 o;
        o.x = pk4fp8(xv[0], xv[1], xv[2], xv[3]);
        o.y = pk4fp8(xv[4], xv[5], xv[6], xv[7]);
        *(uint2*)(xn8 + (size_t)(m0+row)*256 + c8*8) = o;
    }
}

// ---------------- K=64 MFMA GEMM: BM=96, BN=192, 4 waves ----------------
template<int EPI>
__global__ __launch_bounds__(256) void gemm_k64(
    const unsigned short* __restrict__ A, int arb,
    const unsigned short* __restrict__ BT,
    const float* __restrict__ bias,
    unsigned short* __restrict__ out){
    __shared__ __align__(16) char smem[96*128 + 192*128];
    char* ldsA = smem;
    char* ldsB = smem + 96*128;
    int tid = threadIdx.x, lane = tid & 63;
    int wid = tid >> 6, wm = wid >> 1, wn = wid & 1;
    int l15 = lane & 15, lq = lane >> 4;
    int m0 = blockIdx.x * 96;

    stage_swz((const char*)A + (size_t)m0*arb, arb, ldsA, 96*8, tid);
    stage_swz((const char*)BT, 128, ldsB, 192*8, tid);
    __syncthreads();

    f32x4 acc[3][6];
    #pragma unroll
    for (int i = 0; i < 3; i++)
        #pragma unroll
        for (int j = 0; j < 6; j++){ f32x4 z = {0.f,0.f,0.f,0.f}; acc[i][j] = z; }

    #pragma unroll
    for (int ks = 0; ks < 2; ks++){
        bf16x8 a[3], b[6];
        int kb = ks*64 + lq*16;
        #pragma unroll
        for (int mf = 0; mf < 3; mf++) a[mf] = frag_ld(ldsA, wm*48 + mf*16 + l15, kb);
        #pragma unroll
        for (int nf = 0; nf < 6; nf++) b[nf] = frag_ld(ldsB, wn*96 + nf*16 + l15, kb);
        #pragma unroll
        for (int mf = 0; mf < 3; mf++)
            #pragma unroll
            for (int nf = 0; nf < 6; nf++)
                acc[mf][nf] = __builtin_amdgcn_mfma_f32_16x16x32_bf16(a[mf], b[nf], acc[mf][nf], 0, 0, 0);
    }

    size_t row0;
    if constexpr (EPI == 0) row0 = (size_t)m0;
    else {
        int b = m0/3072;
        row0 = (size_t)b*PROWS + 192 + (m0 - b*3072);
    }
    #pragma unroll
    for (int nf = 0; nf < 6; nf++){
        int col = wn*96 + nf*16 + l15;
        float bb = bias[col];
        #pragma unroll
        for (int mf = 0; mf < 3; mf++){
            size_t rr = row0 + wm*48 + mf*16 + lq*4;
            f32x4 v = acc[mf][nf];
            #pragma unroll
            for (int r = 0; r < 4; r++)
                out[(rr+r)*192 + col] = f2bf(v[r] + bb);
        }
    }
}

// ---------------- windowed attention ----------------
__global__ __launch_bounds__(192) void attn_win(
        const unsigned short* __restrict__ qkvbuf,
        unsigned short* __restrict__ attnout){
    int win = blockIdx.x, br = blockIdx.y;
    size_t base = (size_t)br*NTOK + (size_t)win*48;
    __shared__ float Q[48*196];
    int tid = threadIdx.x;
    const unsigned short* src = qkvbuf + base*192;
    for (int i = 0; i < 6; i++){
        int ch = i*192 + tid;
        int v = ch/24, c8 = ch%24;
        uint4 u = *(const uint4*)(src + (size_t)v*192 + c8*8);
        unpk8(u, &Q[v*196 + c8*8]);
    }
    __syncthreads();
    int u = tid & 15, gh = tid >> 4, g = gh >> 2, h = gh & 3;
    int ru = g*16 + u;
    float qreg[16];
    #pragma unroll
    for (int d = 0; d < 16; d++) qreg[d] = Q[ru*196 + h*16 + d];
    float sc[16]; float mx = -1e30f;
    #pragma unroll
    for (int w = 0; w < 16; w++){
        float s = 0.f;
        #pragma unroll
        for (int d = 0; d < 16; d++) s += qreg[d]*Q[(g*16+w)*196 + 64 + h*16 + d];
        s *= 0.5f; sc[w] = s; mx = fmaxf(mx, s);
    }
    float sum = 0.f;
    #pragma unroll
    for (int w = 0; w < 16; w++){ sc[w] = __expf(sc[w]-mx); sum += sc[w]; }
    float inv = __builtin_amdgcn_rcpf(sum);
    unsigned int w32[8];
    #pragma unroll
    for (int dp = 0; dp < 8; dp++){
        float o0 = 0.f, o1 = 0.f;
        #pragma unroll
        for (int w = 0; w < 16; w++){
            float p = sc[w];
            o0 += p*Q[(g*16+w)*196 + 128 + h*16 + dp*2];
            o1 += p*Q[(g*16+w)*196 + 128 + h*16 + dp*2+1];
        }
        w32[dp] = (unsigned int)f2bf(o0*inv) | ((unsigned int)f2bf(o1*inv) << 16);
    }
    unsigned short* dst = attnout + (base + ru)*64 + h*16;
    uint4 q0; q0.x=w32[0]; q0.y=w32[1]; q0.z=w32[2]; q0.w=w32[3];
    uint4 q1; q1.x=w32[4]; q1.y=w32[5]; q1.z=w32[6]; q1.w=w32[7];
    *(uint4*)(dst)   = q0;
    *(uint4*)(dst+8) = q1;
}

// ---------------- tcl as MFMA GEMM: K=960 (15 tiles), dbuf + counted vmcnt ----------------
__global__ __launch_bounds__(256) void tcl_mfma(const unsigned short* __restrict__ A0p,
        const unsigned short* __restrict__ BT, const float* __restrict__ tb,
        unsigned short* __restrict__ ybf, int outoff){
    constexpr int HALF = (192+64)*128;
    __shared__ __align__(16) char smem[2*HALF];
    int tid = threadIdx.x, lane = tid & 63;
    int wid = tid >> 6;
    int l15 = lane & 15, lq = lane >> 4;
    int bid = blockIdx.x;
    int per = gridDim.x >> 3;
    int wkid = (bid & 7)*per + (bid >> 3);
    int m0 = wkid * 192;
    int b = m0 / 3072;
    long brow0 = (long)b*PROWS + 192 + (m0 - b*3072);

    const char* gA[6]; int loA[6];
    const char* gB[2]; int loB[2];
    {
        const char* Ab = (const char*)A0p + (brow0 - 192)*384;
        #pragma unroll
        for (int i = 0; i < 6; i++){
            int c = tid + i*256;
            int p = c << 4, r = p >> 7;
            int kl = (p & 127) ^ ((r & 7) << 4);
            gA[i] = Ab + (size_t)r*384 + kl; loA[i] = p;
        }
        #pragma unroll
        for (int i = 0; i < 2; i++){
            int c = tid + i*256;
            int p = c << 4, r = p >> 7;
            int kl = (p & 127) ^ ((r & 7) << 4);
            gB[i] = (const char*)BT + (size_t)r*1920 + kl; loB[i] = 192*128 + p;
        }
    }

    f32x4 acc[3][4];
    #pragma unroll
    for (int i = 0; i < 3; i++)
        #pragma unroll
        for (int j = 0; j < 4; j++){ f32x4 z = {0.f,0.f,0.f,0.f}; acc[i][j] = z; }

    #pragma unroll
    for (int i = 0; i < 6; i++) gll16(gA[i], smem + loA[i]);
    #pragma unroll
    for (int i = 0; i < 2; i++) gll16(gB[i], smem + loB[i]);

    long offA = 0; int kc3 = 0; int offB = 0;
    for (int kt = 0; kt < 15; kt++){
        char* cur = smem + (kt & 1)*HALF;
        if (kt + 1 < 15){
            char* nxt = smem + ((kt + 1) & 1)*HALF;
            if (kc3 == 2){ offA += 18432 - 256; kc3 = 0; }
            else         { offA += 128; kc3++; }
            offB += 128;
            #pragma unroll
            for (int i = 0; i < 6; i++) gll16(gA[i] + offA, nxt + loA[i]);
            #pragma unroll
            for (int i = 0; i < 2; i++) gll16(gB[i] + offB, nxt + loB[i]);
            asm volatile("s_waitcnt vmcnt(8)" ::: "memory");
        } else {
            asm volatile("s_waitcnt vmcnt(0)" ::: "memory");
        }
        __builtin_amdgcn_s_barrier();
        __builtin_amdgcn_sched_barrier(0);
        char* ldsA = cur;
        char* ldsB = cur + 192*128;
        #pragma unroll
        for (int ks = 0; ks < 2; ks++){
            bf16x8 a[3], bb[4];
            int kb = ks*64 + lq*16;
            #pragma unroll
            for (int mf = 0; mf < 3; mf++) a[mf] = frag_ld(ldsA, wid*48 + mf*16 + l15, kb);
            #pragma unroll
            for (int nf = 0; nf < 4; nf++) bb[nf] = frag_ld(ldsB, nf*16 + l15, kb);
            #pragma unroll
            for (int mf = 0; mf < 3; mf++)
                #pragma unroll
                for (int nf = 0; nf < 4; nf++)
                    acc[mf][nf] = __builtin_amdgcn_mfma_f32_16x16x32_bf16(a[mf], bb[nf], acc[mf][nf], 0, 0, 0);
        }
        __builtin_amdgcn_sched_barrier(0);
        __builtin_amdgcn_s_barrier();
    }
    #pragma unroll
    for (int nf = 0; nf < 4; nf++){
        int col = nf*16 + l15;
        float bb = tb[col];
        #pragma unroll
        for (int mf = 0; mf < 3; mf++){
            int tok = m0 + wid*48 + mf*16 + lq*4;
            f32x4 v = acc[mf][nf];
            #pragma unroll
            for (int r = 0; r < 4; r++)
                ybf[(size_t)(tok+r)*256 + outoff + col] = f2bf(v[r] + bb);
        }
    }
}

// ---------------- y1 pad fill: fbf cols 64..127 -> y1pad[b][PR7 rows][64], zero edges ----------------
__global__ __launch_bounds__(256) void pad_y1(const unsigned short* __restrict__ fbf,
        unsigned short* __restrict__ pad){
    int i = blockIdx.x*256 + threadIdx.x;     // 32*PR7*8 = 860160 chunks
    int c8 = i & 7; int pr = i >> 3;
    int b = pr / PR7; int r = pr - b*PR7;
    int tr = r - 144;
    uint4 u; u.x = 0; u.y = 0; u.z = 0; u.w = 0;
    if (tr >= 0 && tr < 3072)
        u = *(const uint4*)(fbf + ((size_t)b*3072 + tr)*256 + 64 + c8*8);
    *(uint4*)(pad + (size_t)pr*64 + c8*8) = u;
}

// ---------------- y1 as MFMA GEMM: K=448 (7 tiles of 64 ch), block-diag weights ----------------
__global__ __launch_bounds__(256) void y1_mfma(const unsigned short* __restrict__ pad,
        const unsigned short* __restrict__ BT, const float* __restrict__ tb,
        unsigned short* __restrict__ ybf){
    constexpr int HALF = (192+64)*128;
    __shared__ __align__(16) char smem[2*HALF];
    int tid = threadIdx.x, lane = tid & 63;
    int wid = tid >> 6;
    int l15 = lane & 15, lq = lane >> 4;
    int bid = blockIdx.x;
    int per = gridDim.x >> 3;
    int wkid = (bid & 7)*per + (bid >> 3);
    int m0 = wkid * 192;
    int b = m0 / 3072;

    const char* gA[6]; int loA[6];
    const char* gB[2]; int loB[2];
    {
        const char* Ab = (const char*)pad + ((size_t)b*PR7 + (m0 - b*3072)) * 128;
        #pragma unroll
        for (int i = 0; i < 6; i++){
            int c = tid + i*256;
            int p = c << 4, r = p >> 7;
            int kl = (p & 127) ^ ((r & 7) << 4);
            gA[i] = Ab + (size_t)r*128 + kl; loA[i] = p;
        }
        #pragma unroll
        for (int i = 0; i < 2; i++){
            int c = tid + i*256;
            int p = c << 4, r = p >> 7;
            int kl = (p & 127) ^ ((r & 7) << 4);
            gB[i] = (const char*)BT + (size_t)r*896 + kl; loB[i] = 192*128 + p;
        }
    }

    f32x4 acc[3][4];
    #pragma unroll
    for (int i = 0; i < 3; i++)
        #pragma unroll
        for (int j = 0; j < 4; j++){ f32x4 z = {0.f,0.f,0.f,0.f}; acc[i][j] = z; }

    #pragma unroll
    for (int i = 0; i < 6; i++) gll16(gA[i], smem + loA[i]);
    #pragma unroll
    for (int i = 0; i < 2; i++) gll16(gB[i], smem + loB[i]);

    int offA = 0, offB = 0;
    for (int kt = 0; kt < 7; kt++){
        char* cur = smem + (kt & 1)*HALF;
        if (kt + 1 < 7){
            char* nxt = smem + ((kt + 1) & 1)*HALF;
            offA += 6144;          // +48 pad rows (one tap)
            offB += 128;
            #pragma unroll
            for (int i = 0; i < 6; i++) gll16(gA[i] + offA, nxt + loA[i]);
            #pragma unroll
            for (int i = 0; i < 2; i++) gll16(gB[i] + offB, nxt + loB[i]);
            asm volatile("s_waitcnt vmcnt(8)" ::: "memory");
        } else {
            asm volatile("s_waitcnt vmcnt(0)" ::: "memory");
        }
        __builtin_amdgcn_s_barrier();
        __builtin_amdgcn_sched_barrier(0);
        char* ldsA = cur;
        char* ldsB = cur + 192*128;
        #pragma unroll
        for (int ks = 0; ks < 2; ks++){
            bf16x8 a[3], bb[4];
            int kb = ks*64 + lq*16;
            #pragma unroll
            for (int mf = 0; mf < 3; mf++) a[mf] = frag_ld(ldsA, wid*48 + mf*16 + l15, kb);
            #pragma unroll
            for (int nf = 0; nf < 4; nf++) bb[nf] = frag_ld(ldsB, nf*16 + l15, kb);
            #pragma unroll
            for (int mf = 0; mf < 3; mf++)
                #pragma unroll
                for (int nf = 0; nf < 4; nf++)
                    acc[mf][nf] = __builtin_amdgcn_mfma_f32_16x16x32_bf16(a[mf], bb[nf], acc[mf][nf], 0, 0, 0);
        }
        __builtin_amdgcn_sched_barrier(0);
        __builtin_amdgcn_s_barrier();
    }
    #pragma unroll
    for (int nf = 0; nf < 4; nf++){
        int col = nf*16 + l15;
        float bb = tb[col];
        #pragma unroll
        for (int mf = 0; mf < 3; mf++){
            int tok = m0 + wid*48 + mf*16 + lq*4;
            f32x4 v = acc[mf][nf];
            #pragma unroll
            for (int r = 0; r < 4; r++)
                ybf[(size_t)(tok+r)*256 + 64 + col] = f2bf(v[r] + bb);
        }
    }
}

// ---------------- y0: grouped V-mix -> ybf cols 0..63 ----------------
__global__ __launch_bounds__(256) void y0_kernel(const unsigned short* __restrict__ fbf,
        const float* __restrict__ gct, unsigned short* __restrict__ ybf){
    int bt = blockIdx.x; int nb = bt*VV;
    __shared__ float X[48*68];
    for (int it = 0; it < 2; it++){
        int idx = it*256 + threadIdx.x;
        if (idx < 384){
            int v = idx >> 3, c8 = idx & 7;
            uint4 u = *(const uint4*)(fbf + (size_t)(nb+v)*256 + c8*8);
            unpk8(u, &X[v*68 + c8*8]);
        }
    }
    __syncthreads();
    int c = threadIdx.x % 64, vv = threadIdx.x / 64;
    int g = c >> 3;
    float acc[12] = {};
    for (int u = 0; u < 48; u++){
        float xv = X[u*68 + c];
        const float* gr = gct + (size_t)(g*48+u)*48 + vv*12;
        float4 g0 = *(const float4*)(gr);
        float4 g1 = *(const float4*)(gr+4);
        float4 g2 = *(const float4*)(gr+8);
        acc[0]+=xv*g0.x; acc[1]+=xv*g0.y; acc[2]+=xv*g0.z;  acc[3]+=xv*g0.w;
        acc[4]+=xv*g1.x; acc[5]+=xv*g1.y; acc[6]+=xv*g1.z;  acc[7]+=xv*g1.w;
        acc[8]+=xv*g2.x; acc[9]+=xv*g2.y; acc[10]+=xv*g2.z; acc[11]+=xv*g2.w;
    }
    #pragma unroll
    for (int j = 0; j < 12; j++)
        ybf[(size_t)(nb + vv*12 + j)*256 + c] = f2bf(acc[j]);
}

extern "C" void kernel_launch(void* const* d_in, const int* in_sizes, int n_in,
                              void* d_out, int out_size, void* d_ws, size_t ws_size,
                              hipStream_t stream){
    const float* input   = (const float*)d_in[0];
    const float* n1g     = (const float*)d_in[1];
    const float* n1b     = (const float*)d_in[2];
    const float* map_w   = (const float*)d_in[3];
    const float* map_b   = (const float*)d_in[4];
    const float* gconv   = (const float*)d_in[5];
    const float* tconv_w = (const float*)d_in[6];
    const float* tconv_b = (const float*)d_in[7];
    const float* qkv_w0  = (const float*)d_in[8];
    const float* qkv_b0  = (const float*)d_in[9];
    const float* aproj_w0= (const float*)d_in[10];
    const float* aproj_b0= (const float*)d_in[11];
    const float* tcl_w0  = (const float*)d_in[12];
    const float* tcl_b0  = (const float*)d_in[13];
    const float* qkv_w1  = (const float*)d_in[14];
    const float* qkv_b1  = (const float*)d_in[15];
    const float* aproj_w1= (const float*)d_in[16];
    const float* aproj_b1= (const float*)d_in[17];
    const float* tcl_w1  = (const float*)d_in[18];
    const float* tcl_b1  = (const float*)d_in[19];
    const float* proj_w  = (const float*)d_in[20];
    const float* proj_b  = (const float*)d_in[21];
    const float* n2g     = (const float*)d_in[22];
    const float* n2b     = (const float*)d_in[23];
    const float* mlp_w1  = (const float*)d_in[24];
    const float* mlp_b1  = (const float*)d_in[25];
    const float* mlp_w2  = (const float*)d_in[26];
    const float* mlp_b2  = (const float*)d_in[27];

    const size_t Nt = NTOK;
    if (ws_size < 354050048ull) return;

    char* base = (char*)d_ws;
    unsigned short* outtH  = (unsigned short*)base;                  //  50 MB (bf16 outt; w1yT parked here early)
    unsigned short* fbf    = (unsigned short*)(base + 100663296);    //  50 MB
    unsigned short* a0p    = (unsigned short*)(base + 150994944);    //  40 MB
    unsigned short* qkvbuf = (unsigned short*)(base + 191102976);    //  75 MB
    unsigned short* attnout= (unsigned short*)(base + 266600448);    //  25 MB
    unsigned short* A1     = (unsigned short*)(base + 301989888);    //  50 MB
    char* wp = base + 352321536;
    float* gct            = (float*)wp;
    unsigned short* mapT  = (unsigned short*)(wp + 73728);
    unsigned short* projT = mapT + 65536;
    unsigned short* w1T   = projT + 65536;            // layout anchor (1 MB region)
    unsigned char* w2T8   = (unsigned char*)(w1T + 262144);
    unsigned char* w1T8   = w2T8 + 262144;
    unsigned short* tclT0 = w1T + 262144 + 262144;
    unsigned short* tclT1 = tclT0 + 61440;
    unsigned short* qkvT  = tclT1 + 61440;
    unsigned short* aprojT= qkvT + 24576;

    unsigned char* h8   = (unsigned char*)fbf;   // fp8 Nt x 1024 = 100 MB, spans fbf+a0p+part of qkvbuf (dead)
    unsigned char* xn8  = (unsigned char*)A1;    // fp8 Nt x 256 = 25 MB (A1 region dead by then)
    unsigned short* y1pad = A1;                  // 32*PR7*64 ush = 13.8 MB; A1 dead after map GEMM, until proj_ln2
    unsigned short* w1yT  = (unsigned short*)base;  // 64*448 ush = 56 KB in outtH region (dead until proj_ln2)
    unsigned short* ybf = (unsigned short*)d_out;
    unsigned short* xskip = ybf + (size_t)256*Nt;
    float* dout = (float*)d_out;

    prep_weights<<<256, 256, 0, stream>>>(gconv, tcl_w0, tcl_w1, map_w, proj_w, mlp_w1, mlp_w2,
                                          qkv_w0, qkv_w1, aproj_w0, aproj_w1, tconv_w,
                                          gct, mapT, projT, w1T8, w2T8, tclT0, tclT1, qkvT, aprojT, w1yT);
    xpose_ln1<<<NB*TT, 256, 0, stream>>>(input, n1g, n1b, A1, xskip);
    mfma_gemm<256,4><<<1024, 512, 0, stream>>>(A1, mapT, map_b, fbf, nullptr, 256, 2);
    hipMemsetAsync(a0p, 0, A0P_USH*sizeof(unsigned short), stream);
    gemm_k64<0><<<1024, 256, 0, stream>>>(fbf + 128, 512, qkvT,         qkv_b0, qkvbuf);
    gemm_k64<0><<<1024, 256, 0, stream>>>(fbf + 192, 512, qkvT + 12288, qkv_b1, qkvbuf + (size_t)Nt*192);
    attn_win<<<dim3(2048,2), 192, 0, stream>>>(qkvbuf, attnout);
    y0_kernel<<<NB*TT, 256, 0, stream>>>(fbf, gct, ybf);
    pad_y1<<<(NB*PR7*8)/256, 256, 0, stream>>>(fbf, y1pad);
    y1_mfma<<<NTOK/192, 256, 0, stream>>>(y1pad, w1yT, tconv_b, ybf);
    gemm_k64<1><<<1024, 256, 0, stream>>>(attnout,                 128, aprojT,         aproj_b0, a0p);
    tcl_mfma<<<NTOK/192, 256, 0, stream>>>(a0p, tclT0, tcl_b0, ybf, 128);
    gemm_k64<1><<<1024, 256, 0, stream>>>(attnout + (size_t)Nt*64, 128, aprojT + 12288, aproj_b1, a0p);
    tcl_mfma<<<NTOK/192, 256, 0, stream>>>(a0p, tclT1, tcl_b1, ybf, 192);
    proj_ln2<<<512, 512, 0, stream>>>(ybf, projT, proj_b, xskip, n2g, n2b, outtH, xn8);
    mfma_mlp1_fp8<<<4096, 512, 0, stream>>>(xn8, w1T8, mlp_b1, h8);
    mfma_final_fp8<<<1024, 512, 0, stream>>>(h8, w2T8, mlp_b2, outtH, dout);
}